// Round 10
// baseline (189.477 us; speedup 1.0000x reference)
//
#include <hip/hip_runtime.h>
#include <hip/hip_bf16.h>
#include <cstdint>
#include <math.h>

// Problem constants
#define DM   1024
#define NH   16
#define DH   64
#define BB   4
#define TT   2048
#define MTOT (BB*TT)   // 8192 rows

using short8 = __attribute__((ext_vector_type(8))) short;  // 8 bf16 (4 VGPRs)
using f32x4  = __attribute__((ext_vector_type(4))) float;

__device__ __forceinline__ f32x4 mfma16(short8 a, short8 b, f32x4 c) {
  return __builtin_amdgcn_mfma_f32_16x16x32_bf16(a, b, c, 0, 0, 0);
}

typedef const __attribute__((address_space(1))) unsigned int* as1_u32p;
typedef __attribute__((address_space(3))) unsigned int*       as3_u32p;

// async global->LDS, 16B per lane; LDS dest = wave-uniform base + lane*16 (linear)
__device__ __forceinline__ void gl_lds16(const void* g, void* l) {
  __builtin_amdgcn_global_load_lds(
      (as1_u32p)(reinterpret_cast<uintptr_t>(g)),
      (as3_u32p)((unsigned int)(reinterpret_cast<uintptr_t>(l))),
      16, 0, 0);
}

// XOR swizzle for tiles with 64-elem (128B) rows: 8 slots of 8 bf16; slot ^= row&7
__device__ __forceinline__ int swz64(int row, int col) {
  return row*64 + ((((col >> 3) ^ (row & 7)) << 3) | (col & 7));
}

__device__ __forceinline__ unsigned pkbf(float a, float b) {
  __hip_bfloat162 h = __float22bfloat162_rn(make_float2(a, b)); // x=lo, y=hi
  return *reinterpret_cast<unsigned*>(&h);
}

// permlane swaps (VALU pipe). Verified row semantics (involutions):
// perm16(d,s): d'=[d0,s0,d2,s2], s'=[d1,s1,d3,s3]   (16-lane rows)
// perm32(d,s): d'=[d0,d1,s0,s1], s'=[d2,d3,s2,s3]
__device__ __forceinline__ void perm16p(unsigned &a, unsigned &b) {
  asm("v_permlane16_swap_b32 %0, %1" : "+v"(a), "+v"(b));
}
__device__ __forceinline__ void perm32p(unsigned &a, unsigned &b) {
  asm("v_permlane32_swap_b32 %0, %1" : "+v"(a), "+v"(b));
}

// inline-asm LDS reads (opaque to alias analysis: no compiler-inserted vmcnt drains)
// p-series: 1024B step
__device__ __forceinline__ short8 ldsr_p0(unsigned a) {
  short8 r; asm volatile("ds_read_b128 %0, %1" : "=v"(r) : "v"(a)); return r;
}
__device__ __forceinline__ short8 ldsr_p1(unsigned a) {
  short8 r; asm volatile("ds_read_b128 %0, %1 offset:1024" : "=v"(r) : "v"(a)); return r;
}
__device__ __forceinline__ short8 ldsr_p2(unsigned a) {
  short8 r; asm volatile("ds_read_b128 %0, %1 offset:2048" : "=v"(r) : "v"(a)); return r;
}
__device__ __forceinline__ short8 ldsr_p3(unsigned a) {
  short8 r; asm volatile("ds_read_b128 %0, %1 offset:3072" : "=v"(r) : "v"(a)); return r;
}
__device__ __forceinline__ short8 ldsr_p4(unsigned a) {
  short8 r; asm volatile("ds_read_b128 %0, %1 offset:4096" : "=v"(r) : "v"(a)); return r;
}
__device__ __forceinline__ short8 ldsr_p5(unsigned a) {
  short8 r; asm volatile("ds_read_b128 %0, %1 offset:5120" : "=v"(r) : "v"(a)); return r;
}
__device__ __forceinline__ short8 ldsr_p6(unsigned a) {
  short8 r; asm volatile("ds_read_b128 %0, %1 offset:6144" : "=v"(r) : "v"(a)); return r;
}
__device__ __forceinline__ short8 ldsr_p7(unsigned a) {
  short8 r; asm volatile("ds_read_b128 %0, %1 offset:7168" : "=v"(r) : "v"(a)); return r;
}

#define LGKM0  do { asm volatile("s_waitcnt lgkmcnt(0)"); __builtin_amdgcn_sched_barrier(0); } while(0)
#define VMCNT8 do { __builtin_amdgcn_sched_barrier(0); asm volatile("s_waitcnt vmcnt(8)"); __builtin_amdgcn_sched_barrier(0); } while(0)
#define VMCNT6 do { __builtin_amdgcn_sched_barrier(0); asm volatile("s_waitcnt vmcnt(6)"); __builtin_amdgcn_sched_barrier(0); } while(0)
#define VMCNT4 do { __builtin_amdgcn_sched_barrier(0); asm volatile("s_waitcnt vmcnt(4)"); __builtin_amdgcn_sched_barrier(0); } while(0)
#define VMCNT0 do { __builtin_amdgcn_sched_barrier(0); asm volatile("s_waitcnt vmcnt(0)"); __builtin_amdgcn_sched_barrier(0); } while(0)
#define BARRIER do { __builtin_amdgcn_s_barrier(); __builtin_amdgcn_sched_barrier(0); } while(0)

// ---------------- fp32 -> bf16 copy convert ----------------
__global__ __launch_bounds__(256) void k_cvt(const float* __restrict__ in,
                                             __hip_bfloat16* __restrict__ out, int n8) {
  int i = blockIdx.x * 256 + threadIdx.x;
  if (i >= n8) return;
  const float* p = in + (size_t)i * 8;
  short8 o;
#pragma unroll
  for (int j = 0; j < 8; ++j) {
    __hip_bfloat16 h = __float2bfloat16(p[j]);
    o[j] = *reinterpret_cast<short*>(&h);
  }
  *reinterpret_cast<short8*>(out + (size_t)i * 8) = o;
}

// ---------------- W [K][N] fp32 -> Wt [N][K] bf16 (tiled transpose) ----------------
__global__ __launch_bounds__(256) void k_transpose_cvt(const float* __restrict__ W,
                                                       __hip_bfloat16* __restrict__ Wt,
                                                       int K, int N) {
  __shared__ float tbuf[32][33];
  const int n0 = blockIdx.x * 32, k0 = blockIdx.y * 32;
  const int tx = threadIdx.x & 31, ty = threadIdx.x >> 5;
#pragma unroll
  for (int i = 0; i < 4; ++i)
    tbuf[ty + i*8][tx] = W[(size_t)(k0 + ty + i*8) * N + n0 + tx];
  __syncthreads();
#pragma unroll
  for (int i = 0; i < 4; ++i)
    Wt[(size_t)(n0 + ty + i*8) * K + k0 + tx] = __float2bfloat16(tbuf[tx][ty + i*8]);
}

// ---------------- 256x256 BK=32 4-deep-pipeline QKV GEMM ----------------
// 512 threads / 8 waves (2M x 4N), per-wave 128x64 output. 32 K-tiles.
// 4 LDS slots (32KB each = A 16KB + B 16KB); stage tile t+3 while computing t.
// Boundary wait = counted vmcnt(8) (retires tile t+1's 4 loads; 8 in flight).
// K-pairs packed 2-per-128B LDS row with XOR swizzle (verified bank pattern).
__global__ __launch_bounds__(512, 2) void k_gemm3(const __hip_bfloat16* __restrict__ A,
                                                  const __hip_bfloat16* __restrict__ Bt,
                                                  const float* __restrict__ bias,
                                                  __hip_bfloat16* __restrict__ Qb,
                                                  __hip_bfloat16* __restrict__ Kb,
                                                  __hip_bfloat16* __restrict__ Vtb) {
  __shared__ __hip_bfloat16 Ls[4][16384];   // 4 slots x 32KB
  const int tid = threadIdx.x;
  const int l = tid & 63, w = tid >> 6;
  const int lr = l & 15, lg = l >> 4;
  const int lr2 = lr >> 1;
  const int wm = w >> 2, wn = w & 3;
  const int m0 = blockIdx.x * 256, n0 = blockIdx.y * 256;

  // staging source offsets: LDS elem e (linear dest) holds global (row, k):
  //   rr=e>>6, s8=(e>>3)&7, c8=s8^(rr&7), row=rr*2+(c8>>2), k=(c8&3)*8+(e&7)
  size_t aoffs[2], boffs[2];
#pragma unroll
  for (int j = 0; j < 2; ++j) {
    const int e = j * 4096 + tid * 8;
    const int rr = e >> 6;
    const int c8 = ((e >> 3) & 7) ^ (rr & 7);
    const int rg = rr * 2 + (c8 >> 2);
    const int ko = (c8 & 3) * 8;
    aoffs[j] = (size_t)(m0 + rg) * 1024 + ko;
    boffs[j] = (size_t)(n0 + rg) * 1024 + ko;
  }
  const int ld0 = tid * 8;

  auto stage = [&](int t, int s) {
    const int kb = t * 32;
    __hip_bfloat16* base = &Ls[s][0];
    gl_lds16(A + aoffs[0] + kb, base + ld0);
    gl_lds16(A + aoffs[1] + kb, base + 4096 + ld0);
    gl_lds16(Bt + boffs[0] + kb, base + 8192 + ld0);
    gl_lds16(Bt + boffs[1] + kb, base + 12288 + ld0);
  };

  // fragment read bases (byte addresses):
  // frag row ra = base + mi*16 + lr -> packed rr = base/2 + mi*8 + lr2; slot dep. on lane only
  const unsigned asLds = (unsigned)(uintptr_t)&Ls[0][0];
  const unsigned fslot = (unsigned)((((lr & 1) << 2) | lg) ^ (lr2 & 7));
  const unsigned laneA = (unsigned)(lr2 * 128) + fslot * 16u;
  const unsigned aLane = asLds + (unsigned)(wm * 8192) + laneA;
  const unsigned bLane = asLds + 16384u + (unsigned)(wn * 4096) + laneA;

  // prologue: stage tiles 0..2; wait tile0 (8 loads of tiles 1,2 stay in flight)
  stage(0, 0); stage(1, 1); stage(2, 2);
  VMCNT8;
  BARRIER;

  f32x4 acc[8][4] = {};
  short8 a_[8], b_[4];

#pragma unroll 4
  for (int t = 0; t < 32; ++t) {
    const int s = t & 3;
    const unsigned aB = aLane + (unsigned)s * 32768u;
    const unsigned bB = bLane + (unsigned)s * 32768u;
    if (t < 29) stage(t + 3, (t + 3) & 3);
    a_[0] = ldsr_p0(aB); a_[1] = ldsr_p1(aB); a_[2] = ldsr_p2(aB); a_[3] = ldsr_p3(aB);
    a_[4] = ldsr_p4(aB); a_[5] = ldsr_p5(aB); a_[6] = ldsr_p6(aB); a_[7] = ldsr_p7(aB);
    b_[0] = ldsr_p0(bB); b_[1] = ldsr_p1(bB); b_[2] = ldsr_p2(bB); b_[3] = ldsr_p3(bB);
    LGKM0;
    __builtin_amdgcn_s_setprio(1);
#pragma unroll
    for (int ni = 0; ni < 4; ++ni)
#pragma unroll
      for (int mi = 0; mi < 8; ++mi)
        acc[mi][ni] = mfma16(a_[mi], b_[ni], acc[mi][ni]);
    __builtin_amdgcn_s_setprio(0);
    if (t <= 28)      { VMCNT8; BARRIER; }
    else if (t == 29) { VMCNT4; BARRIER; }
    else if (t == 30) { VMCNT0; BARRIER; }
  }

  __syncthreads();
  // ---- LDS-bounce epilogue: wave-private 64x64 region, two 64-row halves ----
  __hip_bfloat16* reg = &Ls[0][0] + w * 4096;
  const int colbase = n0 + wn * 64;          // wave-uniform: one head, one of Q/K/V
  const int which = colbase >> 10;
  const int hh = (colbase >> 6) & 15;
  const float qs = 0.18033688011112042f;     // 0.125 * log2(e) folded into Q
#pragma unroll
  for (int h = 0; h < 2; ++h) {
#pragma unroll
    for (int n = 0; n < 4; ++n) {
      const int lc = n * 16 + lr;
      const float bv = bias[colbase + lc];
#pragma unroll
      for (int m = 0; m < 4; ++m) {
#pragma unroll
        for (int r = 0; r < 4; ++r) {
          const int lrow = m * 16 + lg * 4 + r;
          float v = acc[h * 4 + m][n][r] + bv;
          if (which == 0) v *= qs;
          const __hip_bfloat16 hv = __float2bfloat16(v);
          if (which == 2) reg[swz64(lc, lrow)] = hv;
          else            reg[swz64(lrow, lc)] = hv;
        }
      }
    }
    const int rowbase = m0 + wm * 128 + h * 64;
    const int b = rowbase >> 11;
    const size_t bh = (size_t)b * 16 + hh;
    const int g = l >> 2, i = l & 3;
    if (which < 2) {
      __hip_bfloat16* basep = (which == 0) ? Qb : Kb;
#pragma unroll
      for (int j = 0; j < 4; ++j) {
        const int lrow = j * 16 + g;
        const int t = (rowbase & 2047) + lrow;
        __hip_bfloat16* dst = basep + (bh * TT + t) * 64 + i * 16;
        short8 y0 = *reinterpret_cast<const short8*>(&reg[swz64(lrow, i * 16)]);
        short8 y1 = *reinterpret_cast<const short8*>(&reg[swz64(lrow, i * 16 + 8)]);
        *reinterpret_cast<short8*>(dst) = y0;
        *reinterpret_cast<short8*>(dst + 8) = y1;
      }
    } else {
#pragma unroll
      for (int j = 0; j < 4; ++j) {
        const int dd = j * 16 + g;
        const int t = (rowbase & 2047) + i * 16;
        __hip_bfloat16* dst = Vtb + (bh * 64 + dd) * TT + t;
        short8 y0 = *reinterpret_cast<const short8*>(&reg[swz64(dd, i * 16)]);
        short8 y1 = *reinterpret_cast<const short8*>(&reg[swz64(dd, i * 16 + 8)]);
        *reinterpret_cast<short8*>(dst) = y0;
        *reinterpret_cast<short8*>(dst + 8) = y1;
      }
    }
  }
}

// ---------------- 256x128 triple-buffered deep-pipeline GEMM (proj) ----------------
__device__ __forceinline__ short8 ldsr_o0(unsigned a) { return ldsr_p0(a); }
__global__ __launch_bounds__(512, 2) void k_gemm2(const __hip_bfloat16* __restrict__ A,
                                                  const __hip_bfloat16* __restrict__ Bt,
                                                  const float* __restrict__ bias,
                                                  float* __restrict__ outF) {
  __shared__ __hip_bfloat16 As[3][256 * 64];
  __shared__ __hip_bfloat16 Bs[3][128 * 64];
  const int tid = threadIdx.x;
  const int l = tid & 63, w = tid >> 6;
  const int lr = l & 15, lg = l >> 4;
  const int wm = w >> 1, wn = w & 1;
  const int m0 = blockIdx.x * 256, n0 = blockIdx.y * 128;

  const int srow = tid >> 3;
  const int scol = (((tid & 7) ^ (srow & 7)) << 3);
  const size_t aoffs = (size_t)(m0 + srow) * 1024 + scol;
  const size_t boffs = (size_t)(n0 + srow) * 1024 + scol;
  const int ldst = tid * 8;

  auto stage = [&](int t, int s) {
    const int k0 = t * 64;
    __hip_bfloat16* as_ = &As[s][0];
    __hip_bfloat16* bs_ = &Bs[s][0];
#pragma unroll
    for (int rd = 0; rd < 4; ++rd)
      gl_lds16(A + aoffs + (size_t)rd * 65536 + k0, as_ + rd * 4096 + ldst);
#pragma unroll
    for (int rd = 0; rd < 2; ++rd)
      gl_lds16(Bt + boffs + (size_t)rd * 65536 + k0, bs_ + rd * 4096 + ldst);
  };

  const unsigned asLds = (unsigned)(uintptr_t)&As[0][0];
  const unsigned bsLds = (unsigned)(uintptr_t)&Bs[0][0];
  const unsigned aBase = asLds + 2u * ((wm*64 + lr) * 64 + ((lg ^ (lr & 7)) << 3));
  const unsigned bBase = bsLds + 2u * ((wn*64 + lr) * 64 + ((lg ^ (lr & 7)) << 3));

  stage(0, 0);
  stage(1, 1);
  VMCNT6;
  BARRIER;

  f32x4 acc[4][4] = {};
  short8 a_[4][2], b_[2][2];

#pragma unroll
  for (int t = 0; t < 16; ++t) {
    const int s = t % 3;
    const unsigned aB0 = aBase + (unsigned)s * 32768u;
    const unsigned aB1 = aB0 ^ 64u;
    const unsigned bB0 = bBase + (unsigned)s * 16384u;
    const unsigned bB1 = bB0 ^ 64u;
    if (t + 2 < 16) stage(t + 2, (t + 2) % 3);
    a_[0][0] = ldsr_p0(aB0); a_[1][0] = ldsr_p2(aB0); a_[2][0] = ldsr_p4(aB0); a_[3][0] = ldsr_p6(aB0);
    a_[0][1] = ldsr_p0(aB1); a_[1][1] = ldsr_p2(aB1); a_[2][1] = ldsr_p4(aB1); a_[3][1] = ldsr_p6(aB1);
    b_[0][0] = ldsr_p0(bB0); b_[1][0] = ldsr_p2(bB0);
    b_[0][1] = ldsr_p0(bB1); b_[1][1] = ldsr_p2(bB1);
    LGKM0;
    __builtin_amdgcn_s_setprio(1);
#pragma unroll
    for (int m = 0; m < 4; ++m)
#pragma unroll
      for (int n = 0; n < 2; ++n)
#pragma unroll
        for (int ks = 0; ks < 2; ++ks)
          acc[m][n] = mfma16(a_[m][ks], b_[n][ks], acc[m][n]);
    __builtin_amdgcn_s_setprio(0);
    b_[0][0] = ldsr_p4(bB0); b_[1][0] = ldsr_p6(bB0);
    b_[0][1] = ldsr_p4(bB1); b_[1][1] = ldsr_p6(bB1);
    LGKM0;
    __builtin_amdgcn_s_setprio(1);
#pragma unroll
    for (int m = 0; m < 4; ++m)
#pragma unroll
      for (int n = 0; n < 2; ++n)
#pragma unroll
        for (int ks = 0; ks < 2; ++ks)
          acc[m][n + 2] = mfma16(a_[m][ks], b_[n][ks], acc[m][n + 2]);
    __builtin_amdgcn_s_setprio(0);
    if (t <= 13) { VMCNT6; }
    else if (t == 14) { VMCNT0; }
    BARRIER;
  }

  __syncthreads();
#pragma unroll
  for (int n = 0; n < 4; ++n) {
    const int col = n0 + wn * 64 + n * 16 + lr;
    const float bvv = bias[col];
#pragma unroll
    for (int m = 0; m < 4; ++m)
#pragma unroll
      for (int r = 0; r < 4; ++r) {
        const int row = m0 + wm * 64 + m * 16 + lg * 4 + r;
        outF[(size_t)row * 1024 + col] = acc[m][n][r] + bvv;
      }
  }
}

// ---------------- causal flash attention ----------------
// Merged paired q-tiles, fixed-max softmax, sigma-permuted K rows so the P->PV
// redistribution is exactly 2x permlane16_swap + 2x permlane32_swap (no cndmask).
__device__ __forceinline__ void tile_step(f32x4 s0, f32x4 s1, int kbase, int kmaxw, int qmb,
                                          short8 v0, short8 v1, short8 v2, short8 v3,
                                          f32x4 (&acc)[4], float& lrun) {
  if (kbase + 31 > kmaxw - 15) {       // diagonal chunk: per-element causal mask
#pragma unroll
    for (int r = 0; r < 4; ++r) {
      const int off = (r & 1) + ((r & 2) << 2);   // 0,1,8,9
      if (kbase + off > qmb)      s0[r] = -INFINITY;
      if (kbase + 16 + off > qmb) s1[r] = -INFINITY;
    }
  }
  float p0 = __builtin_amdgcn_exp2f(s0[0]), p1 = __builtin_amdgcn_exp2f(s0[1]);
  float p2 = __builtin_amdgcn_exp2f(s0[2]), p3 = __builtin_amdgcn_exp2f(s0[3]);
  float p4 = __builtin_amdgcn_exp2f(s1[0]), p5 = __builtin_amdgcn_exp2f(s1[1]);
  float p6 = __builtin_amdgcn_exp2f(s1[2]), p7 = __builtin_amdgcn_exp2f(s1[3]);
  lrun += ((p0 + p1) + (p2 + p3)) + ((p4 + p5) + (p6 + p7));
  unsigned u0 = pkbf(p0, p1);
  unsigned u1 = pkbf(p2, p3);
  unsigned u2 = pkbf(p4, p5);
  unsigned u3 = pkbf(p6, p7);
  perm16p(u0, u1);
  perm16p(u2, u3);
  perm32p(u0, u2);
  perm32p(u1, u3);
  union { unsigned u[4]; short8 s; } pw;
  pw.u[0] = u0; pw.u[1] = u2; pw.u[2] = u1; pw.u[3] = u3;
  const short8 pf = pw.s;
  acc[0] = mfma16(v0, pf, acc[0]);
  acc[1] = mfma16(v1, pf, acc[1]);
  acc[2] = mfma16(v2, pf, acc[2]);
  acc[3] = mfma16(v3, pf, acc[3]);
}

__device__ __forceinline__ void store_tile(__hip_bfloat16* Ylds, f32x4 (&acc)[4],
                                           float lrun, int q0, int w, int l,
                                           int lr, int lg, int bh,
                                           __hip_bfloat16* __restrict__ Y) {
  lrun += __shfl_xor(lrun, 16);
  lrun += __shfl_xor(lrun, 32);
  const float inv = 1.f / lrun;
#pragma unroll
  for (int nb = 0; nb < 4; ++nb) {
#pragma unroll
    for (int r = 0; r < 4; ++r) {
      const int d = nb * 16 + lg * 4 + r;
      Ylds[swz64(lr, d)] = __float2bfloat16(acc[nb][r] * inv);
    }
  }
  const int rr = l >> 2, part = l & 3;
  const int trow = q0 + w * 16 + rr;
  const int b = bh >> 4, h = bh & 15;
  short8 y0 = *reinterpret_cast<const short8*>(&Ylds[swz64(rr, part * 16)]);
  short8 y1 = *reinterpret_cast<const short8*>(&Ylds[swz64(rr, part * 16 + 8)]);
  __hip_bfloat16* dst = Y + ((size_t)b * TT + trow) * 1024 + h * 64 + part * 16;
  *reinterpret_cast<short8*>(dst) = y0;
  *reinterpret_cast<short8*>(dst + 8) = y1;
}

__global__ __launch_bounds__(256, 4) void k_flash(const __hip_bfloat16* __restrict__ Qb,
                                                  const __hip_bfloat16* __restrict__ Kb,
                                                  const __hip_bfloat16* __restrict__ Vtb,
                                                  __hip_bfloat16* __restrict__ Y) {
  __shared__ __hip_bfloat16 Klds[128 * 64];
  __shared__ __hip_bfloat16 Vtlds[64 * 128];
  const int tid = threadIdx.x;
  const int l = tid & 63, w = tid >> 6;
  const int lr = l & 15, lg = l >> 4;
  const int p  = blockIdx.x >> 6;       // pair index 0..15
  const int bh = blockIdx.x & 63;
  const int q0A = p * 64, q0B = (31 - p) * 64;
  const __hip_bfloat16* Qp = Qb + (size_t)bh * TT * 64;
  const __hip_bfloat16* Kp = Kb + (size_t)bh * TT * 64;
  const __hip_bfloat16* Vp = Vtb + (size_t)bh * 64 * TT;
  const int qrowA = q0A + w * 16 + lr;
  const int qrowB = q0B + w * 16 + lr;
  const short8 qfA0 = *reinterpret_cast<const short8*>(Qp + (size_t)qrowA * 64 + lg * 8);
  const short8 qfA1 = *reinterpret_cast<const short8*>(Qp + (size_t)qrowA * 64 + 32 + lg * 8);
  const short8 qfB0 = *reinterpret_cast<const short8*>(Qp + (size_t)qrowB * 64 + lg * 8);
  const short8 qfB1 = *reinterpret_cast<const short8*>(Qp + (size_t)qrowB * 64 + 32 + lg * 8);
  f32x4 accA[4] = {}, accB[4] = {};
  float lA = 0.f, lB = 0.f;

  const int ka  = lr * 64 + ((lg ^ (lr & 7)) << 3);
  const int va  = lr * 128 + ((lg ^ (lr & 15)) << 3);

  const __hip_bfloat16* gk[4];
  const __hip_bfloat16* gv[4];
  __hip_bfloat16* lk[4];
  __hip_bfloat16* lv[4];
#pragma unroll
  for (int it = 0; it < 4; ++it) {
    int e = it * 2048 + tid * 8;
    int rowk = e >> 6;
    int lcolk = ((((e >> 3) & 7) ^ (rowk & 7)) << 3);
    int rk = rowk & 15;
    int srk = (((rk >> 1) ^ (rk >> 3)) & 1) ? (rk ^ 10) : rk;
    int rowks = (rowk & ~15) | srk;
    gk[it] = Kp + (size_t)rowks * 64 + lcolk;
    lk[it] = &Klds[e];
    int rowv = e >> 7;
    int lcolv = ((((e >> 3) & 15) ^ (rowv & 15)) << 3);
    gv[it] = Vp + (size_t)rowv * TT + lcolv;
    lv[it] = &Vtlds[e];
  }

  const int kmaxwA = q0A + w * 16 + 15;
  const int kmaxwB = q0B + w * 16 + 15;
  const int base_lg = ((lg & 1) << 2) | (lg & 2);
  const int qmbA = qrowA - base_lg;
  const int qmbB = qrowB - base_lg;
  const int nblk = (q0B + 63) / 128 + 1;
  for (int blk = 0; blk < nblk; ++blk) {
    const int kv0 = blk * 128;
#pragma unroll
    for (int it = 0; it < 4; ++it) {
      gl_lds16(gk[it], lk[it]);
      gk[it] += 128 * 64;
    }
#pragma unroll
    for (int it = 0; it < 4; ++it) {
      gl_lds16(gv[it], lv[it]);
      gv[it] += 128;
    }
    __syncthreads();
#pragma unroll
    for (int kci = 0; kci < 4; ++kci) {
      const int kbase = kv0 + kci * 32;
      if (kbase > kmaxwB) break;
      const int kb = ka + kci * 2048;
      const short8 kf00 = *reinterpret_cast<const short8*>(&Klds[kb]);
      const short8 kf10 = *reinterpret_cast<const short8*>(&Klds[kb + 1024]);
      const short8 kf01 = *reinterpret_cast<const short8*>(&Klds[kb ^ 32]);
      const short8 kf11 = *reinterpret_cast<const short8*>(&Klds[(kb + 1024) ^ 32]);
      f32x4 sB0 = {}, sB1 = {};
      sB0 = mfma16(kf00, qfB0, sB0);
      sB1 = mfma16(kf10, qfB0, sB1);
      sB0 = mfma16(kf01, qfB1, sB0);
      sB1 = mfma16(kf11, qfB1, sB1);
      const bool aAct = (kbase <= kmaxwA);
      f32x4 sA0 = {}, sA1 = {};
      if (aAct) {
        sA0 = mfma16(kf00, qfA0, sA0);
        sA1 = mfma16(kf10, qfA0, sA1);
        sA0 = mfma16(kf01, qfA1, sA0);
        sA1 = mfma16(kf11, qfA1, sA1);
      }
      const int vb = va ^ (kci * 32);
      const short8 v0 = *reinterpret_cast<const short8*>(&Vtlds[vb]);
      const short8 v1 = *reinterpret_cast<const short8*>(&Vtlds[vb + 2048]);
      const short8 v2 = *reinterpret_cast<const short8*>(&Vtlds[vb + 4096]);
      const short8 v3 = *reinterpret_cast<const short8*>(&Vtlds[vb + 6144]);
      tile_step(sB0, sB1, kbase, kmaxwB, qmbB, v0, v1, v2, v3, accB, lB);
      if (aAct)
        tile_step(sA0, sA1, kbase, kmaxwA, qmbA, v0, v1, v2, v3, accA, lA);
    }
    __syncthreads();
  }
  __hip_bfloat16* Ylds = Klds + w * 1024;
  store_tile(Ylds, accA, lA, q0A, w, l, lr, lg, bh, Y);
  store_tile(Ylds, accB, lB, q0B, w, l, lr, lg, bh, Y);
}

// ---------------- launch ----------------
extern "C" void kernel_launch(void* const* d_in, const int* in_sizes, int n_in,
                              void* d_out, int out_size, void* d_ws, size_t ws_size,
                              hipStream_t stream) {
  const float* x     = (const float*)d_in[0];
  const float* Wqkv  = (const float*)d_in[1];
  const float* bqkv  = (const float*)d_in[2];
  const float* Wproj = (const float*)d_in[3];
  const float* bproj = (const float*)d_in[4];

  char* ws = (char*)d_ws;
  size_t off = 0;
  auto alloc = [&](size_t bytes) {
    char* p = ws + off;
    off += (bytes + 255) & ~(size_t)255;
    return p;
  };
  __hip_bfloat16* xb    = (__hip_bfloat16*)alloc((size_t)MTOT * 1024 * 2);
  __hip_bfloat16* wqkvT = (__hip_bfloat16*)alloc((size_t)3072 * 1024 * 2);
  __hip_bfloat16* wpT   = (__hip_bfloat16*)alloc((size_t)1024 * 1024 * 2);
  __hip_bfloat16* Qb    = (__hip_bfloat16*)alloc((size_t)64 * TT * 64 * 2);
  __hip_bfloat16* Kb    = (__hip_bfloat16*)alloc((size_t)64 * TT * 64 * 2);
  __hip_bfloat16* Vtb   = (__hip_bfloat16*)alloc((size_t)64 * TT * 64 * 2);
  __hip_bfloat16* Yb    = (__hip_bfloat16*)alloc((size_t)MTOT * 1024 * 2);

  k_cvt<<<(MTOT * 1024 / 8 + 255) / 256, 256, 0, stream>>>(x, xb, MTOT * 1024 / 8);
  k_transpose_cvt<<<dim3(3072 / 32, 1024 / 32), 256, 0, stream>>>(Wqkv, wqkvT, 1024, 3072);
  k_transpose_cvt<<<dim3(1024 / 32, 1024 / 32), 256, 0, stream>>>(Wproj, wpT, 1024, 1024);
  k_gemm3<<<dim3(32, 12), 512, 0, stream>>>(xb, wqkvT, bqkv, Qb, Kb, Vtb);
  k_flash<<<16 * 64, 256, 0, stream>>>(Qb, Kb, Vtb, Yb);
  k_gemm2<<<dim3(32, 8), 512, 0, stream>>>(Yb, wpT, bproj, (float*)d_out);
}

// Round 11
// 165.368 us; speedup vs baseline: 1.1458x; 1.1458x over previous
//
#include <hip/hip_runtime.h>
#include <hip/hip_bf16.h>
#include <cstdint>
#include <math.h>

// Problem constants
#define DM   1024
#define NH   16
#define DH   64
#define BB   4
#define TT   2048
#define MTOT (BB*TT)   // 8192 rows

using short8 = __attribute__((ext_vector_type(8))) short;  // 8 bf16 (4 VGPRs)
using f32x4  = __attribute__((ext_vector_type(4))) float;

__device__ __forceinline__ f32x4 mfma16(short8 a, short8 b, f32x4 c) {
  return __builtin_amdgcn_mfma_f32_16x16x32_bf16(a, b, c, 0, 0, 0);
}

typedef const __attribute__((address_space(1))) unsigned int* as1_u32p;
typedef __attribute__((address_space(3))) unsigned int*       as3_u32p;

// async global->LDS, 16B per lane; LDS dest = wave-uniform base + lane*16 (linear)
__device__ __forceinline__ void gl_lds16(const void* g, void* l) {
  __builtin_amdgcn_global_load_lds(
      (as1_u32p)(reinterpret_cast<uintptr_t>(g)),
      (as3_u32p)((unsigned int)(reinterpret_cast<uintptr_t>(l))),
      16, 0, 0);
}

// XOR swizzle for tiles with 64-elem (128B) rows: 8 slots of 8 bf16; slot ^= row&7
__device__ __forceinline__ int swz64(int row, int col) {
  return row*64 + ((((col >> 3) ^ (row & 7)) << 3) | (col & 7));
}

__device__ __forceinline__ unsigned pkbf(float a, float b) {
  __hip_bfloat162 h = __float22bfloat162_rn(make_float2(a, b)); // x=lo, y=hi
  return *reinterpret_cast<unsigned*>(&h);
}

// permlane swaps (VALU pipe). Verified row semantics (involutions):
// perm16(d,s): d'=[d0,s0,d2,s2], s'=[d1,s1,d3,s3]   (16-lane rows)
// perm32(d,s): d'=[d0,d1,s0,s1], s'=[d2,d3,s2,s3]
__device__ __forceinline__ void perm16p(unsigned &a, unsigned &b) {
  asm("v_permlane16_swap_b32 %0, %1" : "+v"(a), "+v"(b));
}
__device__ __forceinline__ void perm32p(unsigned &a, unsigned &b) {
  asm("v_permlane32_swap_b32 %0, %1" : "+v"(a), "+v"(b));
}

// inline-asm LDS reads (opaque to alias analysis: no compiler-inserted vmcnt drains)
__device__ __forceinline__ short8 ldsr_o0(unsigned a) {
  short8 r; asm volatile("ds_read_b128 %0, %1" : "=v"(r) : "v"(a)); return r;
}
__device__ __forceinline__ short8 ldsr_o1(unsigned a) {
  short8 r; asm volatile("ds_read_b128 %0, %1 offset:2048" : "=v"(r) : "v"(a)); return r;
}
__device__ __forceinline__ short8 ldsr_o2(unsigned a) {
  short8 r; asm volatile("ds_read_b128 %0, %1 offset:4096" : "=v"(r) : "v"(a)); return r;
}
__device__ __forceinline__ short8 ldsr_o3(unsigned a) {
  short8 r; asm volatile("ds_read_b128 %0, %1 offset:6144" : "=v"(r) : "v"(a)); return r;
}
__device__ __forceinline__ short8 ldsr_o4(unsigned a) {
  short8 r; asm volatile("ds_read_b128 %0, %1 offset:8192" : "=v"(r) : "v"(a)); return r;
}
__device__ __forceinline__ short8 ldsr_o5(unsigned a) {
  short8 r; asm volatile("ds_read_b128 %0, %1 offset:10240" : "=v"(r) : "v"(a)); return r;
}
__device__ __forceinline__ short8 ldsr_o6(unsigned a) {
  short8 r; asm volatile("ds_read_b128 %0, %1 offset:12288" : "=v"(r) : "v"(a)); return r;
}

#define LGKM0  do { asm volatile("s_waitcnt lgkmcnt(0)"); __builtin_amdgcn_sched_barrier(0); } while(0)
#define LGKM4  do { asm volatile("s_waitcnt lgkmcnt(4)"); __builtin_amdgcn_sched_barrier(0); } while(0)
#define VMCNT8 do { __builtin_amdgcn_sched_barrier(0); asm volatile("s_waitcnt vmcnt(8)"); __builtin_amdgcn_sched_barrier(0); } while(0)
#define VMCNT6 do { __builtin_amdgcn_sched_barrier(0); asm volatile("s_waitcnt vmcnt(6)"); __builtin_amdgcn_sched_barrier(0); } while(0)
#define VMCNT0 do { __builtin_amdgcn_sched_barrier(0); asm volatile("s_waitcnt vmcnt(0)"); __builtin_amdgcn_sched_barrier(0); } while(0)
#define BARRIER do { __builtin_amdgcn_s_barrier(); __builtin_amdgcn_sched_barrier(0); } while(0)

// ---------------- fp32 -> bf16 copy convert ----------------
__global__ __launch_bounds__(256) void k_cvt(const float* __restrict__ in,
                                             __hip_bfloat16* __restrict__ out, int n8) {
  int i = blockIdx.x * 256 + threadIdx.x;
  if (i >= n8) return;
  const float* p = in + (size_t)i * 8;
  short8 o;
#pragma unroll
  for (int j = 0; j < 8; ++j) {
    __hip_bfloat16 h = __float2bfloat16(p[j]);
    o[j] = *reinterpret_cast<short*>(&h);
  }
  *reinterpret_cast<short8*>(out + (size_t)i * 8) = o;
}

// ---------------- W [K][N] fp32 -> Wt [N][K] bf16 (tiled transpose) ----------------
__global__ __launch_bounds__(256) void k_transpose_cvt(const float* __restrict__ W,
                                                       __hip_bfloat16* __restrict__ Wt,
                                                       int K, int N) {
  __shared__ float tbuf[32][33];
  const int n0 = blockIdx.x * 32, k0 = blockIdx.y * 32;
  const int tx = threadIdx.x & 31, ty = threadIdx.x >> 5;
#pragma unroll
  for (int i = 0; i < 4; ++i)
    tbuf[ty + i*8][tx] = W[(size_t)(k0 + ty + i*8) * N + n0 + tx];
  __syncthreads();
#pragma unroll
  for (int i = 0; i < 4; ++i)
    Wt[(size_t)(n0 + ty + i*8) * K + k0 + tx] = __float2bfloat16(tbuf[tx][ty + i*8]);
}

// ---------------- 256x192 double-buffered deep-pipeline QKV GEMM ----------------
// (r9-proven) + XCD-aware block swizzle (each XCD owns 64 contiguous linear ids
// = 2 B-panels -> B panel reads become L2-local; bijective since 512 % 8 == 0).
__global__ __launch_bounds__(512, 2) void k_gemm3(const __hip_bfloat16* __restrict__ A,
                                                  const __hip_bfloat16* __restrict__ Bt,
                                                  const float* __restrict__ bias,
                                                  __hip_bfloat16* __restrict__ Qb,
                                                  __hip_bfloat16* __restrict__ Kb,
                                                  __hip_bfloat16* __restrict__ Vtb) {
  __shared__ __hip_bfloat16 As[2][256 * 64];
  __shared__ __hip_bfloat16 Bs[2][192 * 64];
  const int tid = threadIdx.x;
  const int l = tid & 63, w = tid >> 6;
  const int lr = l & 15, lg = l >> 4;
  const int wm = w >> 1, wn = w & 1;
  const int lin = (int)blockIdx.x + ((int)blockIdx.y << 5);   // 512 wgs
  const int swzb = (lin & 7) * 64 + (lin >> 3);
  const int m0 = (swzb & 31) * 256, n0 = (swzb >> 5) * 192;

  const int srow = tid >> 3;
  const int scol = (((tid & 7) ^ (srow & 7)) << 3);
  const size_t aoffs = (size_t)(m0 + srow) * 1024 + scol;
  const size_t boffs = (size_t)(n0 + srow) * 1024 + scol;
  const int ldst = tid * 8;

  auto stage = [&](int t, int s) {
    const int k0 = t * 64;
#pragma unroll
    for (int rd = 0; rd < 4; ++rd)
      gl_lds16(A + aoffs + (size_t)rd * 65536 + k0, &As[s][rd * 4096 + ldst]);
#pragma unroll
    for (int rd = 0; rd < 3; ++rd)
      gl_lds16(Bt + boffs + (size_t)rd * 65536 + k0, &Bs[s][rd * 4096 + ldst]);
  };

  const unsigned asLds = (unsigned)(uintptr_t)&As[0][0];
  const unsigned bsLds = (unsigned)(uintptr_t)&Bs[0][0];
  const unsigned aBase0 = asLds + 2u * ((wm*64 + lr) * 64 + ((lg ^ (lr & 7)) << 3));
  const unsigned bBase0 = bsLds + 2u * ((wn*96 + lr) * 64 + ((lg ^ (lr & 7)) << 3));

  stage(0, 0);
  VMCNT0;
  BARRIER;

  f32x4 acc[4][6] = {};
  short8 a_[4][2], b_[3][2];

#pragma unroll
  for (int t = 0; t < 16; ++t) {
    const int s = t & 1;
    const unsigned aB0 = aBase0 + (unsigned)s * 32768u;
    const unsigned aB1 = aB0 ^ 64u;
    const unsigned bB0 = bBase0 + (unsigned)s * 24576u;
    const unsigned bB1 = bB0 ^ 64u;
    if (t < 15) stage(t + 1, s ^ 1);
    // phase A: A frags + B n0..2, MFMA n=0..2
    a_[0][0] = ldsr_o0(aB0); a_[1][0] = ldsr_o1(aB0); a_[2][0] = ldsr_o2(aB0); a_[3][0] = ldsr_o3(aB0);
    a_[0][1] = ldsr_o0(aB1); a_[1][1] = ldsr_o1(aB1); a_[2][1] = ldsr_o2(aB1); a_[3][1] = ldsr_o3(aB1);
    b_[0][0] = ldsr_o0(bB0); b_[1][0] = ldsr_o1(bB0); b_[2][0] = ldsr_o2(bB0);
    b_[0][1] = ldsr_o0(bB1); b_[1][1] = ldsr_o1(bB1); b_[2][1] = ldsr_o2(bB1);
    LGKM0;
    __builtin_amdgcn_s_setprio(1);
#pragma unroll
    for (int m = 0; m < 4; ++m)
#pragma unroll
      for (int n = 0; n < 3; ++n)
#pragma unroll
        for (int ks = 0; ks < 2; ++ks)
          acc[m][n] = mfma16(a_[m][ks], b_[n][ks], acc[m][n]);
    __builtin_amdgcn_s_setprio(0);
    // phase B: B n3..5, MFMA n=3..5
    b_[0][0] = ldsr_o3(bB0); b_[1][0] = ldsr_o4(bB0); b_[2][0] = ldsr_o5(bB0);
    b_[0][1] = ldsr_o3(bB1); b_[1][1] = ldsr_o4(bB1); b_[2][1] = ldsr_o5(bB1);
    LGKM0;
    __builtin_amdgcn_s_setprio(1);
#pragma unroll
    for (int m = 0; m < 4; ++m)
#pragma unroll
      for (int n = 0; n < 3; ++n)
#pragma unroll
        for (int ks = 0; ks < 2; ++ks)
          acc[m][n + 3] = mfma16(a_[m][ks], b_[n][ks], acc[m][n + 3]);
    __builtin_amdgcn_s_setprio(0);
    if (t < 15) { VMCNT0; }
    BARRIER;
  }

  __syncthreads();
  // ---- per-16-col-group LDS-bounce epilogue ----
  __hip_bfloat16* reg = (w < 4) ? (&As[0][0] + w * 6144)
                                : (&Bs[0][0] + (w - 4) * 6144);
  const int colbase = n0 + wn * 96;
  const int rowbase = m0 + wm * 64;
  const int bidx = rowbase >> 11;
  const int tbase = rowbase & 2047;
  const float qs = 0.18033688011112042f;   // 0.125 * log2(e) folded into Q
  float bv[6];
#pragma unroll
  for (int g = 0; g < 6; ++g) bv[g] = bias[colbase + g * 16 + lr];
#pragma unroll
  for (int g = 0; g < 6; ++g) {
    const int cg0 = colbase + g * 16;
    const int which = cg0 >> 10;
    __hip_bfloat16* rg = reg + g * 1024;
    if (which == 2) {
#pragma unroll
      for (int m = 0; m < 4; ++m)
#pragma unroll
        for (int r = 0; r < 4; ++r) {
          const int t = m * 16 + lg * 4 + r;
          rg[lr * 64 + (t ^ ((lr & 7) << 3))] = __float2bfloat16(acc[m][g][r] + bv[g]);
        }
    } else {
      const float sc = (which == 0) ? qs : 1.f;
#pragma unroll
      for (int m = 0; m < 4; ++m)
#pragma unroll
        for (int r = 0; r < 4; ++r) {
          const int t = m * 16 + lg * 4 + r;
          rg[t * 16 + (lr ^ (((t >> 2) & 1) << 3))] =
              __float2bfloat16((acc[m][g][r] + bv[g]) * sc);
        }
    }
  }
#pragma unroll
  for (int g = 0; g < 6; ++g) {
    const int cg0 = colbase + g * 16;
    const int which = cg0 >> 10;
    const int hh = (cg0 >> 6) & 15;
    const int dd0 = cg0 & 48;
    const size_t bh = (size_t)bidx * 16 + hh;
    const __hip_bfloat16* rg = reg + g * 1024;
    if (which < 2) {
      __hip_bfloat16* basep = (which == 0) ? Qb : Kb;
      const int t = l;
      const int Xc = ((t >> 2) & 1) << 3;
      short8 y0 = *reinterpret_cast<const short8*>(&rg[t * 16 + Xc]);
      short8 y1 = *reinterpret_cast<const short8*>(&rg[t * 16 + (Xc ^ 8)]);
      __hip_bfloat16* dst = basep + (bh * TT + tbase + t) * 64 + dd0;
      *reinterpret_cast<short8*>(dst) = y0;
      *reinterpret_cast<short8*>(dst + 8) = y1;
    } else {
      const int dd = l >> 2, tseg = l & 3;
      const int X = (dd & 7) << 3;
      const int S0 = (((tseg ^ (X >> 4)) & 3) << 4) | (X & 8);
      short8 y0 = *reinterpret_cast<const short8*>(&rg[dd * 64 + S0]);
      short8 y1 = *reinterpret_cast<const short8*>(&rg[dd * 64 + (S0 ^ 8)]);
      __hip_bfloat16* dst = Vtb + (bh * 64 + dd0 + dd) * TT + tbase + tseg * 16;
      *reinterpret_cast<short8*>(dst) = y0;
      *reinterpret_cast<short8*>(dst + 8) = y1;
    }
  }
}

// ---------------- 256x128 triple-buffered deep-pipeline GEMM (proj) ----------------
__global__ __launch_bounds__(512, 2) void k_gemm2(const __hip_bfloat16* __restrict__ A,
                                                  const __hip_bfloat16* __restrict__ Bt,
                                                  const float* __restrict__ bias,
                                                  float* __restrict__ outF) {
  __shared__ __hip_bfloat16 As[3][256 * 64];
  __shared__ __hip_bfloat16 Bs[3][128 * 64];
  const int tid = threadIdx.x;
  const int l = tid & 63, w = tid >> 6;
  const int lr = l & 15, lg = l >> 4;
  const int wm = w >> 1, wn = w & 1;
  const int lin = (int)blockIdx.x + ((int)blockIdx.y << 5);   // 256 wgs
  const int swzb = (lin & 7) * 32 + (lin >> 3);
  const int m0 = (swzb & 31) * 256, n0 = (swzb >> 5) * 128;

  const int srow = tid >> 3;
  const int scol = (((tid & 7) ^ (srow & 7)) << 3);
  const size_t aoffs = (size_t)(m0 + srow) * 1024 + scol;
  const size_t boffs = (size_t)(n0 + srow) * 1024 + scol;
  const int ldst = tid * 8;

  auto stage = [&](int t, int s) {
    const int k0 = t * 64;
    __hip_bfloat16* as_ = &As[s][0];
    __hip_bfloat16* bs_ = &Bs[s][0];
#pragma unroll
    for (int rd = 0; rd < 4; ++rd)
      gl_lds16(A + aoffs + (size_t)rd * 65536 + k0, as_ + rd * 4096 + ldst);
#pragma unroll
    for (int rd = 0; rd < 2; ++rd)
      gl_lds16(Bt + boffs + (size_t)rd * 65536 + k0, bs_ + rd * 4096 + ldst);
  };

  const unsigned asLds = (unsigned)(uintptr_t)&As[0][0];
  const unsigned bsLds = (unsigned)(uintptr_t)&Bs[0][0];
  const unsigned aBase = asLds + 2u * ((wm*64 + lr) * 64 + ((lg ^ (lr & 7)) << 3));
  const unsigned bBase = bsLds + 2u * ((wn*64 + lr) * 64 + ((lg ^ (lr & 7)) << 3));

  stage(0, 0);
  stage(1, 1);
  VMCNT6;
  BARRIER;

  f32x4 acc[4][4] = {};
  short8 a_[4][2], b_[2][2];

#pragma unroll
  for (int t = 0; t < 16; ++t) {
    const int s = t % 3;
    const unsigned aB0 = aBase + (unsigned)s * 32768u;
    const unsigned aB1 = aB0 ^ 64u;
    const unsigned bB0 = bBase + (unsigned)s * 16384u;
    const unsigned bB1 = bB0 ^ 64u;
    if (t + 2 < 16) stage(t + 2, (t + 2) % 3);
    a_[0][0] = ldsr_o0(aB0); a_[1][0] = ldsr_o1(aB0); a_[2][0] = ldsr_o2(aB0); a_[3][0] = ldsr_o3(aB0);
    a_[0][1] = ldsr_o0(aB1); a_[1][1] = ldsr_o1(aB1); a_[2][1] = ldsr_o2(aB1); a_[3][1] = ldsr_o3(aB1);
    b_[0][0] = ldsr_o0(bB0); b_[1][0] = ldsr_o1(bB0);
    b_[0][1] = ldsr_o0(bB1); b_[1][1] = ldsr_o1(bB1);
    LGKM0;
    __builtin_amdgcn_s_setprio(1);
#pragma unroll
    for (int m = 0; m < 4; ++m)
#pragma unroll
      for (int n = 0; n < 2; ++n)
#pragma unroll
        for (int ks = 0; ks < 2; ++ks)
          acc[m][n] = mfma16(a_[m][ks], b_[n][ks], acc[m][n]);
    __builtin_amdgcn_s_setprio(0);
    b_[0][0] = ldsr_o2(bB0); b_[1][0] = ldsr_o3(bB0);
    b_[0][1] = ldsr_o2(bB1); b_[1][1] = ldsr_o3(bB1);
    LGKM0;
    __builtin_amdgcn_s_setprio(1);
#pragma unroll
    for (int m = 0; m < 4; ++m)
#pragma unroll
      for (int n = 0; n < 2; ++n)
#pragma unroll
        for (int ks = 0; ks < 2; ++ks)
          acc[m][n + 2] = mfma16(a_[m][ks], b_[n][ks], acc[m][n + 2]);
    __builtin_amdgcn_s_setprio(0);
    if (t <= 13) { VMCNT6; }
    else if (t == 14) { VMCNT0; }
    BARRIER;
  }

  __syncthreads();
#pragma unroll
  for (int n = 0; n < 4; ++n) {
    const int col = n0 + wn * 64 + n * 16 + lr;
    const float bvv = bias[col];
#pragma unroll
    for (int m = 0; m < 4; ++m)
#pragma unroll
      for (int r = 0; r < 4; ++r) {
        const int row = m0 + wm * 64 + m * 16 + lg * 4 + r;
        outF[(size_t)row * 1024 + col] = acc[m][n][r] + bvv;
      }
  }
}

// ---------------- causal flash attention (pipelined, double-buffered K/V) ----------------
// Merged paired q-tiles, fixed-max softmax, sigma-permuted K rows (permlane P-redistribution).
// NEW: 2-slot K/V LDS; stage blk+1 before computing blk; counted vmcnt(8); inline-asm
// ds_read for K/V frags (avoids compiler vmcnt(0) drains); lgkmcnt(4) so V-read latency
// hides under QK MFMAs.
__device__ __forceinline__ void tile_step(f32x4 s0, f32x4 s1, int kbase, int kmaxw, int qmb,
                                          short8 v0, short8 v1, short8 v2, short8 v3,
                                          f32x4 (&acc)[4], float& lrun) {
  if (kbase + 31 > kmaxw - 15) {       // diagonal chunk: per-element causal mask
#pragma unroll
    for (int r = 0; r < 4; ++r) {
      const int off = (r & 1) + ((r & 2) << 2);   // 0,1,8,9
      if (kbase + off > qmb)      s0[r] = -INFINITY;
      if (kbase + 16 + off > qmb) s1[r] = -INFINITY;
    }
  }
  float p0 = __builtin_amdgcn_exp2f(s0[0]), p1 = __builtin_amdgcn_exp2f(s0[1]);
  float p2 = __builtin_amdgcn_exp2f(s0[2]), p3 = __builtin_amdgcn_exp2f(s0[3]);
  float p4 = __builtin_amdgcn_exp2f(s1[0]), p5 = __builtin_amdgcn_exp2f(s1[1]);
  float p6 = __builtin_amdgcn_exp2f(s1[2]), p7 = __builtin_amdgcn_exp2f(s1[3]);
  lrun += ((p0 + p1) + (p2 + p3)) + ((p4 + p5) + (p6 + p7));
  unsigned u0 = pkbf(p0, p1);
  unsigned u1 = pkbf(p2, p3);
  unsigned u2 = pkbf(p4, p5);
  unsigned u3 = pkbf(p6, p7);
  perm16p(u0, u1);
  perm16p(u2, u3);
  perm32p(u0, u2);
  perm32p(u1, u3);
  union { unsigned u[4]; short8 s; } pw;
  pw.u[0] = u0; pw.u[1] = u2; pw.u[2] = u1; pw.u[3] = u3;
  const short8 pf = pw.s;
  acc[0] = mfma16(v0, pf, acc[0]);
  acc[1] = mfma16(v1, pf, acc[1]);
  acc[2] = mfma16(v2, pf, acc[2]);
  acc[3] = mfma16(v3, pf, acc[3]);
}

__device__ __forceinline__ void store_tile(__hip_bfloat16* Ylds, f32x4 (&acc)[4],
                                           float lrun, int q0, int w, int l,
                                           int lr, int lg, int bh,
                                           __hip_bfloat16* __restrict__ Y) {
  lrun += __shfl_xor(lrun, 16);
  lrun += __shfl_xor(lrun, 32);
  const float inv = 1.f / lrun;
#pragma unroll
  for (int nb = 0; nb < 4; ++nb) {
#pragma unroll
    for (int r = 0; r < 4; ++r) {
      const int d = nb * 16 + lg * 4 + r;
      Ylds[swz64(lr, d)] = __float2bfloat16(acc[nb][r] * inv);
    }
  }
  const int rr = l >> 2, part = l & 3;
  const int trow = q0 + w * 16 + rr;
  const int b = bh >> 4, h = bh & 15;
  short8 y0 = *reinterpret_cast<const short8*>(&Ylds[swz64(rr, part * 16)]);
  short8 y1 = *reinterpret_cast<const short8*>(&Ylds[swz64(rr, part * 16 + 8)]);
  __hip_bfloat16* dst = Y + ((size_t)b * TT + trow) * 1024 + h * 64 + part * 16;
  *reinterpret_cast<short8*>(dst) = y0;
  *reinterpret_cast<short8*>(dst + 8) = y1;
}

__global__ __launch_bounds__(256, 2) void k_flash(const __hip_bfloat16* __restrict__ Qb,
                                                  const __hip_bfloat16* __restrict__ Kb,
                                                  const __hip_bfloat16* __restrict__ Vtb,
                                                  __hip_bfloat16* __restrict__ Y) {
  __shared__ __hip_bfloat16 Klds[2][128 * 64];
  __shared__ __hip_bfloat16 Vtlds[2][64 * 128];
  const int tid = threadIdx.x;
  const int l = tid & 63, w = tid >> 6;
  const int lr = l & 15, lg = l >> 4;
  const int p  = blockIdx.x >> 6;       // pair index 0..15
  const int bh = blockIdx.x & 63;
  const int q0A = p * 64, q0B = (31 - p) * 64;
  const __hip_bfloat16* Qp = Qb + (size_t)bh * TT * 64;
  const __hip_bfloat16* Kp = Kb + (size_t)bh * TT * 64;
  const __hip_bfloat16* Vp = Vtb + (size_t)bh * 64 * TT;
  const int qrowA = q0A + w * 16 + lr;
  const int qrowB = q0B + w * 16 + lr;
  const short8 qfA0 = *reinterpret_cast<const short8*>(Qp + (size_t)qrowA * 64 + lg * 8);
  const short8 qfA1 = *reinterpret_cast<const short8*>(Qp + (size_t)qrowA * 64 + 32 + lg * 8);
  const short8 qfB0 = *reinterpret_cast<const short8*>(Qp + (size_t)qrowB * 64 + lg * 8);
  const short8 qfB1 = *reinterpret_cast<const short8*>(Qp + (size_t)qrowB * 64 + 32 + lg * 8);
  f32x4 accA[4] = {}, accB[4] = {};
  float lA = 0.f, lB = 0.f;

  const int ka  = lr * 64 + ((lg ^ (lr & 7)) << 3);
  const int va  = lr * 128 + ((lg ^ (lr & 15)) << 3);
  const unsigned kaB = (unsigned)(uintptr_t)&Klds[0][0] + 2u * (unsigned)ka;
  const unsigned vaB = (unsigned)(uintptr_t)&Vtlds[0][0] + 2u * (unsigned)va;

  const __hip_bfloat16* gk[4];
  const __hip_bfloat16* gv[4];
  __hip_bfloat16* lk[4];
  __hip_bfloat16* lv[4];
#pragma unroll
  for (int it = 0; it < 4; ++it) {
    int e = it * 2048 + tid * 8;
    int rowk = e >> 6;
    int lcolk = ((((e >> 3) & 7) ^ (rowk & 7)) << 3);
    int rk = rowk & 15;
    int srk = (((rk >> 1) ^ (rk >> 3)) & 1) ? (rk ^ 10) : rk;
    int rowks = (rowk & ~15) | srk;
    gk[it] = Kp + (size_t)rowks * 64 + lcolk;
    lk[it] = &Klds[0][e];
    int rowv = e >> 7;
    int lcolv = ((((e >> 3) & 15) ^ (rowv & 15)) << 3);
    gv[it] = Vp + (size_t)rowv * TT + lcolv;
    lv[it] = &Vtlds[0][e];
  }

  const int kmaxwA = q0A + w * 16 + 15;
  const int kmaxwB = q0B + w * 16 + 15;
  const int base_lg = ((lg & 1) << 2) | (lg & 2);
  const int qmbA = qrowA - base_lg;
  const int qmbB = qrowB - base_lg;
  const int nblk = (q0B + 63) / 128 + 1;

  // prologue: stage block 0 into slot 0
#pragma unroll
  for (int it = 0; it < 4; ++it) { gl_lds16(gk[it], lk[it]); gk[it] += 8192; }
#pragma unroll
  for (int it = 0; it < 4; ++it) { gl_lds16(gv[it], lv[it]); gv[it] += 128; }

  for (int blk = 0; blk < nblk; ++blk) {
    const int kv0 = blk * 128;
    const unsigned so = (unsigned)((blk & 1) << 14);   // slot byte offset
    if (blk + 1 < nblk) {
      const int sn = ((blk + 1) & 1) << 13;            // slot elem offset
#pragma unroll
      for (int it = 0; it < 4; ++it) { gl_lds16(gk[it], lk[it] + sn); gk[it] += 8192; }
#pragma unroll
      for (int it = 0; it < 4; ++it) { gl_lds16(gv[it], lv[it] + sn); gv[it] += 128; }
      VMCNT8;        // current block's 8 loads retired; next block's 8 in flight
    } else {
      VMCNT0;
    }
    BARRIER;
#pragma unroll
    for (int kci = 0; kci < 4; ++kci) {
      const int kbase = kv0 + kci * 32;
      if (kbase > kmaxwB) break;       // wave-uniform (B bounds the pair)
      const unsigned kA  = kaB + so + (unsigned)(kci * 4096);
      const unsigned kAx = kA ^ 64u;
      const unsigned vA  = (vaB + so) ^ (unsigned)(kci * 64);
      const short8 kf00 = ldsr_o0(kA);
      const short8 kf10 = ldsr_o1(kA);
      const short8 kf01 = ldsr_o0(kAx);
      const short8 kf11 = ldsr_o1(kAx);
      const short8 v0 = ldsr_o0(vA);
      const short8 v1 = ldsr_o2(vA);
      const short8 v2 = ldsr_o4(vA);
      const short8 v3 = ldsr_o6(vA);
      LGKM4;                            // K frags ready; V still in flight
      f32x4 sB0 = {}, sB1 = {};
      sB0 = mfma16(kf00, qfB0, sB0);
      sB1 = mfma16(kf10, qfB0, sB1);
      sB0 = mfma16(kf01, qfB1, sB0);
      sB1 = mfma16(kf11, qfB1, sB1);
      const bool aAct = (kbase <= kmaxwA);
      f32x4 sA0 = {}, sA1 = {};
      if (aAct) {
        sA0 = mfma16(kf00, qfA0, sA0);
        sA1 = mfma16(kf10, qfA0, sA1);
        sA0 = mfma16(kf01, qfA1, sA0);
        sA1 = mfma16(kf11, qfA1, sA1);
      }
      LGKM0;                            // V frags ready (long since done)
      tile_step(sB0, sB1, kbase, kmaxwB, qmbB, v0, v1, v2, v3, accB, lB);
      if (aAct)
        tile_step(sA0, sA1, kbase, kmaxwA, qmbA, v0, v1, v2, v3, accA, lA);
    }
    BARRIER;
  }
  __hip_bfloat16* Ylds = &Klds[0][0] + w * 1024;
  store_tile(Ylds, accA, lA, q0A, w, l, lr, lg, bh, Y);
  store_tile(Ylds, accB, lB, q0B, w, l, lr, lg, bh, Y);
}

// ---------------- launch ----------------
extern "C" void kernel_launch(void* const* d_in, const int* in_sizes, int n_in,
                              void* d_out, int out_size, void* d_ws, size_t ws_size,
                              hipStream_t stream) {
  const float* x     = (const float*)d_in[0];
  const float* Wqkv  = (const float*)d_in[1];
  const float* bqkv  = (const float*)d_in[2];
  const float* Wproj = (const float*)d_in[3];
  const float* bproj = (const float*)d_in[4];

  char* ws = (char*)d_ws;
  size_t off = 0;
  auto alloc = [&](size_t bytes) {
    char* p = ws + off;
    off += (bytes + 255) & ~(size_t)255;
    return p;
  };
  __hip_bfloat16* xb    = (__hip_bfloat16*)alloc((size_t)MTOT * 1024 * 2);
  __hip_bfloat16* wqkvT = (__hip_bfloat16*)alloc((size_t)3072 * 1024 * 2);
  __hip_bfloat16* wpT   = (__hip_bfloat16*)alloc((size_t)1024 * 1024 * 2);
  __hip_bfloat16* Qb    = (__hip_bfloat16*)alloc((size_t)64 * TT * 64 * 2);
  __hip_bfloat16* Kb    = (__hip_bfloat16*)alloc((size_t)64 * TT * 64 * 2);
  __hip_bfloat16* Vtb   = (__hip_bfloat16*)alloc((size_t)64 * TT * 64 * 2);
  __hip_bfloat16* Yb    = (__hip_bfloat16*)alloc((size_t)MTOT * 1024 * 2);

  k_cvt<<<(MTOT * 1024 / 8 + 255) / 256, 256, 0, stream>>>(x, xb, MTOT * 1024 / 8);
  k_transpose_cvt<<<dim3(3072 / 32, 1024 / 32), 256, 0, stream>>>(Wqkv, wqkvT, 1024, 3072);
  k_transpose_cvt<<<dim3(1024 / 32, 1024 / 32), 256, 0, stream>>>(Wproj, wpT, 1024, 1024);
  k_gemm3<<<dim3(32, 16), 512, 0, stream>>>(xb, wqkvT, bqkv, Qb, Kb, Vtb);
  k_flash<<<16 * 64, 256, 0, stream>>>(Qb, Kb, Vtb, Yb);
  k_gemm2<<<dim3(32, 8), 512, 0, stream>>>(Yb, wpT, bproj, (float*)d_out);
}

// Round 12
// 154.740 us; speedup vs baseline: 1.2245x; 1.0687x over previous
//
#include <hip/hip_runtime.h>
#include <hip/hip_bf16.h>
#include <cstdint>
#include <math.h>

// Problem constants
#define DM   1024
#define NH   16
#define DH   64
#define BB   4
#define TT   2048
#define MTOT (BB*TT)   // 8192 rows

using short8 = __attribute__((ext_vector_type(8))) short;  // 8 bf16 (4 VGPRs)
using f32x4  = __attribute__((ext_vector_type(4))) float;

__device__ __forceinline__ f32x4 mfma16(short8 a, short8 b, f32x4 c) {
  return __builtin_amdgcn_mfma_f32_16x16x32_bf16(a, b, c, 0, 0, 0);
}

typedef const __attribute__((address_space(1))) unsigned int* as1_u32p;
typedef __attribute__((address_space(3))) unsigned int*       as3_u32p;

// async global->LDS, 16B per lane; LDS dest = wave-uniform base + lane*16 (linear)
__device__ __forceinline__ void gl_lds16(const void* g, void* l) {
  __builtin_amdgcn_global_load_lds(
      (as1_u32p)(reinterpret_cast<uintptr_t>(g)),
      (as3_u32p)((unsigned int)(reinterpret_cast<uintptr_t>(l))),
      16, 0, 0);
}

// XOR swizzle for tiles with 64-elem (128B) rows: 8 slots of 8 bf16; slot ^= row&7
__device__ __forceinline__ int swz64(int row, int col) {
  return row*64 + ((((col >> 3) ^ (row & 7)) << 3) | (col & 7));
}

__device__ __forceinline__ unsigned pkbf(float a, float b) {
  __hip_bfloat162 h = __float22bfloat162_rn(make_float2(a, b)); // x=lo, y=hi
  return *reinterpret_cast<unsigned*>(&h);
}

// permlane swaps (VALU pipe). Verified row semantics (involutions):
// perm16(d,s): d'=[d0,s0,d2,s2], s'=[d1,s1,d3,s3]   (16-lane rows)
// perm32(d,s): d'=[d0,d1,s0,s1], s'=[d2,d3,s2,s3]
__device__ __forceinline__ void perm16p(unsigned &a, unsigned &b) {
  asm("v_permlane16_swap_b32 %0, %1" : "+v"(a), "+v"(b));
}
__device__ __forceinline__ void perm32p(unsigned &a, unsigned &b) {
  asm("v_permlane32_swap_b32 %0, %1" : "+v"(a), "+v"(b));
}

// inline-asm LDS reads (opaque to alias analysis: no compiler-inserted vmcnt drains)
__device__ __forceinline__ short8 ldsr_o0(unsigned a) {
  short8 r; asm volatile("ds_read_b128 %0, %1" : "=v"(r) : "v"(a)); return r;
}
__device__ __forceinline__ short8 ldsr_o1(unsigned a) {
  short8 r; asm volatile("ds_read_b128 %0, %1 offset:2048" : "=v"(r) : "v"(a)); return r;
}
__device__ __forceinline__ short8 ldsr_o2(unsigned a) {
  short8 r; asm volatile("ds_read_b128 %0, %1 offset:4096" : "=v"(r) : "v"(a)); return r;
}
__device__ __forceinline__ short8 ldsr_o3(unsigned a) {
  short8 r; asm volatile("ds_read_b128 %0, %1 offset:6144" : "=v"(r) : "v"(a)); return r;
}
__device__ __forceinline__ short8 ldsr_o4(unsigned a) {
  short8 r; asm volatile("ds_read_b128 %0, %1 offset:8192" : "=v"(r) : "v"(a)); return r;
}
__device__ __forceinline__ short8 ldsr_o5(unsigned a) {
  short8 r; asm volatile("ds_read_b128 %0, %1 offset:10240" : "=v"(r) : "v"(a)); return r;
}

#define LGKM0  do { asm volatile("s_waitcnt lgkmcnt(0)"); __builtin_amdgcn_sched_barrier(0); } while(0)
#define VMCNT6 do { __builtin_amdgcn_sched_barrier(0); asm volatile("s_waitcnt vmcnt(6)"); __builtin_amdgcn_sched_barrier(0); } while(0)
#define VMCNT0 do { __builtin_amdgcn_sched_barrier(0); asm volatile("s_waitcnt vmcnt(0)"); __builtin_amdgcn_sched_barrier(0); } while(0)
#define BARRIER do { __builtin_amdgcn_s_barrier(); __builtin_amdgcn_sched_barrier(0); } while(0)

// ---------------- fp32 -> bf16 copy convert ----------------
__global__ __launch_bounds__(256) void k_cvt(const float* __restrict__ in,
                                             __hip_bfloat16* __restrict__ out, int n8) {
  int i = blockIdx.x * 256 + threadIdx.x;
  if (i >= n8) return;
  const float* p = in + (size_t)i * 8;
  short8 o;
#pragma unroll
  for (int j = 0; j < 8; ++j) {
    __hip_bfloat16 h = __float2bfloat16(p[j]);
    o[j] = *reinterpret_cast<short*>(&h);
  }
  *reinterpret_cast<short8*>(out + (size_t)i * 8) = o;
}

// ---------------- W [K][N] fp32 -> Wt [N][K] bf16 (tiled transpose) ----------------
__global__ __launch_bounds__(256) void k_transpose_cvt(const float* __restrict__ W,
                                                       __hip_bfloat16* __restrict__ Wt,
                                                       int K, int N) {
  __shared__ float tbuf[32][33];
  const int n0 = blockIdx.x * 32, k0 = blockIdx.y * 32;
  const int tx = threadIdx.x & 31, ty = threadIdx.x >> 5;
#pragma unroll
  for (int i = 0; i < 4; ++i)
    tbuf[ty + i*8][tx] = W[(size_t)(k0 + ty + i*8) * N + n0 + tx];
  __syncthreads();
#pragma unroll
  for (int i = 0; i < 4; ++i)
    Wt[(size_t)(n0 + ty + i*8) * K + k0 + tx] = __float2bfloat16(tbuf[tx][ty + i*8]);
}

// ---------------- 256x192 double-buffered deep-pipeline QKV GEMM (r9-proven) ----------------
__global__ __launch_bounds__(512, 2) void k_gemm3(const __hip_bfloat16* __restrict__ A,
                                                  const __hip_bfloat16* __restrict__ Bt,
                                                  const float* __restrict__ bias,
                                                  __hip_bfloat16* __restrict__ Qb,
                                                  __hip_bfloat16* __restrict__ Kb,
                                                  __hip_bfloat16* __restrict__ Vtb) {
  __shared__ __hip_bfloat16 As[2][256 * 64];
  __shared__ __hip_bfloat16 Bs[2][192 * 64];
  const int tid = threadIdx.x;
  const int l = tid & 63, w = tid >> 6;
  const int lr = l & 15, lg = l >> 4;
  const int wm = w >> 1, wn = w & 1;
  const int m0 = blockIdx.x * 256, n0 = blockIdx.y * 192;

  const int srow = tid >> 3;
  const int scol = (((tid & 7) ^ (srow & 7)) << 3);
  const size_t aoffs = (size_t)(m0 + srow) * 1024 + scol;
  const size_t boffs = (size_t)(n0 + srow) * 1024 + scol;
  const int ldst = tid * 8;

  auto stage = [&](int t, int s) {
    const int k0 = t * 64;
#pragma unroll
    for (int rd = 0; rd < 4; ++rd)
      gl_lds16(A + aoffs + (size_t)rd * 65536 + k0, &As[s][rd * 4096 + ldst]);
#pragma unroll
    for (int rd = 0; rd < 3; ++rd)
      gl_lds16(Bt + boffs + (size_t)rd * 65536 + k0, &Bs[s][rd * 4096 + ldst]);
  };

  const unsigned asLds = (unsigned)(uintptr_t)&As[0][0];
  const unsigned bsLds = (unsigned)(uintptr_t)&Bs[0][0];
  const unsigned aBase0 = asLds + 2u * ((wm*64 + lr) * 64 + ((lg ^ (lr & 7)) << 3));
  const unsigned bBase0 = bsLds + 2u * ((wn*96 + lr) * 64 + ((lg ^ (lr & 7)) << 3));

  stage(0, 0);
  VMCNT0;
  BARRIER;

  f32x4 acc[4][6] = {};
  short8 a_[4][2], b_[3][2];

#pragma unroll
  for (int t = 0; t < 16; ++t) {
    const int s = t & 1;
    const unsigned aB0 = aBase0 + (unsigned)s * 32768u;
    const unsigned aB1 = aB0 ^ 64u;
    const unsigned bB0 = bBase0 + (unsigned)s * 24576u;
    const unsigned bB1 = bB0 ^ 64u;
    if (t < 15) stage(t + 1, s ^ 1);
    // phase A: A frags + B n0..2, MFMA n=0..2
    a_[0][0] = ldsr_o0(aB0); a_[1][0] = ldsr_o1(aB0); a_[2][0] = ldsr_o2(aB0); a_[3][0] = ldsr_o3(aB0);
    a_[0][1] = ldsr_o0(aB1); a_[1][1] = ldsr_o1(aB1); a_[2][1] = ldsr_o2(aB1); a_[3][1] = ldsr_o3(aB1);
    b_[0][0] = ldsr_o0(bB0); b_[1][0] = ldsr_o1(bB0); b_[2][0] = ldsr_o2(bB0);
    b_[0][1] = ldsr_o0(bB1); b_[1][1] = ldsr_o1(bB1); b_[2][1] = ldsr_o2(bB1);
    LGKM0;
    __builtin_amdgcn_s_setprio(1);
#pragma unroll
    for (int m = 0; m < 4; ++m)
#pragma unroll
      for (int n = 0; n < 3; ++n)
#pragma unroll
        for (int ks = 0; ks < 2; ++ks)
          acc[m][n] = mfma16(a_[m][ks], b_[n][ks], acc[m][n]);
    __builtin_amdgcn_s_setprio(0);
    // phase B: B n3..5, MFMA n=3..5
    b_[0][0] = ldsr_o3(bB0); b_[1][0] = ldsr_o4(bB0); b_[2][0] = ldsr_o5(bB0);
    b_[0][1] = ldsr_o3(bB1); b_[1][1] = ldsr_o4(bB1); b_[2][1] = ldsr_o5(bB1);
    LGKM0;
    __builtin_amdgcn_s_setprio(1);
#pragma unroll
    for (int m = 0; m < 4; ++m)
#pragma unroll
      for (int n = 0; n < 3; ++n)
#pragma unroll
        for (int ks = 0; ks < 2; ++ks)
          acc[m][n + 3] = mfma16(a_[m][ks], b_[n][ks], acc[m][n + 3]);
    __builtin_amdgcn_s_setprio(0);
    if (t < 15) { VMCNT0; }
    BARRIER;
  }

  __syncthreads();
  // ---- per-16-col-group LDS-bounce epilogue ----
  __hip_bfloat16* reg = (w < 4) ? (&As[0][0] + w * 6144)
                                : (&Bs[0][0] + (w - 4) * 6144);
  const int colbase = n0 + wn * 96;
  const int rowbase = m0 + wm * 64;
  const int bidx = rowbase >> 11;
  const int tbase = rowbase & 2047;
  const float qs = 0.18033688011112042f;   // 0.125 * log2(e) folded into Q
  float bv[6];
#pragma unroll
  for (int g = 0; g < 6; ++g) bv[g] = bias[colbase + g * 16 + lr];
#pragma unroll
  for (int g = 0; g < 6; ++g) {
    const int cg0 = colbase + g * 16;
    const int which = cg0 >> 10;
    __hip_bfloat16* rg = reg + g * 1024;
    if (which == 2) {
#pragma unroll
      for (int m = 0; m < 4; ++m)
#pragma unroll
        for (int r = 0; r < 4; ++r) {
          const int t = m * 16 + lg * 4 + r;
          rg[lr * 64 + (t ^ ((lr & 7) << 3))] = __float2bfloat16(acc[m][g][r] + bv[g]);
        }
    } else {
      const float sc = (which == 0) ? qs : 1.f;
#pragma unroll
      for (int m = 0; m < 4; ++m)
#pragma unroll
        for (int r = 0; r < 4; ++r) {
          const int t = m * 16 + lg * 4 + r;
          rg[t * 16 + (lr ^ (((t >> 2) & 1) << 3))] =
              __float2bfloat16((acc[m][g][r] + bv[g]) * sc);
        }
    }
  }
#pragma unroll
  for (int g = 0; g < 6; ++g) {
    const int cg0 = colbase + g * 16;
    const int which = cg0 >> 10;
    const int hh = (cg0 >> 6) & 15;
    const int dd0 = cg0 & 48;
    const size_t bh = (size_t)bidx * 16 + hh;
    const __hip_bfloat16* rg = reg + g * 1024;
    if (which < 2) {
      __hip_bfloat16* basep = (which == 0) ? Qb : Kb;
      const int t = l;
      const int Xc = ((t >> 2) & 1) << 3;
      short8 y0 = *reinterpret_cast<const short8*>(&rg[t * 16 + Xc]);
      short8 y1 = *reinterpret_cast<const short8*>(&rg[t * 16 + (Xc ^ 8)]);
      __hip_bfloat16* dst = basep + (bh * TT + tbase + t) * 64 + dd0;
      *reinterpret_cast<short8*>(dst) = y0;
      *reinterpret_cast<short8*>(dst + 8) = y1;
    } else {
      const int dd = l >> 2, tseg = l & 3;
      const int X = (dd & 7) << 3;
      const int S0 = (((tseg ^ (X >> 4)) & 3) << 4) | (X & 8);
      short8 y0 = *reinterpret_cast<const short8*>(&rg[dd * 64 + S0]);
      short8 y1 = *reinterpret_cast<const short8*>(&rg[dd * 64 + (S0 ^ 8)]);
      __hip_bfloat16* dst = Vtb + (bh * 64 + dd0 + dd) * TT + tbase + tseg * 16;
      *reinterpret_cast<short8*>(dst) = y0;
      *reinterpret_cast<short8*>(dst + 8) = y1;
    }
  }
}

// ---------------- 256x128 triple-buffered deep-pipeline GEMM (proj) ----------------
__global__ __launch_bounds__(512, 2) void k_gemm2(const __hip_bfloat16* __restrict__ A,
                                                  const __hip_bfloat16* __restrict__ Bt,
                                                  const float* __restrict__ bias,
                                                  float* __restrict__ outF) {
  __shared__ __hip_bfloat16 As[3][256 * 64];
  __shared__ __hip_bfloat16 Bs[3][128 * 64];
  const int tid = threadIdx.x;
  const int l = tid & 63, w = tid >> 6;
  const int lr = l & 15, lg = l >> 4;
  const int wm = w >> 1, wn = w & 1;
  const int m0 = blockIdx.x * 256, n0 = blockIdx.y * 128;

  const int srow = tid >> 3;
  const int scol = (((tid & 7) ^ (srow & 7)) << 3);
  const size_t aoffs = (size_t)(m0 + srow) * 1024 + scol;
  const size_t boffs = (size_t)(n0 + srow) * 1024 + scol;
  const int ldst = tid * 8;

  auto stage = [&](int t, int s) {
    const int k0 = t * 64;
    __hip_bfloat16* as_ = &As[s][0];
    __hip_bfloat16* bs_ = &Bs[s][0];
#pragma unroll
    for (int rd = 0; rd < 4; ++rd)
      gl_lds16(A + aoffs + (size_t)rd * 65536 + k0, as_ + rd * 4096 + ldst);
#pragma unroll
    for (int rd = 0; rd < 2; ++rd)
      gl_lds16(Bt + boffs + (size_t)rd * 65536 + k0, bs_ + rd * 4096 + ldst);
  };

  const unsigned asLds = (unsigned)(uintptr_t)&As[0][0];
  const unsigned bsLds = (unsigned)(uintptr_t)&Bs[0][0];
  const unsigned aBase = asLds + 2u * ((wm*64 + lr) * 64 + ((lg ^ (lr & 7)) << 3));
  const unsigned bBase = bsLds + 2u * ((wn*64 + lr) * 64 + ((lg ^ (lr & 7)) << 3));

  stage(0, 0);
  stage(1, 1);
  VMCNT6;
  BARRIER;

  f32x4 acc[4][4] = {};
  short8 a_[4][2], b_[2][2];

#pragma unroll
  for (int t = 0; t < 16; ++t) {
    const int s = t % 3;
    const unsigned aB0 = aBase + (unsigned)s * 32768u;
    const unsigned aB1 = aB0 ^ 64u;
    const unsigned bB0 = bBase + (unsigned)s * 16384u;
    const unsigned bB1 = bB0 ^ 64u;
    if (t + 2 < 16) stage(t + 2, (t + 2) % 3);
    a_[0][0] = ldsr_o0(aB0); a_[1][0] = ldsr_o1(aB0); a_[2][0] = ldsr_o2(aB0); a_[3][0] = ldsr_o3(aB0);
    a_[0][1] = ldsr_o0(aB1); a_[1][1] = ldsr_o1(aB1); a_[2][1] = ldsr_o2(aB1); a_[3][1] = ldsr_o3(aB1);
    b_[0][0] = ldsr_o0(bB0); b_[1][0] = ldsr_o1(bB0);
    b_[0][1] = ldsr_o0(bB1); b_[1][1] = ldsr_o1(bB1);
    LGKM0;
    __builtin_amdgcn_s_setprio(1);
#pragma unroll
    for (int m = 0; m < 4; ++m)
#pragma unroll
      for (int n = 0; n < 2; ++n)
#pragma unroll
        for (int ks = 0; ks < 2; ++ks)
          acc[m][n] = mfma16(a_[m][ks], b_[n][ks], acc[m][n]);
    __builtin_amdgcn_s_setprio(0);
    b_[0][0] = ldsr_o2(bB0); b_[1][0] = ldsr_o3(bB0);
    b_[0][1] = ldsr_o2(bB1); b_[1][1] = ldsr_o3(bB1);
    LGKM0;
    __builtin_amdgcn_s_setprio(1);
#pragma unroll
    for (int m = 0; m < 4; ++m)
#pragma unroll
      for (int n = 0; n < 2; ++n)
#pragma unroll
        for (int ks = 0; ks < 2; ++ks)
          acc[m][n + 2] = mfma16(a_[m][ks], b_[n][ks], acc[m][n + 2]);
    __builtin_amdgcn_s_setprio(0);
    if (t <= 13) { VMCNT6; }
    else if (t == 14) { VMCNT0; }
    BARRIER;
  }

  __syncthreads();
#pragma unroll
  for (int n = 0; n < 4; ++n) {
    const int col = n0 + wn * 64 + n * 16 + lr;
    const float bvv = bias[col];
#pragma unroll
    for (int m = 0; m < 4; ++m)
#pragma unroll
      for (int r = 0; r < 4; ++r) {
        const int row = m0 + wm * 64 + m * 16 + lg * 4 + r;
        outF[(size_t)row * 1024 + col] = acc[m][n][r] + bvv;
      }
  }
}

// ---------------- causal flash attention (per-wave tile ownership) ----------------
// Block = q-tile pair {p, 31-p}; waves 0,1 own tile A (32 rows each = 2 q-frags),
// waves 2,3 own tile B. Each 8-read K/V chunk event now feeds 16 MFMA ALWAYS
// (2 frags share the reads) -> DS-read events -32%. Fixed-max softmax, sigma-permuted
// K rows (permlane P-redistribution), per-wave causal early exit.
__device__ __forceinline__ void tile_step(f32x4 s0, f32x4 s1, int kbase, int kmaxw, int qmb,
                                          short8 v0, short8 v1, short8 v2, short8 v3,
                                          f32x4 (&acc)[4], float& lrun) {
  if (kbase + 31 > kmaxw - 15) {       // diagonal/overflow chunk: per-element causal mask
#pragma unroll
    for (int r = 0; r < 4; ++r) {
      const int off = (r & 1) + ((r & 2) << 2);   // 0,1,8,9
      if (kbase + off > qmb)      s0[r] = -INFINITY;
      if (kbase + 16 + off > qmb) s1[r] = -INFINITY;
    }
  }
  float p0 = __builtin_amdgcn_exp2f(s0[0]), p1 = __builtin_amdgcn_exp2f(s0[1]);
  float p2 = __builtin_amdgcn_exp2f(s0[2]), p3 = __builtin_amdgcn_exp2f(s0[3]);
  float p4 = __builtin_amdgcn_exp2f(s1[0]), p5 = __builtin_amdgcn_exp2f(s1[1]);
  float p6 = __builtin_amdgcn_exp2f(s1[2]), p7 = __builtin_amdgcn_exp2f(s1[3]);
  lrun += ((p0 + p1) + (p2 + p3)) + ((p4 + p5) + (p6 + p7));
  unsigned u0 = pkbf(p0, p1);
  unsigned u1 = pkbf(p2, p3);
  unsigned u2 = pkbf(p4, p5);
  unsigned u3 = pkbf(p6, p7);
  perm16p(u0, u1);
  perm16p(u2, u3);
  perm32p(u0, u2);
  perm32p(u1, u3);
  union { unsigned u[4]; short8 s; } pw;
  pw.u[0] = u0; pw.u[1] = u2; pw.u[2] = u1; pw.u[3] = u3;
  const short8 pf = pw.s;
  acc[0] = mfma16(v0, pf, acc[0]);
  acc[1] = mfma16(v1, pf, acc[1]);
  acc[2] = mfma16(v2, pf, acc[2]);
  acc[3] = mfma16(v3, pf, acc[3]);
}

__device__ __forceinline__ void store_tile(__hip_bfloat16* Ylds, f32x4 (&acc)[4],
                                           float lrun, int rowbase, int l,
                                           int lr, int lg, int bh,
                                           __hip_bfloat16* __restrict__ Y) {
  lrun += __shfl_xor(lrun, 16);
  lrun += __shfl_xor(lrun, 32);
  const float inv = 1.f / lrun;
#pragma unroll
  for (int nb = 0; nb < 4; ++nb) {
#pragma unroll
    for (int r = 0; r < 4; ++r) {
      const int d = nb * 16 + lg * 4 + r;
      Ylds[swz64(lr, d)] = __float2bfloat16(acc[nb][r] * inv);
    }
  }
  const int rr = l >> 2, part = l & 3;
  const int trow = rowbase + rr;
  const int b = bh >> 4, h = bh & 15;
  short8 y0 = *reinterpret_cast<const short8*>(&Ylds[swz64(rr, part * 16)]);
  short8 y1 = *reinterpret_cast<const short8*>(&Ylds[swz64(rr, part * 16 + 8)]);
  __hip_bfloat16* dst = Y + ((size_t)b * TT + trow) * 1024 + h * 64 + part * 16;
  *reinterpret_cast<short8*>(dst) = y0;
  *reinterpret_cast<short8*>(dst + 8) = y1;
}

__global__ __launch_bounds__(256, 4) void k_flash(const __hip_bfloat16* __restrict__ Qb,
                                                  const __hip_bfloat16* __restrict__ Kb,
                                                  const __hip_bfloat16* __restrict__ Vtb,
                                                  __hip_bfloat16* __restrict__ Y) {
  __shared__ __hip_bfloat16 Klds[128 * 64];
  __shared__ __hip_bfloat16 Vtlds[64 * 128];
  const int tid = threadIdx.x;
  const int l = tid & 63, w = tid >> 6;
  const int lr = l & 15, lg = l >> 4;
  const int p  = blockIdx.x >> 6;       // pair index 0..15
  const int bh = blockIdx.x & 63;
  const int q0A = p * 64, q0B = (31 - p) * 64;
  const int q0w = ((w >> 1) ? q0B : q0A) + (w & 1) * 32;   // wave's 32-row slice
  const __hip_bfloat16* Qp = Qb + (size_t)bh * TT * 64;
  const __hip_bfloat16* Kp = Kb + (size_t)bh * TT * 64;
  const __hip_bfloat16* Vp = Vtb + (size_t)bh * 64 * TT;
  const int qrow0 = q0w + lr;
  const int qrow1 = q0w + 16 + lr;
  const short8 qf00 = *reinterpret_cast<const short8*>(Qp + (size_t)qrow0 * 64 + lg * 8);
  const short8 qf01 = *reinterpret_cast<const short8*>(Qp + (size_t)qrow0 * 64 + 32 + lg * 8);
  const short8 qf10 = *reinterpret_cast<const short8*>(Qp + (size_t)qrow1 * 64 + lg * 8);
  const short8 qf11 = *reinterpret_cast<const short8*>(Qp + (size_t)qrow1 * 64 + 32 + lg * 8);
  f32x4 acc0[4] = {}, acc1[4] = {};
  float l0 = 0.f, l1 = 0.f;

  const int ka  = lr * 64 + ((lg ^ (lr & 7)) << 3);
  const int va  = lr * 128 + ((lg ^ (lr & 15)) << 3);

  const __hip_bfloat16* gk[4];
  const __hip_bfloat16* gv[4];
  __hip_bfloat16* lk[4];
  __hip_bfloat16* lv[4];
#pragma unroll
  for (int it = 0; it < 4; ++it) {
    int e = it * 2048 + tid * 8;
    int rowk = e >> 6;
    int lcolk = ((((e >> 3) & 7) ^ (rowk & 7)) << 3);
    int rk = rowk & 15;
    int srk = (((rk >> 1) ^ (rk >> 3)) & 1) ? (rk ^ 10) : rk;
    int rowks = (rowk & ~15) | srk;
    gk[it] = Kp + (size_t)rowks * 64 + lcolk;
    lk[it] = &Klds[e];
    int rowv = e >> 7;
    int lcolv = ((((e >> 3) & 15) ^ (rowv & 15)) << 3);
    gv[it] = Vp + (size_t)rowv * TT + lcolv;
    lv[it] = &Vtlds[e];
  }

  const int kmaxw = q0w + 31;           // wave-uniform causal bound
  const int kmax0 = q0w + 15;           // frag0's own bound (mask trigger)
  const int base_lg = ((lg & 1) << 2) | (lg & 2);
  const int qmb0 = qrow0 - base_lg;
  const int qmb1 = qrow1 - base_lg;
  const int nblk = (q0B + 63) / 128 + 1;   // B's range covers A's
  for (int blk = 0; blk < nblk; ++blk) {
    const int kv0 = blk * 128;
#pragma unroll
    for (int it = 0; it < 4; ++it) {
      gl_lds16(gk[it], lk[it]);
      gk[it] += 128 * 64;
    }
#pragma unroll
    for (int it = 0; it < 4; ++it) {
      gl_lds16(gv[it], lv[it]);
      gv[it] += 128;
    }
    __syncthreads();
#pragma unroll
    for (int kci = 0; kci < 4; ++kci) {
      const int kbase = kv0 + kci * 32;
      if (kbase > kmaxw) break;        // wave-uniform early exit
      // shared K fragments (serve both q-frags)
      const int kb = ka + kci * 2048;
      const short8 kf00 = *reinterpret_cast<const short8*>(&Klds[kb]);
      const short8 kf10 = *reinterpret_cast<const short8*>(&Klds[kb + 1024]);
      const short8 kf01 = *reinterpret_cast<const short8*>(&Klds[kb ^ 32]);
      const short8 kf11 = *reinterpret_cast<const short8*>(&Klds[(kb + 1024) ^ 32]);
      // shared V fragments
      const int vb = va ^ (kci * 32);
      const short8 v0 = *reinterpret_cast<const short8*>(&Vtlds[vb]);
      const short8 v1 = *reinterpret_cast<const short8*>(&Vtlds[vb + 2048]);
      const short8 v2 = *reinterpret_cast<const short8*>(&Vtlds[vb + 4096]);
      const short8 v3 = *reinterpret_cast<const short8*>(&Vtlds[vb + 6144]);
      f32x4 s00 = {}, s01 = {};
      s00 = mfma16(kf00, qf00, s00);
      s01 = mfma16(kf10, qf00, s01);
      s00 = mfma16(kf01, qf01, s00);
      s01 = mfma16(kf11, qf01, s01);
      f32x4 s10 = {}, s11 = {};
      s10 = mfma16(kf00, qf10, s10);
      s11 = mfma16(kf10, qf10, s11);
      s10 = mfma16(kf01, qf11, s10);
      s11 = mfma16(kf11, qf11, s11);
      tile_step(s00, s01, kbase, kmax0, qmb0, v0, v1, v2, v3, acc0, l0);
      tile_step(s10, s11, kbase, kmaxw, qmb1, v0, v1, v2, v3, acc1, l1);
    }
    __syncthreads();
  }
  __hip_bfloat16* Ylds = Klds + w * 1024;
  store_tile(Ylds, acc0, l0, q0w,      l, lr, lg, bh, Y);
  store_tile(Ylds, acc1, l1, q0w + 16, l, lr, lg, bh, Y);
}

// ---------------- launch ----------------
extern "C" void kernel_launch(void* const* d_in, const int* in_sizes, int n_in,
                              void* d_out, int out_size, void* d_ws, size_t ws_size,
                              hipStream_t stream) {
  const float* x     = (const float*)d_in[0];
  const float* Wqkv  = (const float*)d_in[1];
  const float* bqkv  = (const float*)d_in[2];
  const float* Wproj = (const float*)d_in[3];
  const float* bproj = (const float*)d_in[4];

  char* ws = (char*)d_ws;
  size_t off = 0;
  auto alloc = [&](size_t bytes) {
    char* p = ws + off;
    off += (bytes + 255) & ~(size_t)255;
    return p;
  };
  __hip_bfloat16* xb    = (__hip_bfloat16*)alloc((size_t)MTOT * 1024 * 2);
  __hip_bfloat16* wqkvT = (__hip_bfloat16*)alloc((size_t)3072 * 1024 * 2);
  __hip_bfloat16* wpT   = (__hip_bfloat16*)alloc((size_t)1024 * 1024 * 2);
  __hip_bfloat16* Qb    = (__hip_bfloat16*)alloc((size_t)64 * TT * 64 * 2);
  __hip_bfloat16* Kb    = (__hip_bfloat16*)alloc((size_t)64 * TT * 64 * 2);
  __hip_bfloat16* Vtb   = (__hip_bfloat16*)alloc((size_t)64 * TT * 64 * 2);
  __hip_bfloat16* Yb    = (__hip_bfloat16*)alloc((size_t)MTOT * 1024 * 2);

  k_cvt<<<(MTOT * 1024 / 8 + 255) / 256, 256, 0, stream>>>(x, xb, MTOT * 1024 / 8);
  k_transpose_cvt<<<dim3(3072 / 32, 1024 / 32), 256, 0, stream>>>(Wqkv, wqkvT, 1024, 3072);
  k_transpose_cvt<<<dim3(1024 / 32, 1024 / 32), 256, 0, stream>>>(Wproj, wpT, 1024, 1024);
  k_gemm3<<<dim3(32, 16), 512, 0, stream>>>(xb, wqkvT, bqkv, Qb, Kb, Vtb);
  k_flash<<<16 * 64, 256, 0, stream>>>(Qb, Kb, Vtb, Yb);
  k_gemm2<<<dim3(32, 8), 512, 0, stream>>>(Yb, wpT, bproj, (float*)d_out);
}

// Round 13
// 153.036 us; speedup vs baseline: 1.2381x; 1.0111x over previous
//
#include <hip/hip_runtime.h>
#include <hip/hip_bf16.h>
#include <cstdint>
#include <math.h>

// Problem constants
#define DM   1024
#define NH   16
#define DH   64
#define BB   4
#define TT   2048
#define MTOT (BB*TT)   // 8192 rows

using short8 = __attribute__((ext_vector_type(8))) short;  // 8 bf16 (4 VGPRs)
using f32x4  = __attribute__((ext_vector_type(4))) float;

__device__ __forceinline__ f32x4 mfma16(short8 a, short8 b, f32x4 c) {
  return __builtin_amdgcn_mfma_f32_16x16x32_bf16(a, b, c, 0, 0, 0);
}

typedef const __attribute__((address_space(1))) unsigned int* as1_u32p;
typedef __attribute__((address_space(3))) unsigned int*       as3_u32p;

// async global->LDS, 16B per lane; LDS dest = wave-uniform base + lane*16 (linear)
__device__ __forceinline__ void gl_lds16(const void* g, void* l) {
  __builtin_amdgcn_global_load_lds(
      (as1_u32p)(reinterpret_cast<uintptr_t>(g)),
      (as3_u32p)((unsigned int)(reinterpret_cast<uintptr_t>(l))),
      16, 0, 0);
}

// XOR swizzle for tiles with 64-elem (128B) rows: 8 slots of 8 bf16; slot ^= row&7
__device__ __forceinline__ int swz64(int row, int col) {
  return row*64 + ((((col >> 3) ^ (row & 7)) << 3) | (col & 7));
}

__device__ __forceinline__ unsigned pkbf(float a, float b) {
  __hip_bfloat162 h = __float22bfloat162_rn(make_float2(a, b)); // x=lo, y=hi
  return *reinterpret_cast<unsigned*>(&h);
}

// permlane swaps (VALU pipe). Verified row semantics (involutions):
// perm16(d,s): d'=[d0,s0,d2,s2], s'=[d1,s1,d3,s3]   (16-lane rows)
// perm32(d,s): d'=[d0,d1,s0,s1], s'=[d2,d3,s2,s3]
__device__ __forceinline__ void perm16p(unsigned &a, unsigned &b) {
  asm("v_permlane16_swap_b32 %0, %1" : "+v"(a), "+v"(b));
}
__device__ __forceinline__ void perm32p(unsigned &a, unsigned &b) {
  asm("v_permlane32_swap_b32 %0, %1" : "+v"(a), "+v"(b));
}

// inline-asm LDS reads (opaque to alias analysis: no compiler-inserted vmcnt drains)
// o-series: 2048B step (proj/flash)
__device__ __forceinline__ short8 ldsr_o0(unsigned a) {
  short8 r; asm volatile("ds_read_b128 %0, %1" : "=v"(r) : "v"(a)); return r;
}
__device__ __forceinline__ short8 ldsr_o1(unsigned a) {
  short8 r; asm volatile("ds_read_b128 %0, %1 offset:2048" : "=v"(r) : "v"(a)); return r;
}
__device__ __forceinline__ short8 ldsr_o2(unsigned a) {
  short8 r; asm volatile("ds_read_b128 %0, %1 offset:4096" : "=v"(r) : "v"(a)); return r;
}
__device__ __forceinline__ short8 ldsr_o3(unsigned a) {
  short8 r; asm volatile("ds_read_b128 %0, %1 offset:6144" : "=v"(r) : "v"(a)); return r;
}
// p-series: 1024B step (BK=32 packed QKV gemm)
__device__ __forceinline__ short8 ldsr_p0(unsigned a) {
  short8 r; asm volatile("ds_read_b128 %0, %1" : "=v"(r) : "v"(a)); return r;
}
__device__ __forceinline__ short8 ldsr_p1(unsigned a) {
  short8 r; asm volatile("ds_read_b128 %0, %1 offset:1024" : "=v"(r) : "v"(a)); return r;
}
__device__ __forceinline__ short8 ldsr_p2(unsigned a) {
  short8 r; asm volatile("ds_read_b128 %0, %1 offset:2048" : "=v"(r) : "v"(a)); return r;
}
__device__ __forceinline__ short8 ldsr_p3(unsigned a) {
  short8 r; asm volatile("ds_read_b128 %0, %1 offset:3072" : "=v"(r) : "v"(a)); return r;
}
__device__ __forceinline__ short8 ldsr_p4(unsigned a) {
  short8 r; asm volatile("ds_read_b128 %0, %1 offset:4096" : "=v"(r) : "v"(a)); return r;
}
__device__ __forceinline__ short8 ldsr_p5(unsigned a) {
  short8 r; asm volatile("ds_read_b128 %0, %1 offset:5120" : "=v"(r) : "v"(a)); return r;
}

#define LGKM0  do { asm volatile("s_waitcnt lgkmcnt(0)"); __builtin_amdgcn_sched_barrier(0); } while(0)
#define VMCNT8 do { __builtin_amdgcn_sched_barrier(0); asm volatile("s_waitcnt vmcnt(8)"); __builtin_amdgcn_sched_barrier(0); } while(0)
#define VMCNT6 do { __builtin_amdgcn_sched_barrier(0); asm volatile("s_waitcnt vmcnt(6)"); __builtin_amdgcn_sched_barrier(0); } while(0)
#define VMCNT4 do { __builtin_amdgcn_sched_barrier(0); asm volatile("s_waitcnt vmcnt(4)"); __builtin_amdgcn_sched_barrier(0); } while(0)
#define VMCNT3 do { __builtin_amdgcn_sched_barrier(0); asm volatile("s_waitcnt vmcnt(3)"); __builtin_amdgcn_sched_barrier(0); } while(0)
#define VMCNT0 do { __builtin_amdgcn_sched_barrier(0); asm volatile("s_waitcnt vmcnt(0)"); __builtin_amdgcn_sched_barrier(0); } while(0)
#define BARRIER do { __builtin_amdgcn_s_barrier(); __builtin_amdgcn_sched_barrier(0); } while(0)

// ---------------- fp32 -> bf16 copy convert ----------------
__global__ __launch_bounds__(256) void k_cvt(const float* __restrict__ in,
                                             __hip_bfloat16* __restrict__ out, int n8) {
  int i = blockIdx.x * 256 + threadIdx.x;
  if (i >= n8) return;
  const float* p = in + (size_t)i * 8;
  short8 o;
#pragma unroll
  for (int j = 0; j < 8; ++j) {
    __hip_bfloat16 h = __float2bfloat16(p[j]);
    o[j] = *reinterpret_cast<short*>(&h);
  }
  *reinterpret_cast<short8*>(out + (size_t)i * 8) = o;
}

// ---------------- W [K][N] fp32 -> Wt [N][K] bf16 (tiled transpose) ----------------
__global__ __launch_bounds__(256) void k_transpose_cvt(const float* __restrict__ W,
                                                       __hip_bfloat16* __restrict__ Wt,
                                                       int K, int N) {
  __shared__ float tbuf[32][33];
  const int n0 = blockIdx.x * 32, k0 = blockIdx.y * 32;
  const int tx = threadIdx.x & 31, ty = threadIdx.x >> 5;
#pragma unroll
  for (int i = 0; i < 4; ++i)
    tbuf[ty + i*8][tx] = W[(size_t)(k0 + ty + i*8) * N + n0 + tx];
  __syncthreads();
#pragma unroll
  for (int i = 0; i < 4; ++i)
    Wt[(size_t)(n0 + ty + i*8) * K + k0 + tx] = __float2bfloat16(tbuf[tx][ty + i*8]);
}

// ---------------- 256x192 BK=32 distance-3 pipeline QKV GEMM ----------------
// 512 threads / 8 waves (4m x 2n = r9 wave map, acc[4][6]); 32 K-tiles.
// 4 LDS slots x 28KB = 112KB (A 16KB + B 12KB per slot); stage t+3 while computing t.
// Per-wave counted vmcnt (waves 0-3: 4 loads/tile -> vmcnt(8); waves 4-7: 3 -> vmcnt(6));
// barrier publishes cross-wave. Packed-pairs BK=32 layout (r10-verified addressing).
__global__ __launch_bounds__(512, 2) void k_gemm3(const __hip_bfloat16* __restrict__ A,
                                                  const __hip_bfloat16* __restrict__ Bt,
                                                  const float* __restrict__ bias,
                                                  __hip_bfloat16* __restrict__ Qb,
                                                  __hip_bfloat16* __restrict__ Kb,
                                                  __hip_bfloat16* __restrict__ Vtb) {
  __shared__ __hip_bfloat16 Ls[4][14336];   // slot: A elems [0,8192), B elems [8192,14336)
  const int tid = threadIdx.x;
  const int l = tid & 63, w = tid >> 6;
  const int lr = l & 15, lg = l >> 4;
  const int lr2 = lr >> 1;
  const int wm = w >> 1, wn = w & 1;        // r9 wave map: 4m x 2n (64 rows x 96 cols)
  const int m0 = blockIdx.x * 256, n0 = blockIdx.y * 192;

  // staging source offsets: LDS elem e holds global (row, k):
  //   rr=e>>6, c8=((e>>3)&7)^(rr&7), row=rr*2+(c8>>2), k=(c8&3)*8+(e&7)
  auto soff = [&](int e) {
    const int rr = e >> 6;
    const int c8 = ((e >> 3) & 7) ^ (rr & 7);
    return (size_t)(rr * 2 + (c8 >> 2)) * 1024 + (c8 & 3) * 8;
  };
  const size_t aoff0 = (size_t)m0 * 1024 + soff(tid * 8);
  const size_t aoff1 = (size_t)m0 * 1024 + soff(4096 + tid * 8);
  const size_t boff0 = (size_t)n0 * 1024 + soff(tid * 8);
  const size_t boff1 = (size_t)n0 * 1024 + soff(4096 + tid * 8);  // tid<256 only
  const int ld0 = tid * 8;
  const bool xb2 = (tid < 256);

  auto stage = [&](int t, int s) {
    const int kb = t * 32;
    __hip_bfloat16* base = &Ls[s][0];
    gl_lds16(A + aoff0 + kb, base + ld0);
    gl_lds16(A + aoff1 + kb, base + 4096 + ld0);
    gl_lds16(Bt + boff0 + kb, base + 8192 + ld0);
    if (xb2) gl_lds16(Bt + boff1 + kb, base + 12288 + ld0);
  };

  // fragment read bases (bytes): packed row rr = (rowbase + mi*16)/2 + lr2;
  // slot index = ((lr&1)<<2 | lg) ^ (lr2&7)  [r10-verified]
  const unsigned lsBase = (unsigned)(uintptr_t)&Ls[0][0];
  const unsigned fslot = (unsigned)((((lr & 1) << 2) | lg) ^ (lr2 & 7));
  const unsigned laneOff = (unsigned)(lr2 * 128) + fslot * 16u;
  const unsigned aLane = lsBase + (unsigned)(wm * 4096) + laneOff;            // wm*64 rows
  const unsigned bLane = lsBase + 16384u + (unsigned)(wn * 6144) + laneOff;   // wn*96 rows

  // prologue: stage tiles 0..2; wave retires its own tile-0 loads
  stage(0, 0); stage(1, 1); stage(2, 2);
  if (w < 4) { VMCNT8; } else { VMCNT6; }
  BARRIER;

  f32x4 acc[4][6] = {};
  short8 a_[4], b_[6];

#pragma unroll 4
  for (int t = 0; t < 32; ++t) {
    const int s = t & 3;
    const unsigned aB = aLane + (unsigned)s * 28672u;
    const unsigned bB = bLane + (unsigned)s * 28672u;
    if (t < 29) stage(t + 3, (t + 3) & 3);
    a_[0] = ldsr_p0(aB); a_[1] = ldsr_p1(aB); a_[2] = ldsr_p2(aB); a_[3] = ldsr_p3(aB);
    b_[0] = ldsr_p0(bB); b_[1] = ldsr_p1(bB); b_[2] = ldsr_p2(bB);
    b_[3] = ldsr_p3(bB); b_[4] = ldsr_p4(bB); b_[5] = ldsr_p5(bB);
    LGKM0;
    __builtin_amdgcn_s_setprio(1);
#pragma unroll
    for (int n = 0; n < 6; ++n)
#pragma unroll
      for (int m = 0; m < 4; ++m)
        acc[m][n] = mfma16(a_[m], b_[n], acc[m][n]);
    __builtin_amdgcn_s_setprio(0);
    if (t <= 28)      { if (w < 4) { VMCNT8; } else { VMCNT6; } BARRIER; }
    else if (t == 29) { if (w < 4) { VMCNT4; } else { VMCNT3; } BARRIER; }
    else if (t == 30) { VMCNT0; BARRIER; }
  }

  __syncthreads();
  // ---- per-16-col-group LDS-bounce epilogue (r9-proven, acc[4][6]) ----
  __hip_bfloat16* reg = &Ls[0][0] + w * 6144;
  const int colbase = n0 + wn * 96;
  const int rowbase = m0 + wm * 64;
  const int bidx = rowbase >> 11;
  const int tbase = rowbase & 2047;
  const float qs = 0.18033688011112042f;   // 0.125 * log2(e) folded into Q
  float bv[6];
#pragma unroll
  for (int g = 0; g < 6; ++g) bv[g] = bias[colbase + g * 16 + lr];
#pragma unroll
  for (int g = 0; g < 6; ++g) {
    const int cg0 = colbase + g * 16;
    const int which = cg0 >> 10;
    __hip_bfloat16* rg = reg + g * 1024;
    if (which == 2) {
#pragma unroll
      for (int m = 0; m < 4; ++m)
#pragma unroll
        for (int r = 0; r < 4; ++r) {
          const int t = m * 16 + lg * 4 + r;
          rg[lr * 64 + (t ^ ((lr & 7) << 3))] = __float2bfloat16(acc[m][g][r] + bv[g]);
        }
    } else {
      const float sc = (which == 0) ? qs : 1.f;
#pragma unroll
      for (int m = 0; m < 4; ++m)
#pragma unroll
        for (int r = 0; r < 4; ++r) {
          const int t = m * 16 + lg * 4 + r;
          rg[t * 16 + (lr ^ (((t >> 2) & 1) << 3))] =
              __float2bfloat16((acc[m][g][r] + bv[g]) * sc);
        }
    }
  }
#pragma unroll
  for (int g = 0; g < 6; ++g) {
    const int cg0 = colbase + g * 16;
    const int which = cg0 >> 10;
    const int hh = (cg0 >> 6) & 15;
    const int dd0 = cg0 & 48;
    const size_t bh = (size_t)bidx * 16 + hh;
    const __hip_bfloat16* rg = reg + g * 1024;
    if (which < 2) {
      __hip_bfloat16* basep = (which == 0) ? Qb : Kb;
      const int t = l;
      const int Xc = ((t >> 2) & 1) << 3;
      short8 y0 = *reinterpret_cast<const short8*>(&rg[t * 16 + Xc]);
      short8 y1 = *reinterpret_cast<const short8*>(&rg[t * 16 + (Xc ^ 8)]);
      __hip_bfloat16* dst = basep + (bh * TT + tbase + t) * 64 + dd0;
      *reinterpret_cast<short8*>(dst) = y0;
      *reinterpret_cast<short8*>(dst + 8) = y1;
    } else {
      const int dd = l >> 2, tseg = l & 3;
      const int X = (dd & 7) << 3;
      const int S0 = (((tseg ^ (X >> 4)) & 3) << 4) | (X & 8);
      short8 y0 = *reinterpret_cast<const short8*>(&rg[dd * 64 + S0]);
      short8 y1 = *reinterpret_cast<const short8*>(&rg[dd * 64 + (S0 ^ 8)]);
      __hip_bfloat16* dst = Vtb + (bh * 64 + dd0 + dd) * TT + tbase + tseg * 16;
      *reinterpret_cast<short8*>(dst) = y0;
      *reinterpret_cast<short8*>(dst + 8) = y1;
    }
  }
}

// ---------------- 256x128 triple-buffered deep-pipeline GEMM (proj) ----------------
__global__ __launch_bounds__(512, 2) void k_gemm2(const __hip_bfloat16* __restrict__ A,
                                                  const __hip_bfloat16* __restrict__ Bt,
                                                  const float* __restrict__ bias,
                                                  float* __restrict__ outF) {
  __shared__ __hip_bfloat16 As[3][256 * 64];
  __shared__ __hip_bfloat16 Bs[3][128 * 64];
  const int tid = threadIdx.x;
  const int l = tid & 63, w = tid >> 6;
  const int lr = l & 15, lg = l >> 4;
  const int wm = w >> 1, wn = w & 1;
  const int m0 = blockIdx.x * 256, n0 = blockIdx.y * 128;

  const int srow = tid >> 3;
  const int scol = (((tid & 7) ^ (srow & 7)) << 3);
  const size_t aoffs = (size_t)(m0 + srow) * 1024 + scol;
  const size_t boffs = (size_t)(n0 + srow) * 1024 + scol;
  const int ldst = tid * 8;

  auto stage = [&](int t, int s) {
    const int k0 = t * 64;
    __hip_bfloat16* as_ = &As[s][0];
    __hip_bfloat16* bs_ = &Bs[s][0];
#pragma unroll
    for (int rd = 0; rd < 4; ++rd)
      gl_lds16(A + aoffs + (size_t)rd * 65536 + k0, as_ + rd * 4096 + ldst);
#pragma unroll
    for (int rd = 0; rd < 2; ++rd)
      gl_lds16(Bt + boffs + (size_t)rd * 65536 + k0, bs_ + rd * 4096 + ldst);
  };

  const unsigned asLds = (unsigned)(uintptr_t)&As[0][0];
  const unsigned bsLds = (unsigned)(uintptr_t)&Bs[0][0];
  const unsigned aBase = asLds + 2u * ((wm*64 + lr) * 64 + ((lg ^ (lr & 7)) << 3));
  const unsigned bBase = bsLds + 2u * ((wn*64 + lr) * 64 + ((lg ^ (lr & 7)) << 3));

  stage(0, 0);
  stage(1, 1);
  VMCNT6;
  BARRIER;

  f32x4 acc[4][4] = {};
  short8 a_[4][2], b_[2][2];

#pragma unroll
  for (int t = 0; t < 16; ++t) {
    const int s = t % 3;
    const unsigned aB0 = aBase + (unsigned)s * 32768u;
    const unsigned aB1 = aB0 ^ 64u;
    const unsigned bB0 = bBase + (unsigned)s * 16384u;
    const unsigned bB1 = bB0 ^ 64u;
    if (t + 2 < 16) stage(t + 2, (t + 2) % 3);
    a_[0][0] = ldsr_o0(aB0); a_[1][0] = ldsr_o1(aB0); a_[2][0] = ldsr_o2(aB0); a_[3][0] = ldsr_o3(aB0);
    a_[0][1] = ldsr_o0(aB1); a_[1][1] = ldsr_o1(aB1); a_[2][1] = ldsr_o2(aB1); a_[3][1] = ldsr_o3(aB1);
    b_[0][0] = ldsr_o0(bB0); b_[1][0] = ldsr_o1(bB0);
    b_[0][1] = ldsr_o0(bB1); b_[1][1] = ldsr_o1(bB1);
    LGKM0;
    __builtin_amdgcn_s_setprio(1);
#pragma unroll
    for (int m = 0; m < 4; ++m)
#pragma unroll
      for (int n = 0; n < 2; ++n)
#pragma unroll
        for (int ks = 0; ks < 2; ++ks)
          acc[m][n] = mfma16(a_[m][ks], b_[n][ks], acc[m][n]);
    __builtin_amdgcn_s_setprio(0);
    b_[0][0] = ldsr_o2(bB0); b_[1][0] = ldsr_o3(bB0);
    b_[0][1] = ldsr_o2(bB1); b_[1][1] = ldsr_o3(bB1);
    LGKM0;
    __builtin_amdgcn_s_setprio(1);
#pragma unroll
    for (int m = 0; m < 4; ++m)
#pragma unroll
      for (int n = 0; n < 2; ++n)
#pragma unroll
        for (int ks = 0; ks < 2; ++ks)
          acc[m][n + 2] = mfma16(a_[m][ks], b_[n][ks], acc[m][n + 2]);
    __builtin_amdgcn_s_setprio(0);
    if (t <= 13) { VMCNT6; }
    else if (t == 14) { VMCNT0; }
    BARRIER;
  }

  __syncthreads();
#pragma unroll
  for (int n = 0; n < 4; ++n) {
    const int col = n0 + wn * 64 + n * 16 + lr;
    const float bvv = bias[col];
#pragma unroll
    for (int m = 0; m < 4; ++m)
#pragma unroll
      for (int r = 0; r < 4; ++r) {
        const int row = m0 + wm * 64 + m * 16 + lg * 4 + r;
        outF[(size_t)row * 1024 + col] = acc[m][n][r] + bvv;
      }
  }
}

// ---------------- causal flash attention (r9-proven merged paired q-tiles) ----------------
// Fixed-max softmax, sigma-permuted K rows -> P redistribution is exactly
// 2x permlane16_swap + 2x permlane32_swap. Shared K/V frag reads serve both tiles.
__device__ __forceinline__ void tile_step(f32x4 s0, f32x4 s1, int kbase, int kmaxw, int qmb,
                                          short8 v0, short8 v1, short8 v2, short8 v3,
                                          f32x4 (&acc)[4], float& lrun) {
  if (kbase + 31 > kmaxw - 15) {       // diagonal chunk: per-element causal mask
#pragma unroll
    for (int r = 0; r < 4; ++r) {
      const int off = (r & 1) + ((r & 2) << 2);   // 0,1,8,9
      if (kbase + off > qmb)      s0[r] = -INFINITY;
      if (kbase + 16 + off > qmb) s1[r] = -INFINITY;
    }
  }
  float p0 = __builtin_amdgcn_exp2f(s0[0]), p1 = __builtin_amdgcn_exp2f(s0[1]);
  float p2 = __builtin_amdgcn_exp2f(s0[2]), p3 = __builtin_amdgcn_exp2f(s0[3]);
  float p4 = __builtin_amdgcn_exp2f(s1[0]), p5 = __builtin_amdgcn_exp2f(s1[1]);
  float p6 = __builtin_amdgcn_exp2f(s1[2]), p7 = __builtin_amdgcn_exp2f(s1[3]);
  lrun += ((p0 + p1) + (p2 + p3)) + ((p4 + p5) + (p6 + p7));
  unsigned u0 = pkbf(p0, p1);
  unsigned u1 = pkbf(p2, p3);
  unsigned u2 = pkbf(p4, p5);
  unsigned u3 = pkbf(p6, p7);
  perm16p(u0, u1);
  perm16p(u2, u3);
  perm32p(u0, u2);
  perm32p(u1, u3);
  union { unsigned u[4]; short8 s; } pw;
  pw.u[0] = u0; pw.u[1] = u2; pw.u[2] = u1; pw.u[3] = u3;
  const short8 pf = pw.s;
  acc[0] = mfma16(v0, pf, acc[0]);
  acc[1] = mfma16(v1, pf, acc[1]);
  acc[2] = mfma16(v2, pf, acc[2]);
  acc[3] = mfma16(v3, pf, acc[3]);
}

__device__ __forceinline__ void store_tile(__hip_bfloat16* Ylds, f32x4 (&acc)[4],
                                           float lrun, int q0, int w, int l,
                                           int lr, int lg, int bh,
                                           __hip_bfloat16* __restrict__ Y) {
  lrun += __shfl_xor(lrun, 16);
  lrun += __shfl_xor(lrun, 32);
  const float inv = 1.f / lrun;
#pragma unroll
  for (int nb = 0; nb < 4; ++nb) {
#pragma unroll
    for (int r = 0; r < 4; ++r) {
      const int d = nb * 16 + lg * 4 + r;
      Ylds[swz64(lr, d)] = __float2bfloat16(acc[nb][r] * inv);
    }
  }
  const int rr = l >> 2, part = l & 3;
  const int trow = q0 + w * 16 + rr;
  const int b = bh >> 4, h = bh & 15;
  short8 y0 = *reinterpret_cast<const short8*>(&Ylds[swz64(rr, part * 16)]);
  short8 y1 = *reinterpret_cast<const short8*>(&Ylds[swz64(rr, part * 16 + 8)]);
  __hip_bfloat16* dst = Y + ((size_t)b * TT + trow) * 1024 + h * 64 + part * 16;
  *reinterpret_cast<short8*>(dst) = y0;
  *reinterpret_cast<short8*>(dst + 8) = y1;
}

__global__ __launch_bounds__(256, 4) void k_flash(const __hip_bfloat16* __restrict__ Qb,
                                                  const __hip_bfloat16* __restrict__ Kb,
                                                  const __hip_bfloat16* __restrict__ Vtb,
                                                  __hip_bfloat16* __restrict__ Y) {
  __shared__ __hip_bfloat16 Klds[128 * 64];
  __shared__ __hip_bfloat16 Vtlds[64 * 128];
  const int tid = threadIdx.x;
  const int l = tid & 63, w = tid >> 6;
  const int lr = l & 15, lg = l >> 4;
  const int p  = blockIdx.x >> 6;       // pair index 0..15
  const int bh = blockIdx.x & 63;
  const int q0A = p * 64, q0B = (31 - p) * 64;
  const __hip_bfloat16* Qp = Qb + (size_t)bh * TT * 64;
  const __hip_bfloat16* Kp = Kb + (size_t)bh * TT * 64;
  const __hip_bfloat16* Vp = Vtb + (size_t)bh * 64 * TT;
  const int qrowA = q0A + w * 16 + lr;
  const int qrowB = q0B + w * 16 + lr;
  const short8 qfA0 = *reinterpret_cast<const short8*>(Qp + (size_t)qrowA * 64 + lg * 8);
  const short8 qfA1 = *reinterpret_cast<const short8*>(Qp + (size_t)qrowA * 64 + 32 + lg * 8);
  const short8 qfB0 = *reinterpret_cast<const short8*>(Qp + (size_t)qrowB * 64 + lg * 8);
  const short8 qfB1 = *reinterpret_cast<const short8*>(Qp + (size_t)qrowB * 64 + 32 + lg * 8);
  f32x4 accA[4] = {}, accB[4] = {};
  float lA = 0.f, lB = 0.f;

  const int ka  = lr * 64 + ((lg ^ (lr & 7)) << 3);
  const int va  = lr * 128 + ((lg ^ (lr & 15)) << 3);

  const __hip_bfloat16* gk[4];
  const __hip_bfloat16* gv[4];
  __hip_bfloat16* lk[4];
  __hip_bfloat16* lv[4];
#pragma unroll
  for (int it = 0; it < 4; ++it) {
    int e = it * 2048 + tid * 8;
    int rowk = e >> 6;
    int lcolk = ((((e >> 3) & 7) ^ (rowk & 7)) << 3);
    int rk = rowk & 15;
    int srk = (((rk >> 1) ^ (rk >> 3)) & 1) ? (rk ^ 10) : rk;
    int rowks = (rowk & ~15) | srk;
    gk[it] = Kp + (size_t)rowks * 64 + lcolk;
    lk[it] = &Klds[e];
    int rowv = e >> 7;
    int lcolv = ((((e >> 3) & 15) ^ (rowv & 15)) << 3);
    gv[it] = Vp + (size_t)rowv * TT + lcolv;
    lv[it] = &Vtlds[e];
  }

  const int kmaxwA = q0A + w * 16 + 15;
  const int kmaxwB = q0B + w * 16 + 15;
  const int base_lg = ((lg & 1) << 2) | (lg & 2);
  const int qmbA = qrowA - base_lg;
  const int qmbB = qrowB - base_lg;
  const int nblk = (q0B + 63) / 128 + 1;
  for (int blk = 0; blk < nblk; ++blk) {
    const int kv0 = blk * 128;
#pragma unroll
    for (int it = 0; it < 4; ++it) {
      gl_lds16(gk[it], lk[it]);
      gk[it] += 128 * 64;
    }
#pragma unroll
    for (int it = 0; it < 4; ++it) {
      gl_lds16(gv[it], lv[it]);
      gv[it] += 128;
    }
    __syncthreads();
#pragma unroll
    for (int kci = 0; kci < 4; ++kci) {
      const int kbase = kv0 + kci * 32;
      if (kbase > kmaxwB) break;
      const int kb = ka + kci * 2048;
      const short8 kf00 = *reinterpret_cast<const short8*>(&Klds[kb]);
      const short8 kf10 = *reinterpret_cast<const short8*>(&Klds[kb + 1024]);
      const short8 kf01 = *reinterpret_cast<const short8*>(&Klds[kb ^ 32]);
      const short8 kf11 = *reinterpret_cast<const short8*>(&Klds[(kb + 1024) ^ 32]);
      f32x4 sB0 = {}, sB1 = {};
      sB0 = mfma16(kf00, qfB0, sB0);
      sB1 = mfma16(kf10, qfB0, sB1);
      sB0 = mfma16(kf01, qfB1, sB0);
      sB1 = mfma16(kf11, qfB1, sB1);
      const bool aAct = (kbase <= kmaxwA);
      f32x4 sA0 = {}, sA1 = {};
      if (aAct) {
        sA0 = mfma16(kf00, qfA0, sA0);
        sA1 = mfma16(kf10, qfA0, sA1);
        sA0 = mfma16(kf01, qfA1, sA0);
        sA1 = mfma16(kf11, qfA1, sA1);
      }
      const int vb = va ^ (kci * 32);
      const short8 v0 = *reinterpret_cast<const short8*>(&Vtlds[vb]);
      const short8 v1 = *reinterpret_cast<const short8*>(&Vtlds[vb + 2048]);
      const short8 v2 = *reinterpret_cast<const short8*>(&Vtlds[vb + 4096]);
      const short8 v3 = *reinterpret_cast<const short8*>(&Vtlds[vb + 6144]);
      tile_step(sB0, sB1, kbase, kmaxwB, qmbB, v0, v1, v2, v3, accB, lB);
      if (aAct)
        tile_step(sA0, sA1, kbase, kmaxwA, qmbA, v0, v1, v2, v3, accA, lA);
    }
    __syncthreads();
  }
  __hip_bfloat16* Ylds = Klds + w * 1024;
  store_tile(Ylds, accA, lA, q0A, w, l, lr, lg, bh, Y);
  store_tile(Ylds, accB, lB, q0B, w, l, lr, lg, bh, Y);
}

// ---------------- launch ----------------
extern "C" void kernel_launch(void* const* d_in, const int* in_sizes, int n_in,
                              void* d_out, int out_size, void* d_ws, size_t ws_size,
                              hipStream_t stream) {
  const float* x     = (const float*)d_in[0];
  const float* Wqkv  = (const float*)d_in[1];
  const float* bqkv  = (const float*)d_in[2];
  const float* Wproj = (const float*)d_in[3];
  const float* bproj = (const float*)d_in[4];

  char* ws = (char*)d_ws;
  size_t off = 0;
  auto alloc = [&](size_t bytes) {
    char* p = ws + off;
    off += (bytes + 255) & ~(size_t)255;
    return p;
  };
  __hip_bfloat16* xb    = (__hip_bfloat16*)alloc((size_t)MTOT * 1024 * 2);
  __hip_bfloat16* wqkvT = (__hip_bfloat16*)alloc((size_t)3072 * 1024 * 2);
  __hip_bfloat16* wpT   = (__hip_bfloat16*)alloc((size_t)1024 * 1024 * 2);
  __hip_bfloat16* Qb    = (__hip_bfloat16*)alloc((size_t)64 * TT * 64 * 2);
  __hip_bfloat16* Kb    = (__hip_bfloat16*)alloc((size_t)64 * TT * 64 * 2);
  __hip_bfloat16* Vtb   = (__hip_bfloat16*)alloc((size_t)64 * TT * 64 * 2);
  __hip_bfloat16* Yb    = (__hip_bfloat16*)alloc((size_t)MTOT * 1024 * 2);

  k_cvt<<<(MTOT * 1024 / 8 + 255) / 256, 256, 0, stream>>>(x, xb, MTOT * 1024 / 8);
  k_transpose_cvt<<<dim3(3072 / 32, 1024 / 32), 256, 0, stream>>>(Wqkv, wqkvT, 1024, 3072);
  k_transpose_cvt<<<dim3(1024 / 32, 1024 / 32), 256, 0, stream>>>(Wproj, wpT, 1024, 1024);
  k_gemm3<<<dim3(32, 16), 512, 0, stream>>>(xb, wqkvT, bqkv, Qb, Kb, Vtb);
  k_flash<<<16 * 64, 256, 0, stream>>>(Qb, Kb, Vtb, Yb);
  k_gemm2<<<dim3(32, 8), 512, 0, stream>>>(Yb, wpT, bproj, (float*)d_out);
}

// Round 14
// 148.080 us; speedup vs baseline: 1.2796x; 1.0335x over previous
//
#include <hip/hip_runtime.h>
#include <hip/hip_bf16.h>
#include <cstdint>
#include <math.h>

// Problem constants
#define DM   1024
#define NH   16
#define DH   64
#define BB   4
#define TT   2048
#define MTOT (BB*TT)   // 8192 rows

using short8 = __attribute__((ext_vector_type(8))) short;  // 8 bf16 (4 VGPRs)
using f32x4  = __attribute__((ext_vector_type(4))) float;

__device__ __forceinline__ f32x4 mfma16(short8 a, short8 b, f32x4 c) {
  return __builtin_amdgcn_mfma_f32_16x16x32_bf16(a, b, c, 0, 0, 0);
}

typedef const __attribute__((address_space(1))) unsigned int* as1_u32p;
typedef __attribute__((address_space(3))) unsigned int*       as3_u32p;

// async global->LDS, 16B per lane; LDS dest = wave-uniform base + lane*16 (linear)
__device__ __forceinline__ void gl_lds16(const void* g, void* l) {
  __builtin_amdgcn_global_load_lds(
      (as1_u32p)(reinterpret_cast<uintptr_t>(g)),
      (as3_u32p)((unsigned int)(reinterpret_cast<uintptr_t>(l))),
      16, 0, 0);
}

// XOR swizzle for tiles with 64-elem (128B) rows: 8 slots of 8 bf16; slot ^= row&7
__device__ __forceinline__ int swz64(int row, int col) {
  return row*64 + ((((col >> 3) ^ (row & 7)) << 3) | (col & 7));
}

__device__ __forceinline__ unsigned pkbf(float a, float b) {
  __hip_bfloat162 h = __float22bfloat162_rn(make_float2(a, b)); // x=lo, y=hi
  return *reinterpret_cast<unsigned*>(&h);
}

// permlane swaps (VALU pipe). Verified row semantics (involutions):
// perm16(d,s): d'=[d0,s0,d2,s2], s'=[d1,s1,d3,s3]   (16-lane rows)
// perm32(d,s): d'=[d0,d1,s0,s1], s'=[d2,d3,s2,s3]
__device__ __forceinline__ void perm16p(unsigned &a, unsigned &b) {
  asm("v_permlane16_swap_b32 %0, %1" : "+v"(a), "+v"(b));
}
__device__ __forceinline__ void perm32p(unsigned &a, unsigned &b) {
  asm("v_permlane32_swap_b32 %0, %1" : "+v"(a), "+v"(b));
}

// inline-asm LDS reads (opaque to alias analysis: no compiler-inserted vmcnt drains)
__device__ __forceinline__ short8 ldsr_o0(unsigned a) {
  short8 r; asm volatile("ds_read_b128 %0, %1" : "=v"(r) : "v"(a)); return r;
}
__device__ __forceinline__ short8 ldsr_o1(unsigned a) {
  short8 r; asm volatile("ds_read_b128 %0, %1 offset:2048" : "=v"(r) : "v"(a)); return r;
}
__device__ __forceinline__ short8 ldsr_o2(unsigned a) {
  short8 r; asm volatile("ds_read_b128 %0, %1 offset:4096" : "=v"(r) : "v"(a)); return r;
}
__device__ __forceinline__ short8 ldsr_o3(unsigned a) {
  short8 r; asm volatile("ds_read_b128 %0, %1 offset:6144" : "=v"(r) : "v"(a)); return r;
}
__device__ __forceinline__ short8 ldsr_o4(unsigned a) {
  short8 r; asm volatile("ds_read_b128 %0, %1 offset:8192" : "=v"(r) : "v"(a)); return r;
}
__device__ __forceinline__ short8 ldsr_o5(unsigned a) {
  short8 r; asm volatile("ds_read_b128 %0, %1 offset:10240" : "=v"(r) : "v"(a)); return r;
}

#define LGKM0  do { asm volatile("s_waitcnt lgkmcnt(0)"); __builtin_amdgcn_sched_barrier(0); } while(0)
#define VMCNT6 do { __builtin_amdgcn_sched_barrier(0); asm volatile("s_waitcnt vmcnt(6)"); __builtin_amdgcn_sched_barrier(0); } while(0)
#define VMCNT0 do { __builtin_amdgcn_sched_barrier(0); asm volatile("s_waitcnt vmcnt(0)"); __builtin_amdgcn_sched_barrier(0); } while(0)
#define BARRIER do { __builtin_amdgcn_s_barrier(); __builtin_amdgcn_sched_barrier(0); } while(0)

// ---------------- fp32 -> bf16 copy convert ----------------
__global__ __launch_bounds__(256) void k_cvt(const float* __restrict__ in,
                                             __hip_bfloat16* __restrict__ out, int n8) {
  int i = blockIdx.x * 256 + threadIdx.x;
  if (i >= n8) return;
  const float* p = in + (size_t)i * 8;
  short8 o;
#pragma unroll
  for (int j = 0; j < 8; ++j) {
    __hip_bfloat16 h = __float2bfloat16(p[j]);
    o[j] = *reinterpret_cast<short*>(&h);
  }
  *reinterpret_cast<short8*>(out + (size_t)i * 8) = o;
}

// ---------------- W [K][N] fp32 -> Wt [N][K] bf16 (tiled transpose) ----------------
__global__ __launch_bounds__(256) void k_transpose_cvt(const float* __restrict__ W,
                                                       __hip_bfloat16* __restrict__ Wt,
                                                       int K, int N) {
  __shared__ float tbuf[32][33];
  const int n0 = blockIdx.x * 32, k0 = blockIdx.y * 32;
  const int tx = threadIdx.x & 31, ty = threadIdx.x >> 5;
#pragma unroll
  for (int i = 0; i < 4; ++i)
    tbuf[ty + i*8][tx] = W[(size_t)(k0 + ty + i*8) * N + n0 + tx];
  __syncthreads();
#pragma unroll
  for (int i = 0; i < 4; ++i)
    Wt[(size_t)(n0 + ty + i*8) * K + k0 + tx] = __float2bfloat16(tbuf[tx][ty + i*8]);
}

// ---------------- 256x192 double-buffered deep-pipeline QKV GEMM (r9-proven, 65us) ----------------
__global__ __launch_bounds__(512, 2) void k_gemm3(const __hip_bfloat16* __restrict__ A,
                                                  const __hip_bfloat16* __restrict__ Bt,
                                                  const float* __restrict__ bias,
                                                  __hip_bfloat16* __restrict__ Qb,
                                                  __hip_bfloat16* __restrict__ Kb,
                                                  __hip_bfloat16* __restrict__ Vtb) {
  __shared__ __hip_bfloat16 As[2][256 * 64];
  __shared__ __hip_bfloat16 Bs[2][192 * 64];
  const int tid = threadIdx.x;
  const int l = tid & 63, w = tid >> 6;
  const int lr = l & 15, lg = l >> 4;
  const int wm = w >> 1, wn = w & 1;
  const int m0 = blockIdx.x * 256, n0 = blockIdx.y * 192;

  const int srow = tid >> 3;
  const int scol = (((tid & 7) ^ (srow & 7)) << 3);
  const size_t aoffs = (size_t)(m0 + srow) * 1024 + scol;
  const size_t boffs = (size_t)(n0 + srow) * 1024 + scol;
  const int ldst = tid * 8;

  auto stage = [&](int t, int s) {
    const int k0 = t * 64;
#pragma unroll
    for (int rd = 0; rd < 4; ++rd)
      gl_lds16(A + aoffs + (size_t)rd * 65536 + k0, &As[s][rd * 4096 + ldst]);
#pragma unroll
    for (int rd = 0; rd < 3; ++rd)
      gl_lds16(Bt + boffs + (size_t)rd * 65536 + k0, &Bs[s][rd * 4096 + ldst]);
  };

  const unsigned asLds = (unsigned)(uintptr_t)&As[0][0];
  const unsigned bsLds = (unsigned)(uintptr_t)&Bs[0][0];
  const unsigned aBase0 = asLds + 2u * ((wm*64 + lr) * 64 + ((lg ^ (lr & 7)) << 3));
  const unsigned bBase0 = bsLds + 2u * ((wn*96 + lr) * 64 + ((lg ^ (lr & 7)) << 3));

  stage(0, 0);
  VMCNT0;
  BARRIER;

  f32x4 acc[4][6] = {};
  short8 a_[4][2], b_[3][2];

#pragma unroll
  for (int t = 0; t < 16; ++t) {
    const int s = t & 1;
    const unsigned aB0 = aBase0 + (unsigned)s * 32768u;
    const unsigned aB1 = aB0 ^ 64u;
    const unsigned bB0 = bBase0 + (unsigned)s * 24576u;
    const unsigned bB1 = bB0 ^ 64u;
    if (t < 15) stage(t + 1, s ^ 1);
    // phase A: A frags + B n0..2, MFMA n=0..2
    a_[0][0] = ldsr_o0(aB0); a_[1][0] = ldsr_o1(aB0); a_[2][0] = ldsr_o2(aB0); a_[3][0] = ldsr_o3(aB0);
    a_[0][1] = ldsr_o0(aB1); a_[1][1] = ldsr_o1(aB1); a_[2][1] = ldsr_o2(aB1); a_[3][1] = ldsr_o3(aB1);
    b_[0][0] = ldsr_o0(bB0); b_[1][0] = ldsr_o1(bB0); b_[2][0] = ldsr_o2(bB0);
    b_[0][1] = ldsr_o0(bB1); b_[1][1] = ldsr_o1(bB1); b_[2][1] = ldsr_o2(bB1);
    LGKM0;
    __builtin_amdgcn_s_setprio(1);
#pragma unroll
    for (int m = 0; m < 4; ++m)
#pragma unroll
      for (int n = 0; n < 3; ++n)
#pragma unroll
        for (int ks = 0; ks < 2; ++ks)
          acc[m][n] = mfma16(a_[m][ks], b_[n][ks], acc[m][n]);
    __builtin_amdgcn_s_setprio(0);
    // phase B: B n3..5, MFMA n=3..5
    b_[0][0] = ldsr_o3(bB0); b_[1][0] = ldsr_o4(bB0); b_[2][0] = ldsr_o5(bB0);
    b_[0][1] = ldsr_o3(bB1); b_[1][1] = ldsr_o4(bB1); b_[2][1] = ldsr_o5(bB1);
    LGKM0;
    __builtin_amdgcn_s_setprio(1);
#pragma unroll
    for (int m = 0; m < 4; ++m)
#pragma unroll
      for (int n = 0; n < 3; ++n)
#pragma unroll
        for (int ks = 0; ks < 2; ++ks)
          acc[m][n + 3] = mfma16(a_[m][ks], b_[n][ks], acc[m][n + 3]);
    __builtin_amdgcn_s_setprio(0);
    if (t < 15) { VMCNT0; }
    BARRIER;
  }

  __syncthreads();
  // ---- per-16-col-group LDS-bounce epilogue ----
  __hip_bfloat16* reg = (w < 4) ? (&As[0][0] + w * 6144)
                                : (&Bs[0][0] + (w - 4) * 6144);
  const int colbase = n0 + wn * 96;
  const int rowbase = m0 + wm * 64;
  const int bidx = rowbase >> 11;
  const int tbase = rowbase & 2047;
  const float qs = 0.18033688011112042f;   // 0.125 * log2(e) folded into Q
  float bv[6];
#pragma unroll
  for (int g = 0; g < 6; ++g) bv[g] = bias[colbase + g * 16 + lr];
#pragma unroll
  for (int g = 0; g < 6; ++g) {
    const int cg0 = colbase + g * 16;
    const int which = cg0 >> 10;
    __hip_bfloat16* rg = reg + g * 1024;
    if (which == 2) {
#pragma unroll
      for (int m = 0; m < 4; ++m)
#pragma unroll
        for (int r = 0; r < 4; ++r) {
          const int t = m * 16 + lg * 4 + r;
          rg[lr * 64 + (t ^ ((lr & 7) << 3))] = __float2bfloat16(acc[m][g][r] + bv[g]);
        }
    } else {
      const float sc = (which == 0) ? qs : 1.f;
#pragma unroll
      for (int m = 0; m < 4; ++m)
#pragma unroll
        for (int r = 0; r < 4; ++r) {
          const int t = m * 16 + lg * 4 + r;
          rg[t * 16 + (lr ^ (((t >> 2) & 1) << 3))] =
              __float2bfloat16((acc[m][g][r] + bv[g]) * sc);
        }
    }
  }
#pragma unroll
  for (int g = 0; g < 6; ++g) {
    const int cg0 = colbase + g * 16;
    const int which = cg0 >> 10;
    const int hh = (cg0 >> 6) & 15;
    const int dd0 = cg0 & 48;
    const size_t bh = (size_t)bidx * 16 + hh;
    const __hip_bfloat16* rg = reg + g * 1024;
    if (which < 2) {
      __hip_bfloat16* basep = (which == 0) ? Qb : Kb;
      const int t = l;
      const int Xc = ((t >> 2) & 1) << 3;
      short8 y0 = *reinterpret_cast<const short8*>(&rg[t * 16 + Xc]);
      short8 y1 = *reinterpret_cast<const short8*>(&rg[t * 16 + (Xc ^ 8)]);
      __hip_bfloat16* dst = basep + (bh * TT + tbase + t) * 64 + dd0;
      *reinterpret_cast<short8*>(dst) = y0;
      *reinterpret_cast<short8*>(dst + 8) = y1;
    } else {
      const int dd = l >> 2, tseg = l & 3;
      const int X = (dd & 7) << 3;
      const int S0 = (((tseg ^ (X >> 4)) & 3) << 4) | (X & 8);
      short8 y0 = *reinterpret_cast<const short8*>(&rg[dd * 64 + S0]);
      short8 y1 = *reinterpret_cast<const short8*>(&rg[dd * 64 + (S0 ^ 8)]);
      __hip_bfloat16* dst = Vtb + (bh * 64 + dd0 + dd) * TT + tbase + tseg * 16;
      *reinterpret_cast<short8*>(dst) = y0;
      *reinterpret_cast<short8*>(dst + 8) = y1;
    }
  }
}

// ---------------- 256x128 triple-buffered deep-pipeline GEMM (proj) ----------------
__global__ __launch_bounds__(512, 2) void k_gemm2(const __hip_bfloat16* __restrict__ A,
                                                  const __hip_bfloat16* __restrict__ Bt,
                                                  const float* __restrict__ bias,
                                                  float* __restrict__ outF) {
  __shared__ __hip_bfloat16 As[3][256 * 64];
  __shared__ __hip_bfloat16 Bs[3][128 * 64];
  const int tid = threadIdx.x;
  const int l = tid & 63, w = tid >> 6;
  const int lr = l & 15, lg = l >> 4;
  const int wm = w >> 1, wn = w & 1;
  const int m0 = blockIdx.x * 256, n0 = blockIdx.y * 128;

  const int srow = tid >> 3;
  const int scol = (((tid & 7) ^ (srow & 7)) << 3);
  const size_t aoffs = (size_t)(m0 + srow) * 1024 + scol;
  const size_t boffs = (size_t)(n0 + srow) * 1024 + scol;
  const int ldst = tid * 8;

  auto stage = [&](int t, int s) {
    const int k0 = t * 64;
    __hip_bfloat16* as_ = &As[s][0];
    __hip_bfloat16* bs_ = &Bs[s][0];
#pragma unroll
    for (int rd = 0; rd < 4; ++rd)
      gl_lds16(A + aoffs + (size_t)rd * 65536 + k0, as_ + rd * 4096 + ldst);
#pragma unroll
    for (int rd = 0; rd < 2; ++rd)
      gl_lds16(Bt + boffs + (size_t)rd * 65536 + k0, bs_ + rd * 4096 + ldst);
  };

  const unsigned asLds = (unsigned)(uintptr_t)&As[0][0];
  const unsigned bsLds = (unsigned)(uintptr_t)&Bs[0][0];
  const unsigned aBase = asLds + 2u * ((wm*64 + lr) * 64 + ((lg ^ (lr & 7)) << 3));
  const unsigned bBase = bsLds + 2u * ((wn*64 + lr) * 64 + ((lg ^ (lr & 7)) << 3));

  stage(0, 0);
  stage(1, 1);
  VMCNT6;
  BARRIER;

  f32x4 acc[4][4] = {};
  short8 a_[4][2], b_[2][2];

#pragma unroll
  for (int t = 0; t < 16; ++t) {
    const int s = t % 3;
    const unsigned aB0 = aBase + (unsigned)s * 32768u;
    const unsigned aB1 = aB0 ^ 64u;
    const unsigned bB0 = bBase + (unsigned)s * 16384u;
    const unsigned bB1 = bB0 ^ 64u;
    if (t + 2 < 16) stage(t + 2, (t + 2) % 3);
    a_[0][0] = ldsr_o0(aB0); a_[1][0] = ldsr_o1(aB0); a_[2][0] = ldsr_o2(aB0); a_[3][0] = ldsr_o3(aB0);
    a_[0][1] = ldsr_o0(aB1); a_[1][1] = ldsr_o1(aB1); a_[2][1] = ldsr_o2(aB1); a_[3][1] = ldsr_o3(aB1);
    b_[0][0] = ldsr_o0(bB0); b_[1][0] = ldsr_o1(bB0);
    b_[0][1] = ldsr_o0(bB1); b_[1][1] = ldsr_o1(bB1);
    LGKM0;
    __builtin_amdgcn_s_setprio(1);
#pragma unroll
    for (int m = 0; m < 4; ++m)
#pragma unroll
      for (int n = 0; n < 2; ++n)
#pragma unroll
        for (int ks = 0; ks < 2; ++ks)
          acc[m][n] = mfma16(a_[m][ks], b_[n][ks], acc[m][n]);
    __builtin_amdgcn_s_setprio(0);
    b_[0][0] = ldsr_o2(bB0); b_[1][0] = ldsr_o3(bB0);
    b_[0][1] = ldsr_o2(bB1); b_[1][1] = ldsr_o3(bB1);
    LGKM0;
    __builtin_amdgcn_s_setprio(1);
#pragma unroll
    for (int m = 0; m < 4; ++m)
#pragma unroll
      for (int n = 0; n < 2; ++n)
#pragma unroll
        for (int ks = 0; ks < 2; ++ks)
          acc[m][n + 2] = mfma16(a_[m][ks], b_[n][ks], acc[m][n + 2]);
    __builtin_amdgcn_s_setprio(0);
    if (t <= 13) { VMCNT6; }
    else if (t == 14) { VMCNT0; }
    BARRIER;
  }

  __syncthreads();
#pragma unroll
  for (int n = 0; n < 4; ++n) {
    const int col = n0 + wn * 64 + n * 16 + lr;
    const float bvv = bias[col];
#pragma unroll
    for (int m = 0; m < 4; ++m)
#pragma unroll
      for (int r = 0; r < 4; ++r) {
        const int row = m0 + wm * 64 + m * 16 + lg * 4 + r;
        outF[(size_t)row * 1024 + col] = acc[m][n][r] + bvv;
      }
  }
}

// ---------------- causal flash attention (4 q-frags per wave) ----------------
// Block owns 4 q-tiles {j, 15-j, 16+j, 31-j} (uniform total work: per-wave chunk
// count = 128 for all j); 4 waves, each owning q-frag rows w*16 of every tile.
// Each 8-read K/V chunk event feeds up to 32 MFMA -> DS reads per unit work HALVED
// vs paired-tile version. Fixed-max softmax, sigma-permuted K rows (permlane redist).
__device__ __forceinline__ void tile_step(f32x4 s0, f32x4 s1, int kbase, int kmaxw, int qmb,
                                          short8 v0, short8 v1, short8 v2, short8 v3,
                                          f32x4 (&acc)[4], float& lrun) {
  if (kbase + 31 > kmaxw - 15) {       // diagonal chunk: per-element causal mask
#pragma unroll
    for (int r = 0; r < 4; ++r) {
      const int off = (r & 1) + ((r & 2) << 2);   // 0,1,8,9
      if (kbase + off > qmb)      s0[r] = -INFINITY;
      if (kbase + 16 + off > qmb) s1[r] = -INFINITY;
    }
  }
  float p0 = __builtin_amdgcn_exp2f(s0[0]), p1 = __builtin_amdgcn_exp2f(s0[1]);
  float p2 = __builtin_amdgcn_exp2f(s0[2]), p3 = __builtin_amdgcn_exp2f(s0[3]);
  float p4 = __builtin_amdgcn_exp2f(s1[0]), p5 = __builtin_amdgcn_exp2f(s1[1]);
  float p6 = __builtin_amdgcn_exp2f(s1[2]), p7 = __builtin_amdgcn_exp2f(s1[3]);
  lrun += ((p0 + p1) + (p2 + p3)) + ((p4 + p5) + (p6 + p7));
  unsigned u0 = pkbf(p0, p1);
  unsigned u1 = pkbf(p2, p3);
  unsigned u2 = pkbf(p4, p5);
  unsigned u3 = pkbf(p6, p7);
  perm16p(u0, u1);
  perm16p(u2, u3);
  perm32p(u0, u2);
  perm32p(u1, u3);
  union { unsigned u[4]; short8 s; } pw;
  pw.u[0] = u0; pw.u[1] = u2; pw.u[2] = u1; pw.u[3] = u3;
  const short8 pf = pw.s;
  acc[0] = mfma16(v0, pf, acc[0]);
  acc[1] = mfma16(v1, pf, acc[1]);
  acc[2] = mfma16(v2, pf, acc[2]);
  acc[3] = mfma16(v3, pf, acc[3]);
}

__device__ __forceinline__ void store_tile(__hip_bfloat16* Ylds, f32x4 (&acc)[4],
                                           float lrun, int q0, int w, int l,
                                           int lr, int lg, int bh,
                                           __hip_bfloat16* __restrict__ Y) {
  lrun += __shfl_xor(lrun, 16);
  lrun += __shfl_xor(lrun, 32);
  const float inv = 1.f / lrun;
#pragma unroll
  for (int nb = 0; nb < 4; ++nb) {
#pragma unroll
    for (int r = 0; r < 4; ++r) {
      const int d = nb * 16 + lg * 4 + r;
      Ylds[swz64(lr, d)] = __float2bfloat16(acc[nb][r] * inv);
    }
  }
  const int rr = l >> 2, part = l & 3;
  const int trow = q0 + w * 16 + rr;
  const int b = bh >> 4, h = bh & 15;
  short8 y0 = *reinterpret_cast<const short8*>(&Ylds[swz64(rr, part * 16)]);
  short8 y1 = *reinterpret_cast<const short8*>(&Ylds[swz64(rr, part * 16 + 8)]);
  __hip_bfloat16* dst = Y + ((size_t)b * TT + trow) * 1024 + h * 64 + part * 16;
  *reinterpret_cast<short8*>(dst) = y0;
  *reinterpret_cast<short8*>(dst + 8) = y1;
}

__global__ __launch_bounds__(256, 2) void k_flash(const __hip_bfloat16* __restrict__ Qb,
                                                  const __hip_bfloat16* __restrict__ Kb,
                                                  const __hip_bfloat16* __restrict__ Vtb,
                                                  __hip_bfloat16* __restrict__ Y) {
  __shared__ __hip_bfloat16 Klds[128 * 64];
  __shared__ __hip_bfloat16 Vtlds[64 * 128];
  const int tid = threadIdx.x;
  const int l = tid & 63, w = tid >> 6;
  const int lr = l & 15, lg = l >> 4;
  const int j  = blockIdx.x >> 6;       // tile-group index 0..7
  const int bh = blockIdx.x & 63;
  const int q0t[4] = { j * 64, (15 - j) * 64, (16 + j) * 64, (31 - j) * 64 };
  const __hip_bfloat16* Qp = Qb + (size_t)bh * TT * 64;
  const __hip_bfloat16* Kp = Kb + (size_t)bh * TT * 64;
  const __hip_bfloat16* Vp = Vtb + (size_t)bh * 64 * TT;

  short8 qf[4][2];
  int kmax[4], qmb[4];
  const int base_lg = ((lg & 1) << 2) | (lg & 2);
#pragma unroll
  for (int t = 0; t < 4; ++t) {
    const int qrow = q0t[t] + w * 16 + lr;
    qf[t][0] = *reinterpret_cast<const short8*>(Qp + (size_t)qrow * 64 + lg * 8);
    qf[t][1] = *reinterpret_cast<const short8*>(Qp + (size_t)qrow * 64 + 32 + lg * 8);
    kmax[t] = q0t[t] + w * 16 + 15;
    qmb[t] = qrow - base_lg;
  }
  f32x4 acc[4][4] = {};
  float lrun[4] = {0.f, 0.f, 0.f, 0.f};

  const int ka  = lr * 64 + ((lg ^ (lr & 7)) << 3);
  const int va  = lr * 128 + ((lg ^ (lr & 15)) << 3);

  const __hip_bfloat16* gk[4];
  const __hip_bfloat16* gv[4];
  __hip_bfloat16* lk[4];
  __hip_bfloat16* lv[4];
#pragma unroll
  for (int it = 0; it < 4; ++it) {
    int e = it * 2048 + tid * 8;
    int rowk = e >> 6;
    int lcolk = ((((e >> 3) & 7) ^ (rowk & 7)) << 3);
    int rk = rowk & 15;
    int srk = (((rk >> 1) ^ (rk >> 3)) & 1) ? (rk ^ 10) : rk;
    int rowks = (rowk & ~15) | srk;
    gk[it] = Kp + (size_t)rowks * 64 + lcolk;
    lk[it] = &Klds[e];
    int rowv = e >> 7;
    int lcolv = ((((e >> 3) & 15) ^ (rowv & 15)) << 3);
    gv[it] = Vp + (size_t)rowv * TT + lcolv;
    lv[it] = &Vtlds[e];
  }

  const int nblk = (q0t[3] + 63) / 128 + 1;   // largest tile bounds the block
  for (int blk = 0; blk < nblk; ++blk) {
    const int kv0 = blk * 128;
#pragma unroll
    for (int it = 0; it < 4; ++it) {
      gl_lds16(gk[it], lk[it]);
      gk[it] += 128 * 64;
    }
#pragma unroll
    for (int it = 0; it < 4; ++it) {
      gl_lds16(gv[it], lv[it]);
      gv[it] += 128;
    }
    __syncthreads();
#pragma unroll
    for (int kci = 0; kci < 4; ++kci) {
      const int kbase = kv0 + kci * 32;
      if (kbase > kmax[3]) break;      // wave-uniform early exit (tile 3 largest)
      // shared K fragments (serve all active tiles)
      const int kb = ka + kci * 2048;
      const short8 kf00 = *reinterpret_cast<const short8*>(&Klds[kb]);
      const short8 kf10 = *reinterpret_cast<const short8*>(&Klds[kb + 1024]);
      const short8 kf01 = *reinterpret_cast<const short8*>(&Klds[kb ^ 32]);
      const short8 kf11 = *reinterpret_cast<const short8*>(&Klds[(kb + 1024) ^ 32]);
      // shared V fragments
      const int vb = va ^ (kci * 32);
      const short8 v0 = *reinterpret_cast<const short8*>(&Vtlds[vb]);
      const short8 v1 = *reinterpret_cast<const short8*>(&Vtlds[vb + 2048]);
      const short8 v2 = *reinterpret_cast<const short8*>(&Vtlds[vb + 4096]);
      const short8 v3 = *reinterpret_cast<const short8*>(&Vtlds[vb + 6144]);
#pragma unroll
      for (int t = 0; t < 4; ++t) {
        if (t < 3 && kbase > kmax[t]) continue;   // per-tile causal skip
        f32x4 s0 = {}, s1 = {};
        s0 = mfma16(kf00, qf[t][0], s0);
        s1 = mfma16(kf10, qf[t][0], s1);
        s0 = mfma16(kf01, qf[t][1], s0);
        s1 = mfma16(kf11, qf[t][1], s1);
        tile_step(s0, s1, kbase, kmax[t], qmb[t], v0, v1, v2, v3, acc[t], lrun[t]);
      }
    }
    __syncthreads();
  }
  __hip_bfloat16* Ylds = Klds + w * 1024;
#pragma unroll
  for (int t = 0; t < 4; ++t)
    store_tile(Ylds, acc[t], lrun[t], q0t[t], w, l, lr, lg, bh, Y);
}

// ---------------- launch ----------------
extern "C" void kernel_launch(void* const* d_in, const int* in_sizes, int n_in,
                              void* d_out, int out_size, void* d_ws, size_t ws_size,
                              hipStream_t stream) {
  const float* x     = (const float*)d_in[0];
  const float* Wqkv  = (const float*)d_in[1];
  const float* bqkv  = (const float*)d_in[2];
  const float* Wproj = (const float*)d_in[3];
  const float* bproj = (const float*)d_in[4];

  char* ws = (char*)d_ws;
  size_t off = 0;
  auto alloc = [&](size_t bytes) {
    char* p = ws + off;
    off += (bytes + 255) & ~(size_t)255;
    return p;
  };
  __hip_bfloat16* xb    = (__hip_bfloat16*)alloc((size_t)MTOT * 1024 * 2);
  __hip_bfloat16* wqkvT = (__hip_bfloat16*)alloc((size_t)3072 * 1024 * 2);
  __hip_bfloat16* wpT   = (__hip_bfloat16*)alloc((size_t)1024 * 1024 * 2);
  __hip_bfloat16* Qb    = (__hip_bfloat16*)alloc((size_t)64 * TT * 64 * 2);
  __hip_bfloat16* Kb    = (__hip_bfloat16*)alloc((size_t)64 * TT * 64 * 2);
  __hip_bfloat16* Vtb   = (__hip_bfloat16*)alloc((size_t)64 * TT * 64 * 2);
  __hip_bfloat16* Yb    = (__hip_bfloat16*)alloc((size_t)MTOT * 1024 * 2);

  k_cvt<<<(MTOT * 1024 / 8 + 255) / 256, 256, 0, stream>>>(x, xb, MTOT * 1024 / 8);
  k_transpose_cvt<<<dim3(3072 / 32, 1024 / 32), 256, 0, stream>>>(Wqkv, wqkvT, 1024, 3072);
  k_transpose_cvt<<<dim3(1024 / 32, 1024 / 32), 256, 0, stream>>>(Wproj, wpT, 1024, 1024);
  k_gemm3<<<dim3(32, 16), 512, 0, stream>>>(xb, wqkvT, bqkv, Qb, Kb, Vtb);
  k_flash<<<8 * 64, 256, 0, stream>>>(Qb, Kb, Vtb, Yb);
  k_gemm2<<<dim3(32, 8), 512, 0, stream>>>(Yb, wpT, bproj, (float*)d_out);
}

// Round 15
// 145.145 us; speedup vs baseline: 1.3054x; 1.0202x over previous
//
#include <hip/hip_runtime.h>
#include <hip/hip_bf16.h>
#include <cstdint>
#include <math.h>

// Problem constants
#define DM   1024
#define NH   16
#define DH   64
#define BB   4
#define TT   2048
#define MTOT (BB*TT)   // 8192 rows

using short8 = __attribute__((ext_vector_type(8))) short;  // 8 bf16 (4 VGPRs)
using f32x4  = __attribute__((ext_vector_type(4))) float;

__device__ __forceinline__ f32x4 mfma16(short8 a, short8 b, f32x4 c) {
  return __builtin_amdgcn_mfma_f32_16x16x32_bf16(a, b, c, 0, 0, 0);
}

typedef const __attribute__((address_space(1))) unsigned int* as1_u32p;
typedef __attribute__((address_space(3))) unsigned int*       as3_u32p;

// async global->LDS, 16B per lane; LDS dest = wave-uniform base + lane*16 (linear)
__device__ __forceinline__ void gl_lds16(const void* g, void* l) {
  __builtin_amdgcn_global_load_lds(
      (as1_u32p)(reinterpret_cast<uintptr_t>(g)),
      (as3_u32p)((unsigned int)(reinterpret_cast<uintptr_t>(l))),
      16, 0, 0);
}

// XOR swizzle for tiles with 64-elem (128B) rows: 8 slots of 8 bf16; slot ^= row&7
__device__ __forceinline__ int swz64(int row, int col) {
  return row*64 + ((((col >> 3) ^ (row & 7)) << 3) | (col & 7));
}

__device__ __forceinline__ unsigned pkbf(float a, float b) {
  __hip_bfloat162 h = __float22bfloat162_rn(make_float2(a, b)); // x=lo, y=hi
  return *reinterpret_cast<unsigned*>(&h);
}

// permlane swaps (VALU pipe). Verified row semantics (involutions):
// perm16(d,s): d'=[d0,s0,d2,s2], s'=[d1,s1,d3,s3]   (16-lane rows)
// perm32(d,s): d'=[d0,d1,s0,s1], s'=[d2,d3,s2,s3]
__device__ __forceinline__ void perm16p(unsigned &a, unsigned &b) {
  asm("v_permlane16_swap_b32 %0, %1" : "+v"(a), "+v"(b));
}
__device__ __forceinline__ void perm32p(unsigned &a, unsigned &b) {
  asm("v_permlane32_swap_b32 %0, %1" : "+v"(a), "+v"(b));
}

// inline-asm LDS reads (opaque to alias analysis: no compiler-inserted vmcnt drains)
__device__ __forceinline__ short8 ldsr_o0(unsigned a) {
  short8 r; asm volatile("ds_read_b128 %0, %1" : "=v"(r) : "v"(a)); return r;
}
__device__ __forceinline__ short8 ldsr_o1(unsigned a) {
  short8 r; asm volatile("ds_read_b128 %0, %1 offset:2048" : "=v"(r) : "v"(a)); return r;
}
__device__ __forceinline__ short8 ldsr_o2(unsigned a) {
  short8 r; asm volatile("ds_read_b128 %0, %1 offset:4096" : "=v"(r) : "v"(a)); return r;
}
__device__ __forceinline__ short8 ldsr_o3(unsigned a) {
  short8 r; asm volatile("ds_read_b128 %0, %1 offset:6144" : "=v"(r) : "v"(a)); return r;
}
__device__ __forceinline__ short8 ldsr_o4(unsigned a) {
  short8 r; asm volatile("ds_read_b128 %0, %1 offset:8192" : "=v"(r) : "v"(a)); return r;
}
__device__ __forceinline__ short8 ldsr_o5(unsigned a) {
  short8 r; asm volatile("ds_read_b128 %0, %1 offset:10240" : "=v"(r) : "v"(a)); return r;
}

#define LGKM0  do { asm volatile("s_waitcnt lgkmcnt(0)"); __builtin_amdgcn_sched_barrier(0); } while(0)
#define VMCNT0 do { __builtin_amdgcn_sched_barrier(0); asm volatile("s_waitcnt vmcnt(0)"); __builtin_amdgcn_sched_barrier(0); } while(0)
#define BARRIER do { __builtin_amdgcn_s_barrier(); __builtin_amdgcn_sched_barrier(0); } while(0)

// ---------------- fp32 -> bf16 copy convert ----------------
__global__ __launch_bounds__(256) void k_cvt(const float* __restrict__ in,
                                             __hip_bfloat16* __restrict__ out, int n8) {
  int i = blockIdx.x * 256 + threadIdx.x;
  if (i >= n8) return;
  const float* p = in + (size_t)i * 8;
  short8 o;
#pragma unroll
  for (int j = 0; j < 8; ++j) {
    __hip_bfloat16 h = __float2bfloat16(p[j]);
    o[j] = *reinterpret_cast<short*>(&h);
  }
  *reinterpret_cast<short8*>(out + (size_t)i * 8) = o;
}

// ---------------- W [K][N] fp32 -> Wt [N][K] bf16 (tiled transpose) ----------------
__global__ __launch_bounds__(256) void k_transpose_cvt(const float* __restrict__ W,
                                                       __hip_bfloat16* __restrict__ Wt,
                                                       int K, int N) {
  __shared__ float tbuf[32][33];
  const int n0 = blockIdx.x * 32, k0 = blockIdx.y * 32;
  const int tx = threadIdx.x & 31, ty = threadIdx.x >> 5;
#pragma unroll
  for (int i = 0; i < 4; ++i)
    tbuf[ty + i*8][tx] = W[(size_t)(k0 + ty + i*8) * N + n0 + tx];
  __syncthreads();
#pragma unroll
  for (int i = 0; i < 4; ++i)
    Wt[(size_t)(n0 + ty + i*8) * K + k0 + tx] = __float2bfloat16(tbuf[tx][ty + i*8]);
}

// ---------------- 256x192 double-buffered deep-pipeline QKV GEMM (r9-proven, 65us) ----------------
__global__ __launch_bounds__(512, 2) void k_gemm3(const __hip_bfloat16* __restrict__ A,
                                                  const __hip_bfloat16* __restrict__ Bt,
                                                  const float* __restrict__ bias,
                                                  __hip_bfloat16* __restrict__ Qb,
                                                  __hip_bfloat16* __restrict__ Kb,
                                                  __hip_bfloat16* __restrict__ Vtb) {
  __shared__ __hip_bfloat16 As[2][256 * 64];
  __shared__ __hip_bfloat16 Bs[2][192 * 64];
  const int tid = threadIdx.x;
  const int l = tid & 63, w = tid >> 6;
  const int lr = l & 15, lg = l >> 4;
  const int wm = w >> 1, wn = w & 1;
  const int m0 = blockIdx.x * 256, n0 = blockIdx.y * 192;

  const int srow = tid >> 3;
  const int scol = (((tid & 7) ^ (srow & 7)) << 3);
  const size_t aoffs = (size_t)(m0 + srow) * 1024 + scol;
  const size_t boffs = (size_t)(n0 + srow) * 1024 + scol;
  const int ldst = tid * 8;

  auto stage = [&](int t, int s) {
    const int k0 = t * 64;
#pragma unroll
    for (int rd = 0; rd < 4; ++rd)
      gl_lds16(A + aoffs + (size_t)rd * 65536 + k0, &As[s][rd * 4096 + ldst]);
#pragma unroll
    for (int rd = 0; rd < 3; ++rd)
      gl_lds16(Bt + boffs + (size_t)rd * 65536 + k0, &Bs[s][rd * 4096 + ldst]);
  };

  const unsigned asLds = (unsigned)(uintptr_t)&As[0][0];
  const unsigned bsLds = (unsigned)(uintptr_t)&Bs[0][0];
  const unsigned aBase0 = asLds + 2u * ((wm*64 + lr) * 64 + ((lg ^ (lr & 7)) << 3));
  const unsigned bBase0 = bsLds + 2u * ((wn*96 + lr) * 64 + ((lg ^ (lr & 7)) << 3));

  stage(0, 0);
  VMCNT0;
  BARRIER;

  f32x4 acc[4][6] = {};
  short8 a_[4][2], b_[3][2];

#pragma unroll
  for (int t = 0; t < 16; ++t) {
    const int s = t & 1;
    const unsigned aB0 = aBase0 + (unsigned)s * 32768u;
    const unsigned aB1 = aB0 ^ 64u;
    const unsigned bB0 = bBase0 + (unsigned)s * 24576u;
    const unsigned bB1 = bB0 ^ 64u;
    if (t < 15) stage(t + 1, s ^ 1);
    // phase A: A frags + B n0..2, MFMA n=0..2
    a_[0][0] = ldsr_o0(aB0); a_[1][0] = ldsr_o1(aB0); a_[2][0] = ldsr_o2(aB0); a_[3][0] = ldsr_o3(aB0);
    a_[0][1] = ldsr_o0(aB1); a_[1][1] = ldsr_o1(aB1); a_[2][1] = ldsr_o2(aB1); a_[3][1] = ldsr_o3(aB1);
    b_[0][0] = ldsr_o0(bB0); b_[1][0] = ldsr_o1(bB0); b_[2][0] = ldsr_o2(bB0);
    b_[0][1] = ldsr_o0(bB1); b_[1][1] = ldsr_o1(bB1); b_[2][1] = ldsr_o2(bB1);
    LGKM0;
    __builtin_amdgcn_s_setprio(1);
#pragma unroll
    for (int m = 0; m < 4; ++m)
#pragma unroll
      for (int n = 0; n < 3; ++n)
#pragma unroll
        for (int ks = 0; ks < 2; ++ks)
          acc[m][n] = mfma16(a_[m][ks], b_[n][ks], acc[m][n]);
    __builtin_amdgcn_s_setprio(0);
    // phase B: B n3..5, MFMA n=3..5
    b_[0][0] = ldsr_o3(bB0); b_[1][0] = ldsr_o4(bB0); b_[2][0] = ldsr_o5(bB0);
    b_[0][1] = ldsr_o3(bB1); b_[1][1] = ldsr_o4(bB1); b_[2][1] = ldsr_o5(bB1);
    LGKM0;
    __builtin_amdgcn_s_setprio(1);
#pragma unroll
    for (int m = 0; m < 4; ++m)
#pragma unroll
      for (int n = 0; n < 3; ++n)
#pragma unroll
        for (int ks = 0; ks < 2; ++ks)
          acc[m][n + 3] = mfma16(a_[m][ks], b_[n][ks], acc[m][n + 3]);
    __builtin_amdgcn_s_setprio(0);
    if (t < 15) { VMCNT0; }
    BARRIER;
  }

  __syncthreads();
  // ---- per-16-col-group LDS-bounce epilogue ----
  __hip_bfloat16* reg = (w < 4) ? (&As[0][0] + w * 6144)
                                : (&Bs[0][0] + (w - 4) * 6144);
  const int colbase = n0 + wn * 96;
  const int rowbase = m0 + wm * 64;
  const int bidx = rowbase >> 11;
  const int tbase = rowbase & 2047;
  const float qs = 0.18033688011112042f;   // 0.125 * log2(e) folded into Q
  float bv[6];
#pragma unroll
  for (int g = 0; g < 6; ++g) bv[g] = bias[colbase + g * 16 + lr];
#pragma unroll
  for (int g = 0; g < 6; ++g) {
    const int cg0 = colbase + g * 16;
    const int which = cg0 >> 10;
    __hip_bfloat16* rg = reg + g * 1024;
    if (which == 2) {
#pragma unroll
      for (int m = 0; m < 4; ++m)
#pragma unroll
        for (int r = 0; r < 4; ++r) {
          const int t = m * 16 + lg * 4 + r;
          rg[lr * 64 + (t ^ ((lr & 7) << 3))] = __float2bfloat16(acc[m][g][r] + bv[g]);
        }
    } else {
      const float sc = (which == 0) ? qs : 1.f;
#pragma unroll
      for (int m = 0; m < 4; ++m)
#pragma unroll
        for (int r = 0; r < 4; ++r) {
          const int t = m * 16 + lg * 4 + r;
          rg[t * 16 + (lr ^ (((t >> 2) & 1) << 3))] =
              __float2bfloat16((acc[m][g][r] + bv[g]) * sc);
        }
    }
  }
#pragma unroll
  for (int g = 0; g < 6; ++g) {
    const int cg0 = colbase + g * 16;
    const int which = cg0 >> 10;
    const int hh = (cg0 >> 6) & 15;
    const int dd0 = cg0 & 48;
    const size_t bh = (size_t)bidx * 16 + hh;
    const __hip_bfloat16* rg = reg + g * 1024;
    if (which < 2) {
      __hip_bfloat16* basep = (which == 0) ? Qb : Kb;
      const int t = l;
      const int Xc = ((t >> 2) & 1) << 3;
      short8 y0 = *reinterpret_cast<const short8*>(&rg[t * 16 + Xc]);
      short8 y1 = *reinterpret_cast<const short8*>(&rg[t * 16 + (Xc ^ 8)]);
      __hip_bfloat16* dst = basep + (bh * TT + tbase + t) * 64 + dd0;
      *reinterpret_cast<short8*>(dst) = y0;
      *reinterpret_cast<short8*>(dst + 8) = y1;
    } else {
      const int dd = l >> 2, tseg = l & 3;
      const int X = (dd & 7) << 3;
      const int S0 = (((tseg ^ (X >> 4)) & 3) << 4) | (X & 8);
      short8 y0 = *reinterpret_cast<const short8*>(&rg[dd * 64 + S0]);
      short8 y1 = *reinterpret_cast<const short8*>(&rg[dd * 64 + (S0 ^ 8)]);
      __hip_bfloat16* dst = Vtb + (bh * 64 + dd0 + dd) * TT + tbase + tseg * 16;
      *reinterpret_cast<short8*>(dst) = y0;
      *reinterpret_cast<short8*>(dst + 8) = y1;
    }
  }
}

// ---------------- 128x128 double-buffered dist-1 GEMM (proj), 2 blocks/CU ----------------
// 256 threads / 4 waves (2m x 2n), per-wave 64x64 (acc[4][4]). LDS 64KB -> 2 blocks/CU:
// the vmcnt(0) stall of one block hides under the co-resident block's MFMA.
__global__ __launch_bounds__(256, 2) void k_gemm2(const __hip_bfloat16* __restrict__ A,
                                                  const __hip_bfloat16* __restrict__ Bt,
                                                  const float* __restrict__ bias,
                                                  float* __restrict__ outF) {
  __shared__ __hip_bfloat16 As[2][128 * 64];
  __shared__ __hip_bfloat16 Bs[2][128 * 64];
  const int tid = threadIdx.x;
  const int l = tid & 63, w = tid >> 6;
  const int lr = l & 15, lg = l >> 4;
  const int wm = w >> 1, wn = w & 1;
  const int m0 = blockIdx.x * 128, n0 = blockIdx.y * 128;

  const int srow = tid >> 3;                 // 0..31
  const int scol = (((tid & 7) ^ (srow & 7)) << 3);
  const size_t aoffs = (size_t)(m0 + srow) * 1024 + scol;
  const size_t boffs = (size_t)(n0 + srow) * 1024 + scol;
  const int ldst = tid * 8;

  auto stage = [&](int t, int s) {
    const int k0 = t * 64;
#pragma unroll
    for (int rd = 0; rd < 4; ++rd) {
      gl_lds16(A + aoffs + (size_t)rd * 32768 + k0, &As[s][rd * 2048 + ldst]);
      gl_lds16(Bt + boffs + (size_t)rd * 32768 + k0, &Bs[s][rd * 2048 + ldst]);
    }
  };

  const unsigned asLds = (unsigned)(uintptr_t)&As[0][0];
  const unsigned bsLds = (unsigned)(uintptr_t)&Bs[0][0];
  const unsigned aBase0 = asLds + 2u * ((wm*64 + lr) * 64 + ((lg ^ (lr & 7)) << 3));
  const unsigned bBase0 = bsLds + 2u * ((wn*64 + lr) * 64 + ((lg ^ (lr & 7)) << 3));

  stage(0, 0);
  VMCNT0;
  BARRIER;

  f32x4 acc[4][4] = {};
  short8 a_[4][2], b_[4][2];

#pragma unroll
  for (int t = 0; t < 16; ++t) {
    const int s = t & 1;
    const unsigned aB0 = aBase0 + (unsigned)s * 16384u;
    const unsigned aB1 = aB0 ^ 64u;
    const unsigned bB0 = bBase0 + (unsigned)s * 16384u;
    const unsigned bB1 = bB0 ^ 64u;
    if (t < 15) stage(t + 1, s ^ 1);
    a_[0][0] = ldsr_o0(aB0); a_[1][0] = ldsr_o1(aB0); a_[2][0] = ldsr_o2(aB0); a_[3][0] = ldsr_o3(aB0);
    a_[0][1] = ldsr_o0(aB1); a_[1][1] = ldsr_o1(aB1); a_[2][1] = ldsr_o2(aB1); a_[3][1] = ldsr_o3(aB1);
    b_[0][0] = ldsr_o0(bB0); b_[1][0] = ldsr_o1(bB0); b_[2][0] = ldsr_o2(bB0); b_[3][0] = ldsr_o3(bB0);
    b_[0][1] = ldsr_o0(bB1); b_[1][1] = ldsr_o1(bB1); b_[2][1] = ldsr_o2(bB1); b_[3][1] = ldsr_o3(bB1);
    LGKM0;
    __builtin_amdgcn_s_setprio(1);
#pragma unroll
    for (int m = 0; m < 4; ++m)
#pragma unroll
      for (int n = 0; n < 4; ++n)
#pragma unroll
        for (int ks = 0; ks < 2; ++ks)
          acc[m][n] = mfma16(a_[m][ks], b_[n][ks], acc[m][n]);
    __builtin_amdgcn_s_setprio(0);
    if (t < 15) { VMCNT0; }
    BARRIER;
  }

  __syncthreads();
#pragma unroll
  for (int n = 0; n < 4; ++n) {
    const int col = n0 + wn * 64 + n * 16 + lr;
    const float bvv = bias[col];
#pragma unroll
    for (int m = 0; m < 4; ++m)
#pragma unroll
      for (int r = 0; r < 4; ++r) {
        const int row = m0 + wm * 64 + m * 16 + lg * 4 + r;
        outF[(size_t)row * 1024 + col] = acc[m][n][r] + bvv;
      }
  }
}

// ---------------- causal flash attention (r9-proven merged paired q-tiles) ----------------
// Fixed-max softmax, sigma-permuted K rows -> P redistribution is exactly
// 2x permlane16_swap + 2x permlane32_swap. Shared K/V frag reads serve both tiles.
__device__ __forceinline__ void tile_step(f32x4 s0, f32x4 s1, int kbase, int kmaxw, int qmb,
                                          short8 v0, short8 v1, short8 v2, short8 v3,
                                          f32x4 (&acc)[4], float& lrun) {
  if (kbase + 31 > kmaxw - 15) {       // diagonal chunk: per-element causal mask
#pragma unroll
    for (int r = 0; r < 4; ++r) {
      const int off = (r & 1) + ((r & 2) << 2);   // 0,1,8,9
      if (kbase + off > qmb)      s0[r] = -INFINITY;
      if (kbase + 16 + off > qmb) s1[r] = -INFINITY;
    }
  }
  float p0 = __builtin_amdgcn_exp2f(s0[0]), p1 = __builtin_amdgcn_exp2f(s0[1]);
  float p2 = __builtin_amdgcn_exp2f(s0[2]), p3 = __builtin_amdgcn_exp2f(s0[3]);
  float p4 = __builtin_amdgcn_exp2f(s1[0]), p5 = __builtin_amdgcn_exp2f(s1[1]);
  float p6 = __builtin_amdgcn_exp2f(s1[2]), p7 = __builtin_amdgcn_exp2f(s1[3]);
  lrun += ((p0 + p1) + (p2 + p3)) + ((p4 + p5) + (p6 + p7));
  unsigned u0 = pkbf(p0, p1);
  unsigned u1 = pkbf(p2, p3);
  unsigned u2 = pkbf(p4, p5);
  unsigned u3 = pkbf(p6, p7);
  perm16p(u0, u1);
  perm16p(u2, u3);
  perm32p(u0, u2);
  perm32p(u1, u3);
  union { unsigned u[4]; short8 s; } pw;
  pw.u[0] = u0; pw.u[1] = u2; pw.u[2] = u1; pw.u[3] = u3;
  const short8 pf = pw.s;
  acc[0] = mfma16(v0, pf, acc[0]);
  acc[1] = mfma16(v1, pf, acc[1]);
  acc[2] = mfma16(v2, pf, acc[2]);
  acc[3] = mfma16(v3, pf, acc[3]);
}

__device__ __forceinline__ void store_tile(__hip_bfloat16* Ylds, f32x4 (&acc)[4],
                                           float lrun, int q0, int w, int l,
                                           int lr, int lg, int bh,
                                           __hip_bfloat16* __restrict__ Y) {
  lrun += __shfl_xor(lrun, 16);
  lrun += __shfl_xor(lrun, 32);
  const float inv = 1.f / lrun;
#pragma unroll
  for (int nb = 0; nb < 4; ++nb) {
#pragma unroll
    for (int r = 0; r < 4; ++r) {
      const int d = nb * 16 + lg * 4 + r;
      Ylds[swz64(lr, d)] = __float2bfloat16(acc[nb][r] * inv);
    }
  }
  const int rr = l >> 2, part = l & 3;
  const int trow = q0 + w * 16 + rr;
  const int b = bh >> 4, h = bh & 15;
  short8 y0 = *reinterpret_cast<const short8*>(&Ylds[swz64(rr, part * 16)]);
  short8 y1 = *reinterpret_cast<const short8*>(&Ylds[swz64(rr, part * 16 + 8)]);
  __hip_bfloat16* dst = Y + ((size_t)b * TT + trow) * 1024 + h * 64 + part * 16;
  *reinterpret_cast<short8*>(dst) = y0;
  *reinterpret_cast<short8*>(dst + 8) = y1;
}

__global__ __launch_bounds__(256, 4) void k_flash(const __hip_bfloat16* __restrict__ Qb,
                                                  const __hip_bfloat16* __restrict__ Kb,
                                                  const __hip_bfloat16* __restrict__ Vtb,
                                                  __hip_bfloat16* __restrict__ Y) {
  __shared__ __hip_bfloat16 Klds[128 * 64];
  __shared__ __hip_bfloat16 Vtlds[64 * 128];
  const int tid = threadIdx.x;
  const int l = tid & 63, w = tid >> 6;
  const int lr = l & 15, lg = l >> 4;
  const int p  = blockIdx.x >> 6;       // pair index 0..15
  const int bh = blockIdx.x & 63;
  const int q0A = p * 64, q0B = (31 - p) * 64;
  const __hip_bfloat16* Qp = Qb + (size_t)bh * TT * 64;
  const __hip_bfloat16* Kp = Kb + (size_t)bh * TT * 64;
  const __hip_bfloat16* Vp = Vtb + (size_t)bh * 64 * TT;
  const int qrowA = q0A + w * 16 + lr;
  const int qrowB = q0B + w * 16 + lr;
  const short8 qfA0 = *reinterpret_cast<const short8*>(Qp + (size_t)qrowA * 64 + lg * 8);
  const short8 qfA1 = *reinterpret_cast<const short8*>(Qp + (size_t)qrowA * 64 + 32 + lg * 8);
  const short8 qfB0 = *reinterpret_cast<const short8*>(Qp + (size_t)qrowB * 64 + lg * 8);
  const short8 qfB1 = *reinterpret_cast<const short8*>(Qp + (size_t)qrowB * 64 + 32 + lg * 8);
  f32x4 accA[4] = {}, accB[4] = {};
  float lA = 0.f, lB = 0.f;

  const int ka  = lr * 64 + ((lg ^ (lr & 7)) << 3);
  const int va  = lr * 128 + ((lg ^ (lr & 15)) << 3);

  const __hip_bfloat16* gk[4];
  const __hip_bfloat16* gv[4];
  __hip_bfloat16* lk[4];
  __hip_bfloat16* lv[4];
#pragma unroll
  for (int it = 0; it < 4; ++it) {
    int e = it * 2048 + tid * 8;
    int rowk = e >> 6;
    int lcolk = ((((e >> 3) & 7) ^ (rowk & 7)) << 3);
    int rk = rowk & 15;
    int srk = (((rk >> 1) ^ (rk >> 3)) & 1) ? (rk ^ 10) : rk;
    int rowks = (rowk & ~15) | srk;
    gk[it] = Kp + (size_t)rowks * 64 + lcolk;
    lk[it] = &Klds[e];
    int rowv = e >> 7;
    int lcolv = ((((e >> 3) & 15) ^ (rowv & 15)) << 3);
    gv[it] = Vp + (size_t)rowv * TT + lcolv;
    lv[it] = &Vtlds[e];
  }

  const int kmaxwA = q0A + w * 16 + 15;
  const int kmaxwB = q0B + w * 16 + 15;
  const int base_lg = ((lg & 1) << 2) | (lg & 2);
  const int qmbA = qrowA - base_lg;
  const int qmbB = qrowB - base_lg;
  const int nblk = (q0B + 63) / 128 + 1;
  for (int blk = 0; blk < nblk; ++blk) {
    const int kv0 = blk * 128;
#pragma unroll
    for (int it = 0; it < 4; ++it) {
      gl_lds16(gk[it], lk[it]);
      gk[it] += 128 * 64;
    }
#pragma unroll
    for (int it = 0; it < 4; ++it) {
      gl_lds16(gv[it], lv[it]);
      gv[it] += 128;
    }
    __syncthreads();
#pragma unroll
    for (int kci = 0; kci < 4; ++kci) {
      const int kbase = kv0 + kci * 32;
      if (kbase > kmaxwB) break;
      const int kb = ka + kci * 2048;
      const short8 kf00 = *reinterpret_cast<const short8*>(&Klds[kb]);
      const short8 kf10 = *reinterpret_cast<const short8*>(&Klds[kb + 1024]);
      const short8 kf01 = *reinterpret_cast<const short8*>(&Klds[kb ^ 32]);
      const short8 kf11 = *reinterpret_cast<const short8*>(&Klds[(kb + 1024) ^ 32]);
      f32x4 sB0 = {}, sB1 = {};
      sB0 = mfma16(kf00, qfB0, sB0);
      sB1 = mfma16(kf10, qfB0, sB1);
      sB0 = mfma16(kf01, qfB1, sB0);
      sB1 = mfma16(kf11, qfB1, sB1);
      const bool aAct = (kbase <= kmaxwA);
      f32x4 sA0 = {}, sA1 = {};
      if (aAct) {
        sA0 = mfma16(kf00, qfA0, sA0);
        sA1 = mfma16(kf10, qfA0, sA1);
        sA0 = mfma16(kf01, qfA1, sA0);
        sA1 = mfma16(kf11, qfA1, sA1);
      }
      const int vb = va ^ (kci * 32);
      const short8 v0 = *reinterpret_cast<const short8*>(&Vtlds[vb]);
      const short8 v1 = *reinterpret_cast<const short8*>(&Vtlds[vb + 2048]);
      const short8 v2 = *reinterpret_cast<const short8*>(&Vtlds[vb + 4096]);
      const short8 v3 = *reinterpret_cast<const short8*>(&Vtlds[vb + 6144]);
      tile_step(sB0, sB1, kbase, kmaxwB, qmbB, v0, v1, v2, v3, accB, lB);
      if (aAct)
        tile_step(sA0, sA1, kbase, kmaxwA, qmbA, v0, v1, v2, v3, accA, lA);
    }
    __syncthreads();
  }
  __hip_bfloat16* Ylds = Klds + w * 1024;
  store_tile(Ylds, accA, lA, q0A, w, l, lr, lg, bh, Y);
  store_tile(Ylds, accB, lB, q0B, w, l, lr, lg, bh, Y);
}

// ---------------- launch ----------------
extern "C" void kernel_launch(void* const* d_in, const int* in_sizes, int n_in,
                              void* d_out, int out_size, void* d_ws, size_t ws_size,
                              hipStream_t stream) {
  const float* x     = (const float*)d_in[0];
  const float* Wqkv  = (const float*)d_in[1];
  const float* bqkv  = (const float*)d_in[2];
  const float* Wproj = (const float*)d_in[3];
  const float* bproj = (const float*)d_in[4];

  char* ws = (char*)d_ws;
  size_t off = 0;
  auto alloc = [&](size_t bytes) {
    char* p = ws + off;
    off += (bytes + 255) & ~(size_t)255;
    return p;
  };
  __hip_bfloat16* xb    = (__hip_bfloat16*)alloc((size_t)MTOT * 1024 * 2);
  __hip_bfloat16* wqkvT = (__hip_bfloat16*)alloc((size_t)3072 * 1024 * 2);
  __hip_bfloat16* wpT   = (__hip_bfloat16*)alloc((size_t)1024 * 1024 * 2);
  __hip_bfloat16* Qb    = (__hip_bfloat16*)alloc((size_t)64 * TT * 64 * 2);
  __hip_bfloat16* Kb    = (__hip_bfloat16*)alloc((size_t)64 * TT * 64 * 2);
  __hip_bfloat16* Vtb   = (__hip_bfloat16*)alloc((size_t)64 * TT * 64 * 2);
  __hip_bfloat16* Yb    = (__hip_bfloat16*)alloc((size_t)MTOT * 1024 * 2);

  k_cvt<<<(MTOT * 1024 / 8 + 255) / 256, 256, 0, stream>>>(x, xb, MTOT * 1024 / 8);
  k_transpose_cvt<<<dim3(3072 / 32, 1024 / 32), 256, 0, stream>>>(Wqkv, wqkvT, 1024, 3072);
  k_transpose_cvt<<<dim3(1024 / 32, 1024 / 32), 256, 0, stream>>>(Wproj, wpT, 1024, 1024);
  k_gemm3<<<dim3(32, 16), 512, 0, stream>>>(xb, wqkvT, bqkv, Qb, Kb, Vtb);
  k_flash<<<16 * 64, 256, 0, stream>>>(Qb, Kb, Vtb, Yb);
  k_gemm2<<<dim3(64, 8), 256, 0, stream>>>(Yb, wpT, bproj, (float*)d_out);
}

// Round 16
// 140.278 us; speedup vs baseline: 1.3507x; 1.0347x over previous
//
#include <hip/hip_runtime.h>
#include <hip/hip_bf16.h>
#include <cstdint>
#include <math.h>

// Problem constants
#define DM   1024
#define NH   16
#define DH   64
#define BB   4
#define TT   2048
#define MTOT (BB*TT)   // 8192 rows

using short8 = __attribute__((ext_vector_type(8))) short;  // 8 bf16 (4 VGPRs)
using f32x4  = __attribute__((ext_vector_type(4))) float;

__device__ __forceinline__ f32x4 mfma16(short8 a, short8 b, f32x4 c) {
  return __builtin_amdgcn_mfma_f32_16x16x32_bf16(a, b, c, 0, 0, 0);
}

typedef const __attribute__((address_space(1))) unsigned int* as1_u32p;
typedef __attribute__((address_space(3))) unsigned int*       as3_u32p;

// async global->LDS, 16B per lane; LDS dest = wave-uniform base + lane*16 (linear)
__device__ __forceinline__ void gl_lds16(const void* g, void* l) {
  __builtin_amdgcn_global_load_lds(
      (as1_u32p)(reinterpret_cast<uintptr_t>(g)),
      (as3_u32p)((unsigned int)(reinterpret_cast<uintptr_t>(l))),
      16, 0, 0);
}

// XOR swizzle for tiles with 64-elem (128B) rows: 8 slots of 8 bf16; slot ^= row&7
__device__ __forceinline__ int swz64(int row, int col) {
  return row*64 + ((((col >> 3) ^ (row & 7)) << 3) | (col & 7));
}

__device__ __forceinline__ unsigned pkbf(float a, float b) {
  __hip_bfloat162 h = __float22bfloat162_rn(make_float2(a, b)); // x=lo, y=hi
  return *reinterpret_cast<unsigned*>(&h);
}

// permlane swaps (VALU pipe). Verified row semantics (involutions):
// perm16(d,s): d'=[d0,s0,d2,s2], s'=[d1,s1,d3,s3]   (16-lane rows)
// perm32(d,s): d'=[d0,d1,s0,s1], s'=[d2,d3,s2,s3]
__device__ __forceinline__ void perm16p(unsigned &a, unsigned &b) {
  asm("v_permlane16_swap_b32 %0, %1" : "+v"(a), "+v"(b));
}
__device__ __forceinline__ void perm32p(unsigned &a, unsigned &b) {
  asm("v_permlane32_swap_b32 %0, %1" : "+v"(a), "+v"(b));
}

// inline-asm LDS reads (opaque to alias analysis: no compiler-inserted vmcnt drains)
__device__ __forceinline__ short8 ldsr_o0(unsigned a) {
  short8 r; asm volatile("ds_read_b128 %0, %1" : "=v"(r) : "v"(a)); return r;
}
__device__ __forceinline__ short8 ldsr_o1(unsigned a) {
  short8 r; asm volatile("ds_read_b128 %0, %1 offset:2048" : "=v"(r) : "v"(a)); return r;
}
__device__ __forceinline__ short8 ldsr_o2(unsigned a) {
  short8 r; asm volatile("ds_read_b128 %0, %1 offset:4096" : "=v"(r) : "v"(a)); return r;
}
__device__ __forceinline__ short8 ldsr_o3(unsigned a) {
  short8 r; asm volatile("ds_read_b128 %0, %1 offset:6144" : "=v"(r) : "v"(a)); return r;
}
__device__ __forceinline__ short8 ldsr_o4(unsigned a) {
  short8 r; asm volatile("ds_read_b128 %0, %1 offset:8192" : "=v"(r) : "v"(a)); return r;
}
__device__ __forceinline__ short8 ldsr_o5(unsigned a) {
  short8 r; asm volatile("ds_read_b128 %0, %1 offset:10240" : "=v"(r) : "v"(a)); return r;
}

#define LGKM0  do { asm volatile("s_waitcnt lgkmcnt(0)"); __builtin_amdgcn_sched_barrier(0); } while(0)
#define VMCNT0 do { __builtin_amdgcn_sched_barrier(0); asm volatile("s_waitcnt vmcnt(0)"); __builtin_amdgcn_sched_barrier(0); } while(0)
#define BARRIER do { __builtin_amdgcn_s_barrier(); __builtin_amdgcn_sched_barrier(0); } while(0)

// ---------------- fp32 -> bf16 copy convert ----------------
__global__ __launch_bounds__(256) void k_cvt(const float* __restrict__ in,
                                             __hip_bfloat16* __restrict__ out, int n8) {
  int i = blockIdx.x * 256 + threadIdx.x;
  if (i >= n8) return;
  const float* p = in + (size_t)i * 8;
  short8 o;
#pragma unroll
  for (int j = 0; j < 8; ++j) {
    __hip_bfloat16 h = __float2bfloat16(p[j]);
    o[j] = *reinterpret_cast<short*>(&h);
  }
  *reinterpret_cast<short8*>(out + (size_t)i * 8) = o;
}

// ---------------- W [K][N] fp32 -> Wt [N][K] bf16 (tiled transpose) ----------------
__global__ __launch_bounds__(256) void k_transpose_cvt(const float* __restrict__ W,
                                                       __hip_bfloat16* __restrict__ Wt,
                                                       int K, int N) {
  __shared__ float tbuf[32][33];
  const int n0 = blockIdx.x * 32, k0 = blockIdx.y * 32;
  const int tx = threadIdx.x & 31, ty = threadIdx.x >> 5;
#pragma unroll
  for (int i = 0; i < 4; ++i)
    tbuf[ty + i*8][tx] = W[(size_t)(k0 + ty + i*8) * N + n0 + tx];
  __syncthreads();
#pragma unroll
  for (int i = 0; i < 4; ++i)
    Wt[(size_t)(n0 + ty + i*8) * K + k0 + tx] = __float2bfloat16(tbuf[tx][ty + i*8]);
}

// ---------------- 128x192 double-buffered QKV GEMM, 2 blocks/CU ----------------
// 512 threads / 8 waves (2m x 4n), per-wave 64x48 (acc[4][3], ~110 VGPR).
// LDS = (128+192)*64*2*2B = 80KB -> exactly 2 blocks/CU (160KB pool): one block's
// vmcnt(0)/barrier stall hides under the co-resident block's MFMA (proj-validated).
// Grid 64x16 = 1024 blocks = 2 exact rounds; grid.x-consecutive blocks share a B panel.
__global__ __launch_bounds__(512, 4) void k_gemm3(const __hip_bfloat16* __restrict__ A,
                                                  const __hip_bfloat16* __restrict__ Bt,
                                                  const float* __restrict__ bias,
                                                  __hip_bfloat16* __restrict__ Qb,
                                                  __hip_bfloat16* __restrict__ Kb,
                                                  __hip_bfloat16* __restrict__ Vtb) {
  __shared__ __hip_bfloat16 As[2][128 * 64];   // 16 KB per slot
  __shared__ __hip_bfloat16 Bs[2][192 * 64];   // 24 KB per slot
  const int tid = threadIdx.x;
  const int l = tid & 63, w = tid >> 6;
  const int lr = l & 15, lg = l >> 4;
  const int wm = w >> 2, wn = w & 3;           // 2m x 4n: 64 rows x 48 cols per wave
  const int m0 = blockIdx.x * 128, n0 = blockIdx.y * 192;

  const int srow = tid >> 3;                   // 0..63
  const int scol = (((tid & 7) ^ (srow & 7)) << 3);
  const size_t aoffs = (size_t)(m0 + srow) * 1024 + scol;
  const size_t boffs = (size_t)(n0 + srow) * 1024 + scol;
  const int ldst = tid * 8;

  auto stage = [&](int t, int s) {
    const int k0 = t * 64;
#pragma unroll
    for (int rd = 0; rd < 2; ++rd)
      gl_lds16(A + aoffs + (size_t)rd * 65536 + k0, &As[s][rd * 4096 + ldst]);
#pragma unroll
    for (int rd = 0; rd < 3; ++rd)
      gl_lds16(Bt + boffs + (size_t)rd * 65536 + k0, &Bs[s][rd * 4096 + ldst]);
  };

  const unsigned asLds = (unsigned)(uintptr_t)&As[0][0];
  const unsigned bsLds = (unsigned)(uintptr_t)&Bs[0][0];
  const unsigned aBase0 = asLds + 2u * ((wm*64 + lr) * 64 + ((lg ^ (lr & 7)) << 3));
  const unsigned bBase0 = bsLds + 2u * ((wn*48 + lr) * 64 + ((lg ^ (lr & 7)) << 3));

  stage(0, 0);
  VMCNT0;
  BARRIER;

  f32x4 acc[4][3] = {};
  short8 a_[4][2], b_[3][2];

#pragma unroll
  for (int t = 0; t < 16; ++t) {
    const int s = t & 1;
    const unsigned aB0 = aBase0 + (unsigned)s * 16384u;
    const unsigned aB1 = aB0 ^ 64u;
    const unsigned bB0 = bBase0 + (unsigned)s * 24576u;
    const unsigned bB1 = bB0 ^ 64u;
    if (t < 15) stage(t + 1, s ^ 1);
    a_[0][0] = ldsr_o0(aB0); a_[1][0] = ldsr_o1(aB0); a_[2][0] = ldsr_o2(aB0); a_[3][0] = ldsr_o3(aB0);
    a_[0][1] = ldsr_o0(aB1); a_[1][1] = ldsr_o1(aB1); a_[2][1] = ldsr_o2(aB1); a_[3][1] = ldsr_o3(aB1);
    b_[0][0] = ldsr_o0(bB0); b_[1][0] = ldsr_o1(bB0); b_[2][0] = ldsr_o2(bB0);
    b_[0][1] = ldsr_o0(bB1); b_[1][1] = ldsr_o1(bB1); b_[2][1] = ldsr_o2(bB1);
    LGKM0;
    __builtin_amdgcn_s_setprio(1);
#pragma unroll
    for (int m = 0; m < 4; ++m)
#pragma unroll
      for (int n = 0; n < 3; ++n)
#pragma unroll
        for (int ks = 0; ks < 2; ++ks)
          acc[m][n] = mfma16(a_[m][ks], b_[n][ks], acc[m][n]);
    __builtin_amdgcn_s_setprio(0);
    if (t < 15) { VMCNT0; }
    BARRIER;
  }

  __syncthreads();
  // ---- per-16-col-group LDS-bounce epilogue (r9-proven shape, 3 groups/wave) ----
  __hip_bfloat16* reg = &Bs[0][0] + w * 3072;   // 8 waves x 3 groups x 1024 elems
  const int colbase = n0 + wn * 48;
  const int rowbase = m0 + wm * 64;
  const int bidx = rowbase >> 11;
  const int tbase = rowbase & 2047;
  const float qs = 0.18033688011112042f;   // 0.125 * log2(e) folded into Q
  float bv[3];
#pragma unroll
  for (int g = 0; g < 3; ++g) bv[g] = bias[colbase + g * 16 + lr];
#pragma unroll
  for (int g = 0; g < 3; ++g) {
    const int cg0 = colbase + g * 16;
    const int which = cg0 >> 10;
    __hip_bfloat16* rg = reg + g * 1024;
    if (which == 2) {
#pragma unroll
      for (int m = 0; m < 4; ++m)
#pragma unroll
        for (int r = 0; r < 4; ++r) {
          const int t = m * 16 + lg * 4 + r;
          rg[lr * 64 + (t ^ ((lr & 7) << 3))] = __float2bfloat16(acc[m][g][r] + bv[g]);
        }
    } else {
      const float sc = (which == 0) ? qs : 1.f;
#pragma unroll
      for (int m = 0; m < 4; ++m)
#pragma unroll
        for (int r = 0; r < 4; ++r) {
          const int t = m * 16 + lg * 4 + r;
          rg[t * 16 + (lr ^ (((t >> 2) & 1) << 3))] =
              __float2bfloat16((acc[m][g][r] + bv[g]) * sc);
        }
    }
  }
#pragma unroll
  for (int g = 0; g < 3; ++g) {
    const int cg0 = colbase + g * 16;
    const int which = cg0 >> 10;
    const int hh = (cg0 >> 6) & 15;
    const int dd0 = cg0 & 48;
    const size_t bh = (size_t)bidx * 16 + hh;
    const __hip_bfloat16* rg = reg + g * 1024;
    if (which < 2) {
      __hip_bfloat16* basep = (which == 0) ? Qb : Kb;
      const int t = l;
      const int Xc = ((t >> 2) & 1) << 3;
      short8 y0 = *reinterpret_cast<const short8*>(&rg[t * 16 + Xc]);
      short8 y1 = *reinterpret_cast<const short8*>(&rg[t * 16 + (Xc ^ 8)]);
      __hip_bfloat16* dst = basep + (bh * TT + tbase + t) * 64 + dd0;
      *reinterpret_cast<short8*>(dst) = y0;
      *reinterpret_cast<short8*>(dst + 8) = y1;
    } else {
      const int dd = l >> 2, tseg = l & 3;
      const int X = (dd & 7) << 3;
      const int S0 = (((tseg ^ (X >> 4)) & 3) << 4) | (X & 8);
      short8 y0 = *reinterpret_cast<const short8*>(&rg[dd * 64 + S0]);
      short8 y1 = *reinterpret_cast<const short8*>(&rg[dd * 64 + (S0 ^ 8)]);
      __hip_bfloat16* dst = Vtb + (bh * 64 + dd0 + dd) * TT + tbase + tseg * 16;
      *reinterpret_cast<short8*>(dst) = y0;
      *reinterpret_cast<short8*>(dst + 8) = y1;
    }
  }
}

// ---------------- 128x128 double-buffered dist-1 GEMM (proj), 2 blocks/CU ----------------
__global__ __launch_bounds__(256, 2) void k_gemm2(const __hip_bfloat16* __restrict__ A,
                                                  const __hip_bfloat16* __restrict__ Bt,
                                                  const float* __restrict__ bias,
                                                  float* __restrict__ outF) {
  __shared__ __hip_bfloat16 As[2][128 * 64];
  __shared__ __hip_bfloat16 Bs[2][128 * 64];
  const int tid = threadIdx.x;
  const int l = tid & 63, w = tid >> 6;
  const int lr = l & 15, lg = l >> 4;
  const int wm = w >> 1, wn = w & 1;
  const int m0 = blockIdx.x * 128, n0 = blockIdx.y * 128;

  const int srow = tid >> 3;                 // 0..31
  const int scol = (((tid & 7) ^ (srow & 7)) << 3);
  const size_t aoffs = (size_t)(m0 + srow) * 1024 + scol;
  const size_t boffs = (size_t)(n0 + srow) * 1024 + scol;
  const int ldst = tid * 8;

  auto stage = [&](int t, int s) {
    const int k0 = t * 64;
#pragma unroll
    for (int rd = 0; rd < 4; ++rd) {
      gl_lds16(A + aoffs + (size_t)rd * 32768 + k0, &As[s][rd * 2048 + ldst]);
      gl_lds16(Bt + boffs + (size_t)rd * 32768 + k0, &Bs[s][rd * 2048 + ldst]);
    }
  };

  const unsigned asLds = (unsigned)(uintptr_t)&As[0][0];
  const unsigned bsLds = (unsigned)(uintptr_t)&Bs[0][0];
  const unsigned aBase0 = asLds + 2u * ((wm*64 + lr) * 64 + ((lg ^ (lr & 7)) << 3));
  const unsigned bBase0 = bsLds + 2u * ((wn*64 + lr) * 64 + ((lg ^ (lr & 7)) << 3));

  stage(0, 0);
  VMCNT0;
  BARRIER;

  f32x4 acc[4][4] = {};
  short8 a_[4][2], b_[4][2];

#pragma unroll
  for (int t = 0; t < 16; ++t) {
    const int s = t & 1;
    const unsigned aB0 = aBase0 + (unsigned)s * 16384u;
    const unsigned aB1 = aB0 ^ 64u;
    const unsigned bB0 = bBase0 + (unsigned)s * 16384u;
    const unsigned bB1 = bB0 ^ 64u;
    if (t < 15) stage(t + 1, s ^ 1);
    a_[0][0] = ldsr_o0(aB0); a_[1][0] = ldsr_o1(aB0); a_[2][0] = ldsr_o2(aB0); a_[3][0] = ldsr_o3(aB0);
    a_[0][1] = ldsr_o0(aB1); a_[1][1] = ldsr_o1(aB1); a_[2][1] = ldsr_o2(aB1); a_[3][1] = ldsr_o3(aB1);
    b_[0][0] = ldsr_o0(bB0); b_[1][0] = ldsr_o1(bB0); b_[2][0] = ldsr_o2(bB0); b_[3][0] = ldsr_o3(bB0);
    b_[0][1] = ldsr_o0(bB1); b_[1][1] = ldsr_o1(bB1); b_[2][1] = ldsr_o2(bB1); b_[3][1] = ldsr_o3(bB1);
    LGKM0;
    __builtin_amdgcn_s_setprio(1);
#pragma unroll
    for (int m = 0; m < 4; ++m)
#pragma unroll
      for (int n = 0; n < 4; ++n)
#pragma unroll
        for (int ks = 0; ks < 2; ++ks)
          acc[m][n] = mfma16(a_[m][ks], b_[n][ks], acc[m][n]);
    __builtin_amdgcn_s_setprio(0);
    if (t < 15) { VMCNT0; }
    BARRIER;
  }

  __syncthreads();
#pragma unroll
  for (int n = 0; n < 4; ++n) {
    const int col = n0 + wn * 64 + n * 16 + lr;
    const float bvv = bias[col];
#pragma unroll
    for (int m = 0; m < 4; ++m)
#pragma unroll
      for (int r = 0; r < 4; ++r) {
        const int row = m0 + wm * 64 + m * 16 + lg * 4 + r;
        outF[(size_t)row * 1024 + col] = acc[m][n][r] + bvv;
      }
  }
}

// ---------------- causal flash attention (r9-proven merged paired q-tiles) ----------------
__device__ __forceinline__ void tile_step(f32x4 s0, f32x4 s1, int kbase, int kmaxw, int qmb,
                                          short8 v0, short8 v1, short8 v2, short8 v3,
                                          f32x4 (&acc)[4], float& lrun) {
  if (kbase + 31 > kmaxw - 15) {       // diagonal chunk: per-element causal mask
#pragma unroll
    for (int r = 0; r < 4; ++r) {
      const int off = (r & 1) + ((r & 2) << 2);   // 0,1,8,9
      if (kbase + off > qmb)      s0[r] = -INFINITY;
      if (kbase + 16 + off > qmb) s1[r] = -INFINITY;
    }
  }
  float p0 = __builtin_amdgcn_exp2f(s0[0]), p1 = __builtin_amdgcn_exp2f(s0[1]);
  float p2 = __builtin_amdgcn_exp2f(s0[2]), p3 = __builtin_amdgcn_exp2f(s0[3]);
  float p4 = __builtin_amdgcn_exp2f(s1[0]), p5 = __builtin_amdgcn_exp2f(s1[1]);
  float p6 = __builtin_amdgcn_exp2f(s1[2]), p7 = __builtin_amdgcn_exp2f(s1[3]);
  lrun += ((p0 + p1) + (p2 + p3)) + ((p4 + p5) + (p6 + p7));
  unsigned u0 = pkbf(p0, p1);
  unsigned u1 = pkbf(p2, p3);
  unsigned u2 = pkbf(p4, p5);
  unsigned u3 = pkbf(p6, p7);
  perm16p(u0, u1);
  perm16p(u2, u3);
  perm32p(u0, u2);
  perm32p(u1, u3);
  union { unsigned u[4]; short8 s; } pw;
  pw.u[0] = u0; pw.u[1] = u2; pw.u[2] = u1; pw.u[3] = u3;
  const short8 pf = pw.s;
  acc[0] = mfma16(v0, pf, acc[0]);
  acc[1] = mfma16(v1, pf, acc[1]);
  acc[2] = mfma16(v2, pf, acc[2]);
  acc[3] = mfma16(v3, pf, acc[3]);
}

__device__ __forceinline__ void store_tile(__hip_bfloat16* Ylds, f32x4 (&acc)[4],
                                           float lrun, int q0, int w, int l,
                                           int lr, int lg, int bh,
                                           __hip_bfloat16* __restrict__ Y) {
  lrun += __shfl_xor(lrun, 16);
  lrun += __shfl_xor(lrun, 32);
  const float inv = 1.f / lrun;
#pragma unroll
  for (int nb = 0; nb < 4; ++nb) {
#pragma unroll
    for (int r = 0; r < 4; ++r) {
      const int d = nb * 16 + lg * 4 + r;
      Ylds[swz64(lr, d)] = __float2bfloat16(acc[nb][r] * inv);
    }
  }
  const int rr = l >> 2, part = l & 3;
  const int trow = q0 + w * 16 + rr;
  const int b = bh >> 4, h = bh & 15;
  short8 y0 = *reinterpret_cast<const short8*>(&Ylds[swz64(rr, part * 16)]);
  short8 y1 = *reinterpret_cast<const short8*>(&Ylds[swz64(rr, part * 16 + 8)]);
  __hip_bfloat16* dst = Y + ((size_t)b * TT + trow) * 1024 + h * 64 + part * 16;
  *reinterpret_cast<short8*>(dst) = y0;
  *reinterpret_cast<short8*>(dst + 8) = y1;
}

__global__ __launch_bounds__(256, 4) void k_flash(const __hip_bfloat16* __restrict__ Qb,
                                                  const __hip_bfloat16* __restrict__ Kb,
                                                  const __hip_bfloat16* __restrict__ Vtb,
                                                  __hip_bfloat16* __restrict__ Y) {
  __shared__ __hip_bfloat16 Klds[128 * 64];
  __shared__ __hip_bfloat16 Vtlds[64 * 128];
  const int tid = threadIdx.x;
  const int l = tid & 63, w = tid >> 6;
  const int lr = l & 15, lg = l >> 4;
  const int p  = blockIdx.x >> 6;       // pair index 0..15
  const int bh = blockIdx.x & 63;
  const int q0A = p * 64, q0B = (31 - p) * 64;
  const __hip_bfloat16* Qp = Qb + (size_t)bh * TT * 64;
  const __hip_bfloat16* Kp = Kb + (size_t)bh * TT * 64;
  const __hip_bfloat16* Vp = Vtb + (size_t)bh * 64 * TT;
  const int qrowA = q0A + w * 16 + lr;
  const int qrowB = q0B + w * 16 + lr;
  const short8 qfA0 = *reinterpret_cast<const short8*>(Qp + (size_t)qrowA * 64 + lg * 8);
  const short8 qfA1 = *reinterpret_cast<const short8*>(Qp + (size_t)qrowA * 64 + 32 + lg * 8);
  const short8 qfB0 = *reinterpret_cast<const short8*>(Qp + (size_t)qrowB * 64 + lg * 8);
  const short8 qfB1 = *reinterpret_cast<const short8*>(Qp + (size_t)qrowB * 64 + 32 + lg * 8);
  f32x4 accA[4] = {}, accB[4] = {};
  float lA = 0.f, lB = 0.f;

  const int ka  = lr * 64 + ((lg ^ (lr & 7)) << 3);
  const int va  = lr * 128 + ((lg ^ (lr & 15)) << 3);

  const __hip_bfloat16* gk[4];
  const __hip_bfloat16* gv[4];
  __hip_bfloat16* lk[4];
  __hip_bfloat16* lv[4];
#pragma unroll
  for (int it = 0; it < 4; ++it) {
    int e = it * 2048 + tid * 8;
    int rowk = e >> 6;
    int lcolk = ((((e >> 3) & 7) ^ (rowk & 7)) << 3);
    int rk = rowk & 15;
    int srk = (((rk >> 1) ^ (rk >> 3)) & 1) ? (rk ^ 10) : rk;
    int rowks = (rowk & ~15) | srk;
    gk[it] = Kp + (size_t)rowks * 64 + lcolk;
    lk[it] = &Klds[e];
    int rowv = e >> 7;
    int lcolv = ((((e >> 3) & 15) ^ (rowv & 15)) << 3);
    gv[it] = Vp + (size_t)rowv * TT + lcolv;
    lv[it] = &Vtlds[e];
  }

  const int kmaxwA = q0A + w * 16 + 15;
  const int kmaxwB = q0B + w * 16 + 15;
  const int base_lg = ((lg & 1) << 2) | (lg & 2);
  const int qmbA = qrowA - base_lg;
  const int qmbB = qrowB - base_lg;
  const int nblk = (q0B + 63) / 128 + 1;
  for (int blk = 0; blk < nblk; ++blk) {
    const int kv0 = blk * 128;
#pragma unroll
    for (int it = 0; it < 4; ++it) {
      gl_lds16(gk[it], lk[it]);
      gk[it] += 128 * 64;
    }
#pragma unroll
    for (int it = 0; it < 4; ++it) {
      gl_lds16(gv[it], lv[it]);
      gv[it] += 128;
    }
    __syncthreads();
#pragma unroll
    for (int kci = 0; kci < 4; ++kci) {
      const int kbase = kv0 + kci * 32;
      if (kbase > kmaxwB) break;
      const int kb = ka + kci * 2048;
      const short8 kf00 = *reinterpret_cast<const short8*>(&Klds[kb]);
      const short8 kf10 = *reinterpret_cast<const short8*>(&Klds[kb + 1024]);
      const short8 kf01 = *reinterpret_cast<const short8*>(&Klds[kb ^ 32]);
      const short8 kf11 = *reinterpret_cast<const short8*>(&Klds[(kb + 1024) ^ 32]);
      f32x4 sB0 = {}, sB1 = {};
      sB0 = mfma16(kf00, qfB0, sB0);
      sB1 = mfma16(kf10, qfB0, sB1);
      sB0 = mfma16(kf01, qfB1, sB0);
      sB1 = mfma16(kf11, qfB1, sB1);
      const bool aAct = (kbase <= kmaxwA);
      f32x4 sA0 = {}, sA1 = {};
      if (aAct) {
        sA0 = mfma16(kf00, qfA0, sA0);
        sA1 = mfma16(kf10, qfA0, sA1);
        sA0 = mfma16(kf01, qfA1, sA0);
        sA1 = mfma16(kf11, qfA1, sA1);
      }
      const int vb = va ^ (kci * 32);
      const short8 v0 = *reinterpret_cast<const short8*>(&Vtlds[vb]);
      const short8 v1 = *reinterpret_cast<const short8*>(&Vtlds[vb + 2048]);
      const short8 v2 = *reinterpret_cast<const short8*>(&Vtlds[vb + 4096]);
      const short8 v3 = *reinterpret_cast<const short8*>(&Vtlds[vb + 6144]);
      tile_step(sB0, sB1, kbase, kmaxwB, qmbB, v0, v1, v2, v3, accB, lB);
      if (aAct)
        tile_step(sA0, sA1, kbase, kmaxwA, qmbA, v0, v1, v2, v3, accA, lA);
    }
    __syncthreads();
  }
  __hip_bfloat16* Ylds = Klds + w * 1024;
  store_tile(Ylds, accA, lA, q0A, w, l, lr, lg, bh, Y);
  store_tile(Ylds, accB, lB, q0B, w, l, lr, lg, bh, Y);
}

// ---------------- launch ----------------
extern "C" void kernel_launch(void* const* d_in, const int* in_sizes, int n_in,
                              void* d_out, int out_size, void* d_ws, size_t ws_size,
                              hipStream_t stream) {
  const float* x     = (const float*)d_in[0];
  const float* Wqkv  = (const float*)d_in[1];
  const float* bqkv  = (const float*)d_in[2];
  const float* Wproj = (const float*)d_in[3];
  const float* bproj = (const float*)d_in[4];

  char* ws = (char*)d_ws;
  size_t off = 0;
  auto alloc = [&](size_t bytes) {
    char* p = ws + off;
    off += (bytes + 255) & ~(size_t)255;
    return p;
  };
  __hip_bfloat16* xb    = (__hip_bfloat16*)alloc((size_t)MTOT * 1024 * 2);
  __hip_bfloat16* wqkvT = (__hip_bfloat16*)alloc((size_t)3072 * 1024 * 2);
  __hip_bfloat16* wpT   = (__hip_bfloat16*)alloc((size_t)1024 * 1024 * 2);
  __hip_bfloat16* Qb    = (__hip_bfloat16*)alloc((size_t)64 * TT * 64 * 2);
  __hip_bfloat16* Kb    = (__hip_bfloat16*)alloc((size_t)64 * TT * 64 * 2);
  __hip_bfloat16* Vtb   = (__hip_bfloat16*)alloc((size_t)64 * TT * 64 * 2);
  __hip_bfloat16* Yb    = (__hip_bfloat16*)alloc((size_t)MTOT * 1024 * 2);

  k_cvt<<<(MTOT * 1024 / 8 + 255) / 256, 256, 0, stream>>>(x, xb, MTOT * 1024 / 8);
  k_transpose_cvt<<<dim3(3072 / 32, 1024 / 32), 256, 0, stream>>>(Wqkv, wqkvT, 1024, 3072);
  k_transpose_cvt<<<dim3(1024 / 32, 1024 / 32), 256, 0, stream>>>(Wproj, wpT, 1024, 1024);
  k_gemm3<<<dim3(64, 16), 512, 0, stream>>>(xb, wqkvT, bqkv, Qb, Kb, Vtb);
  k_flash<<<16 * 64, 256, 0, stream>>>(Qb, Kb, Vtb, Yb);
  k_gemm2<<<dim3(64, 8), 256, 0, stream>>>(Yb, wpT, bproj, (float*)d_out);
}

// Round 17
// 139.307 us; speedup vs baseline: 1.3601x; 1.0070x over previous
//
#include <hip/hip_runtime.h>
#include <hip/hip_bf16.h>
#include <cstdint>
#include <math.h>

// Problem constants
#define DM   1024
#define NH   16
#define DH   64
#define BB   4
#define TT   2048
#define MTOT (BB*TT)   // 8192 rows

using short8 = __attribute__((ext_vector_type(8))) short;  // 8 bf16 (4 VGPRs)
using f32x4  = __attribute__((ext_vector_type(4))) float;

__device__ __forceinline__ f32x4 mfma16(short8 a, short8 b, f32x4 c) {
  return __builtin_amdgcn_mfma_f32_16x16x32_bf16(a, b, c, 0, 0, 0);
}

typedef const __attribute__((address_space(1))) unsigned int* as1_u32p;
typedef __attribute__((address_space(3))) unsigned int*       as3_u32p;

// async global->LDS, 16B per lane; LDS dest = wave-uniform base + lane*16 (linear)
__device__ __forceinline__ void gl_lds16(const void* g, void* l) {
  __builtin_amdgcn_global_load_lds(
      (as1_u32p)(reinterpret_cast<uintptr_t>(g)),
      (as3_u32p)((unsigned int)(reinterpret_cast<uintptr_t>(l))),
      16, 0, 0);
}

// XOR swizzle for tiles with 64-elem (128B) rows: 8 slots of 8 bf16; slot ^= row&7
__device__ __forceinline__ int swz64(int row, int col) {
  return row*64 + ((((col >> 3) ^ (row & 7)) << 3) | (col & 7));
}

__device__ __forceinline__ unsigned pkbf(float a, float b) {
  __hip_bfloat162 h = __float22bfloat162_rn(make_float2(a, b)); // x=lo, y=hi
  return *reinterpret_cast<unsigned*>(&h);
}

// permlane swaps (VALU pipe). Verified row semantics (involutions):
// perm16(d,s): d'=[d0,s0,d2,s2], s'=[d1,s1,d3,s3]   (16-lane rows)
// perm32(d,s): d'=[d0,d1,s0,s1], s'=[d2,d3,s2,s3]
__device__ __forceinline__ void perm16p(unsigned &a, unsigned &b) {
  asm("v_permlane16_swap_b32 %0, %1" : "+v"(a), "+v"(b));
}
__device__ __forceinline__ void perm32p(unsigned &a, unsigned &b) {
  asm("v_permlane32_swap_b32 %0, %1" : "+v"(a), "+v"(b));
}

// inline-asm LDS reads (opaque to alias analysis: no compiler-inserted vmcnt drains)
__device__ __forceinline__ short8 ldsr_o0(unsigned a) {
  short8 r; asm volatile("ds_read_b128 %0, %1" : "=v"(r) : "v"(a)); return r;
}
__device__ __forceinline__ short8 ldsr_o1(unsigned a) {
  short8 r; asm volatile("ds_read_b128 %0, %1 offset:2048" : "=v"(r) : "v"(a)); return r;
}
__device__ __forceinline__ short8 ldsr_o2(unsigned a) {
  short8 r; asm volatile("ds_read_b128 %0, %1 offset:4096" : "=v"(r) : "v"(a)); return r;
}
__device__ __forceinline__ short8 ldsr_o3(unsigned a) {
  short8 r; asm volatile("ds_read_b128 %0, %1 offset:6144" : "=v"(r) : "v"(a)); return r;
}
__device__ __forceinline__ short8 ldsr_o4(unsigned a) {
  short8 r; asm volatile("ds_read_b128 %0, %1 offset:8192" : "=v"(r) : "v"(a)); return r;
}
__device__ __forceinline__ short8 ldsr_o5(unsigned a) {
  short8 r; asm volatile("ds_read_b128 %0, %1 offset:10240" : "=v"(r) : "v"(a)); return r;
}

#define LGKM0  do { asm volatile("s_waitcnt lgkmcnt(0)"); __builtin_amdgcn_sched_barrier(0); } while(0)
#define VMCNT0 do { __builtin_amdgcn_sched_barrier(0); asm volatile("s_waitcnt vmcnt(0)"); __builtin_amdgcn_sched_barrier(0); } while(0)
#define BARRIER do { __builtin_amdgcn_s_barrier(); __builtin_amdgcn_sched_barrier(0); } while(0)

// ---------------- fp32 -> bf16 copy convert ----------------
__global__ __launch_bounds__(256) void k_cvt(const float* __restrict__ in,
                                             __hip_bfloat16* __restrict__ out, int n8) {
  int i = blockIdx.x * 256 + threadIdx.x;
  if (i >= n8) return;
  const float* p = in + (size_t)i * 8;
  short8 o;
#pragma unroll
  for (int j = 0; j < 8; ++j) {
    __hip_bfloat16 h = __float2bfloat16(p[j]);
    o[j] = *reinterpret_cast<short*>(&h);
  }
  *reinterpret_cast<short8*>(out + (size_t)i * 8) = o;
}

// ---------------- W [K][N] fp32 -> Wt [N][K] bf16 (tiled transpose) ----------------
__global__ __launch_bounds__(256) void k_transpose_cvt(const float* __restrict__ W,
                                                       __hip_bfloat16* __restrict__ Wt,
                                                       int K, int N) {
  __shared__ float tbuf[32][33];
  const int n0 = blockIdx.x * 32, k0 = blockIdx.y * 32;
  const int tx = threadIdx.x & 31, ty = threadIdx.x >> 5;
#pragma unroll
  for (int i = 0; i < 4; ++i)
    tbuf[ty + i*8][tx] = W[(size_t)(k0 + ty + i*8) * N + n0 + tx];
  __syncthreads();
#pragma unroll
  for (int i = 0; i < 4; ++i)
    Wt[(size_t)(n0 + ty + i*8) * K + k0 + tx] = __float2bfloat16(tbuf[tx][ty + i*8]);
}

// ---------------- 128x192 double-buffered QKV GEMM, 2 blocks/CU (r16-proven) ----------------
__global__ __launch_bounds__(512, 4) void k_gemm3(const __hip_bfloat16* __restrict__ A,
                                                  const __hip_bfloat16* __restrict__ Bt,
                                                  const float* __restrict__ bias,
                                                  __hip_bfloat16* __restrict__ Qb,
                                                  __hip_bfloat16* __restrict__ Kb,
                                                  __hip_bfloat16* __restrict__ Vtb) {
  __shared__ __hip_bfloat16 As[2][128 * 64];   // 16 KB per slot
  __shared__ __hip_bfloat16 Bs[2][192 * 64];   // 24 KB per slot
  const int tid = threadIdx.x;
  const int l = tid & 63, w = tid >> 6;
  const int lr = l & 15, lg = l >> 4;
  const int wm = w >> 2, wn = w & 3;           // 2m x 4n: 64 rows x 48 cols per wave
  const int m0 = blockIdx.x * 128, n0 = blockIdx.y * 192;

  const int srow = tid >> 3;                   // 0..63
  const int scol = (((tid & 7) ^ (srow & 7)) << 3);
  const size_t aoffs = (size_t)(m0 + srow) * 1024 + scol;
  const size_t boffs = (size_t)(n0 + srow) * 1024 + scol;
  const int ldst = tid * 8;

  auto stage = [&](int t, int s) {
    const int k0 = t * 64;
#pragma unroll
    for (int rd = 0; rd < 2; ++rd)
      gl_lds16(A + aoffs + (size_t)rd * 65536 + k0, &As[s][rd * 4096 + ldst]);
#pragma unroll
    for (int rd = 0; rd < 3; ++rd)
      gl_lds16(Bt + boffs + (size_t)rd * 65536 + k0, &Bs[s][rd * 4096 + ldst]);
  };

  const unsigned asLds = (unsigned)(uintptr_t)&As[0][0];
  const unsigned bsLds = (unsigned)(uintptr_t)&Bs[0][0];
  const unsigned aBase0 = asLds + 2u * ((wm*64 + lr) * 64 + ((lg ^ (lr & 7)) << 3));
  const unsigned bBase0 = bsLds + 2u * ((wn*48 + lr) * 64 + ((lg ^ (lr & 7)) << 3));

  stage(0, 0);
  VMCNT0;
  BARRIER;

  f32x4 acc[4][3] = {};
  short8 a_[4][2], b_[3][2];

#pragma unroll
  for (int t = 0; t < 16; ++t) {
    const int s = t & 1;
    const unsigned aB0 = aBase0 + (unsigned)s * 16384u;
    const unsigned aB1 = aB0 ^ 64u;
    const unsigned bB0 = bBase0 + (unsigned)s * 24576u;
    const unsigned bB1 = bB0 ^ 64u;
    if (t < 15) stage(t + 1, s ^ 1);
    a_[0][0] = ldsr_o0(aB0); a_[1][0] = ldsr_o1(aB0); a_[2][0] = ldsr_o2(aB0); a_[3][0] = ldsr_o3(aB0);
    a_[0][1] = ldsr_o0(aB1); a_[1][1] = ldsr_o1(aB1); a_[2][1] = ldsr_o2(aB1); a_[3][1] = ldsr_o3(aB1);
    b_[0][0] = ldsr_o0(bB0); b_[1][0] = ldsr_o1(bB0); b_[2][0] = ldsr_o2(bB0);
    b_[0][1] = ldsr_o0(bB1); b_[1][1] = ldsr_o1(bB1); b_[2][1] = ldsr_o2(bB1);
    LGKM0;
    __builtin_amdgcn_s_setprio(1);
#pragma unroll
    for (int m = 0; m < 4; ++m)
#pragma unroll
      for (int n = 0; n < 3; ++n)
#pragma unroll
        for (int ks = 0; ks < 2; ++ks)
          acc[m][n] = mfma16(a_[m][ks], b_[n][ks], acc[m][n]);
    __builtin_amdgcn_s_setprio(0);
    if (t < 15) { VMCNT0; }
    BARRIER;
  }

  __syncthreads();
  // ---- per-16-col-group LDS-bounce epilogue (3 groups/wave) ----
  __hip_bfloat16* reg = &Bs[0][0] + w * 3072;   // 8 waves x 3 groups x 1024 elems
  const int colbase = n0 + wn * 48;
  const int rowbase = m0 + wm * 64;
  const int bidx = rowbase >> 11;
  const int tbase = rowbase & 2047;
  const float qs = 0.18033688011112042f;   // 0.125 * log2(e) folded into Q
  float bv[3];
#pragma unroll
  for (int g = 0; g < 3; ++g) bv[g] = bias[colbase + g * 16 + lr];
#pragma unroll
  for (int g = 0; g < 3; ++g) {
    const int cg0 = colbase + g * 16;
    const int which = cg0 >> 10;
    __hip_bfloat16* rg = reg + g * 1024;
    if (which == 2) {
#pragma unroll
      for (int m = 0; m < 4; ++m)
#pragma unroll
        for (int r = 0; r < 4; ++r) {
          const int t = m * 16 + lg * 4 + r;
          rg[lr * 64 + (t ^ ((lr & 7) << 3))] = __float2bfloat16(acc[m][g][r] + bv[g]);
        }
    } else {
      const float sc = (which == 0) ? qs : 1.f;
#pragma unroll
      for (int m = 0; m < 4; ++m)
#pragma unroll
        for (int r = 0; r < 4; ++r) {
          const int t = m * 16 + lg * 4 + r;
          rg[t * 16 + (lr ^ (((t >> 2) & 1) << 3))] =
              __float2bfloat16((acc[m][g][r] + bv[g]) * sc);
        }
    }
  }
#pragma unroll
  for (int g = 0; g < 3; ++g) {
    const int cg0 = colbase + g * 16;
    const int which = cg0 >> 10;
    const int hh = (cg0 >> 6) & 15;
    const int dd0 = cg0 & 48;
    const size_t bh = (size_t)bidx * 16 + hh;
    const __hip_bfloat16* rg = reg + g * 1024;
    if (which < 2) {
      __hip_bfloat16* basep = (which == 0) ? Qb : Kb;
      const int t = l;
      const int Xc = ((t >> 2) & 1) << 3;
      short8 y0 = *reinterpret_cast<const short8*>(&rg[t * 16 + Xc]);
      short8 y1 = *reinterpret_cast<const short8*>(&rg[t * 16 + (Xc ^ 8)]);
      __hip_bfloat16* dst = basep + (bh * TT + tbase + t) * 64 + dd0;
      *reinterpret_cast<short8*>(dst) = y0;
      *reinterpret_cast<short8*>(dst + 8) = y1;
    } else {
      const int dd = l >> 2, tseg = l & 3;
      const int X = (dd & 7) << 3;
      const int S0 = (((tseg ^ (X >> 4)) & 3) << 4) | (X & 8);
      short8 y0 = *reinterpret_cast<const short8*>(&rg[dd * 64 + S0]);
      short8 y1 = *reinterpret_cast<const short8*>(&rg[dd * 64 + (S0 ^ 8)]);
      __hip_bfloat16* dst = Vtb + (bh * 64 + dd0 + dd) * TT + tbase + tseg * 16;
      *reinterpret_cast<short8*>(dst) = y0;
      *reinterpret_cast<short8*>(dst + 8) = y1;
    }
  }
}

// ---------------- 128x128 double-buffered dist-1 GEMM (proj), 2 blocks/CU ----------------
__global__ __launch_bounds__(256, 2) void k_gemm2(const __hip_bfloat16* __restrict__ A,
                                                  const __hip_bfloat16* __restrict__ Bt,
                                                  const float* __restrict__ bias,
                                                  float* __restrict__ outF) {
  __shared__ __hip_bfloat16 As[2][128 * 64];
  __shared__ __hip_bfloat16 Bs[2][128 * 64];
  const int tid = threadIdx.x;
  const int l = tid & 63, w = tid >> 6;
  const int lr = l & 15, lg = l >> 4;
  const int wm = w >> 1, wn = w & 1;
  const int m0 = blockIdx.x * 128, n0 = blockIdx.y * 128;

  const int srow = tid >> 3;                 // 0..31
  const int scol = (((tid & 7) ^ (srow & 7)) << 3);
  const size_t aoffs = (size_t)(m0 + srow) * 1024 + scol;
  const size_t boffs = (size_t)(n0 + srow) * 1024 + scol;
  const int ldst = tid * 8;

  auto stage = [&](int t, int s) {
    const int k0 = t * 64;
#pragma unroll
    for (int rd = 0; rd < 4; ++rd) {
      gl_lds16(A + aoffs + (size_t)rd * 32768 + k0, &As[s][rd * 2048 + ldst]);
      gl_lds16(Bt + boffs + (size_t)rd * 32768 + k0, &Bs[s][rd * 2048 + ldst]);
    }
  };

  const unsigned asLds = (unsigned)(uintptr_t)&As[0][0];
  const unsigned bsLds = (unsigned)(uintptr_t)&Bs[0][0];
  const unsigned aBase0 = asLds + 2u * ((wm*64 + lr) * 64 + ((lg ^ (lr & 7)) << 3));
  const unsigned bBase0 = bsLds + 2u * ((wn*64 + lr) * 64 + ((lg ^ (lr & 7)) << 3));

  stage(0, 0);
  VMCNT0;
  BARRIER;

  f32x4 acc[4][4] = {};
  short8 a_[4][2], b_[4][2];

#pragma unroll
  for (int t = 0; t < 16; ++t) {
    const int s = t & 1;
    const unsigned aB0 = aBase0 + (unsigned)s * 16384u;
    const unsigned aB1 = aB0 ^ 64u;
    const unsigned bB0 = bBase0 + (unsigned)s * 16384u;
    const unsigned bB1 = bB0 ^ 64u;
    if (t < 15) stage(t + 1, s ^ 1);
    a_[0][0] = ldsr_o0(aB0); a_[1][0] = ldsr_o1(aB0); a_[2][0] = ldsr_o2(aB0); a_[3][0] = ldsr_o3(aB0);
    a_[0][1] = ldsr_o0(aB1); a_[1][1] = ldsr_o1(aB1); a_[2][1] = ldsr_o2(aB1); a_[3][1] = ldsr_o3(aB1);
    b_[0][0] = ldsr_o0(bB0); b_[1][0] = ldsr_o1(bB0); b_[2][0] = ldsr_o2(bB0); b_[3][0] = ldsr_o3(bB0);
    b_[0][1] = ldsr_o0(bB1); b_[1][1] = ldsr_o1(bB1); b_[2][1] = ldsr_o2(bB1); b_[3][1] = ldsr_o3(bB1);
    LGKM0;
    __builtin_amdgcn_s_setprio(1);
#pragma unroll
    for (int m = 0; m < 4; ++m)
#pragma unroll
      for (int n = 0; n < 4; ++n)
#pragma unroll
        for (int ks = 0; ks < 2; ++ks)
          acc[m][n] = mfma16(a_[m][ks], b_[n][ks], acc[m][n]);
    __builtin_amdgcn_s_setprio(0);
    if (t < 15) { VMCNT0; }
    BARRIER;
  }

  __syncthreads();
#pragma unroll
  for (int n = 0; n < 4; ++n) {
    const int col = n0 + wn * 64 + n * 16 + lr;
    const float bvv = bias[col];
#pragma unroll
    for (int m = 0; m < 4; ++m)
#pragma unroll
      for (int r = 0; r < 4; ++r) {
        const int row = m0 + wm * 64 + m * 16 + lg * 4 + r;
        outF[(size_t)row * 1024 + col] = acc[m][n][r] + bvv;
      }
  }
}

// ---------------- causal flash attention (merged paired q-tiles, mfma-lrun) ----------------
// Fixed-max softmax, sigma-permuted K rows -> P redistribution = 2x permlane16_swap +
// 2x permlane32_swap. NEW: row-sum l computed on the MFMA pipe via all-ones A-fragment
// (accL = mfma(ones, P)): removes 8 v_add per tile_step AND the epilogue shfl reduce;
// l now sums the exact bf16 P used in O (more consistent normalization).
__device__ __forceinline__ void tile_step(f32x4 s0, f32x4 s1, int kbase, int kmaxw, int qmb,
                                          short8 ones,
                                          short8 v0, short8 v1, short8 v2, short8 v3,
                                          f32x4 (&acc)[4], f32x4& accL) {
  if (kbase + 31 > kmaxw - 15) {       // diagonal chunk: per-element causal mask
#pragma unroll
    for (int r = 0; r < 4; ++r) {
      const int off = (r & 1) + ((r & 2) << 2);   // 0,1,8,9
      if (kbase + off > qmb)      s0[r] = -INFINITY;
      if (kbase + 16 + off > qmb) s1[r] = -INFINITY;
    }
  }
  float p0 = __builtin_amdgcn_exp2f(s0[0]), p1 = __builtin_amdgcn_exp2f(s0[1]);
  float p2 = __builtin_amdgcn_exp2f(s0[2]), p3 = __builtin_amdgcn_exp2f(s0[3]);
  float p4 = __builtin_amdgcn_exp2f(s1[0]), p5 = __builtin_amdgcn_exp2f(s1[1]);
  float p6 = __builtin_amdgcn_exp2f(s1[2]), p7 = __builtin_amdgcn_exp2f(s1[3]);
  unsigned u0 = pkbf(p0, p1);
  unsigned u1 = pkbf(p2, p3);
  unsigned u2 = pkbf(p4, p5);
  unsigned u3 = pkbf(p6, p7);
  perm16p(u0, u1);
  perm16p(u2, u3);
  perm32p(u0, u2);
  perm32p(u1, u3);
  union { unsigned u[4]; short8 s; } pw;
  pw.u[0] = u0; pw.u[1] = u2; pw.u[2] = u1; pw.u[3] = u3;
  const short8 pf = pw.s;
  acc[0] = mfma16(v0, pf, acc[0]);
  acc[1] = mfma16(v1, pf, acc[1]);
  acc[2] = mfma16(v2, pf, acc[2]);
  acc[3] = mfma16(v3, pf, acc[3]);
  accL   = mfma16(ones, pf, accL);   // row-sum of P on the MFMA pipe
}

__device__ __forceinline__ void store_tile(__hip_bfloat16* Ylds, f32x4 (&acc)[4],
                                           float lsum, int q0, int w, int l,
                                           int lr, int lg, int bh,
                                           __hip_bfloat16* __restrict__ Y) {
  const float inv = 1.f / lsum;      // accL[0]: every lane holds full sum for q=lane&15
#pragma unroll
  for (int nb = 0; nb < 4; ++nb) {
#pragma unroll
    for (int r = 0; r < 4; ++r) {
      const int d = nb * 16 + lg * 4 + r;
      Ylds[swz64(lr, d)] = __float2bfloat16(acc[nb][r] * inv);
    }
  }
  const int rr = l >> 2, part = l & 3;
  const int trow = q0 + w * 16 + rr;
  const int b = bh >> 4, h = bh & 15;
  short8 y0 = *reinterpret_cast<const short8*>(&Ylds[swz64(rr, part * 16)]);
  short8 y1 = *reinterpret_cast<const short8*>(&Ylds[swz64(rr, part * 16 + 8)]);
  __hip_bfloat16* dst = Y + ((size_t)b * TT + trow) * 1024 + h * 64 + part * 16;
  *reinterpret_cast<short8*>(dst) = y0;
  *reinterpret_cast<short8*>(dst + 8) = y1;
}

__global__ __launch_bounds__(256, 4) void k_flash(const __hip_bfloat16* __restrict__ Qb,
                                                  const __hip_bfloat16* __restrict__ Kb,
                                                  const __hip_bfloat16* __restrict__ Vtb,
                                                  __hip_bfloat16* __restrict__ Y) {
  __shared__ __hip_bfloat16 Klds[128 * 64];
  __shared__ __hip_bfloat16 Vtlds[64 * 128];
  const int tid = threadIdx.x;
  const int l = tid & 63, w = tid >> 6;
  const int lr = l & 15, lg = l >> 4;
  const int p  = blockIdx.x >> 6;       // pair index 0..15
  const int bh = blockIdx.x & 63;
  const int q0A = p * 64, q0B = (31 - p) * 64;
  const __hip_bfloat16* Qp = Qb + (size_t)bh * TT * 64;
  const __hip_bfloat16* Kp = Kb + (size_t)bh * TT * 64;
  const __hip_bfloat16* Vp = Vtb + (size_t)bh * 64 * TT;
  const int qrowA = q0A + w * 16 + lr;
  const int qrowB = q0B + w * 16 + lr;
  const short8 qfA0 = *reinterpret_cast<const short8*>(Qp + (size_t)qrowA * 64 + lg * 8);
  const short8 qfA1 = *reinterpret_cast<const short8*>(Qp + (size_t)qrowA * 64 + 32 + lg * 8);
  const short8 qfB0 = *reinterpret_cast<const short8*>(Qp + (size_t)qrowB * 64 + lg * 8);
  const short8 qfB1 = *reinterpret_cast<const short8*>(Qp + (size_t)qrowB * 64 + 32 + lg * 8);
  f32x4 accA[4] = {}, accB[4] = {};
  f32x4 accLA = {}, accLB = {};
  union { unsigned u[4]; short8 s; } onesu;
  onesu.u[0] = onesu.u[1] = onesu.u[2] = onesu.u[3] = 0x3F803F80u;  // bf16 1.0 pairs
  const short8 ones = onesu.s;

  const int ka  = lr * 64 + ((lg ^ (lr & 7)) << 3);
  const int va  = lr * 128 + ((lg ^ (lr & 15)) << 3);

  const __hip_bfloat16* gk[4];
  const __hip_bfloat16* gv[4];
  __hip_bfloat16* lk[4];
  __hip_bfloat16* lv[4];
#pragma unroll
  for (int it = 0; it < 4; ++it) {
    int e = it * 2048 + tid * 8;
    int rowk = e >> 6;
    int lcolk = ((((e >> 3) & 7) ^ (rowk & 7)) << 3);
    int rk = rowk & 15;
    int srk = (((rk >> 1) ^ (rk >> 3)) & 1) ? (rk ^ 10) : rk;
    int rowks = (rowk & ~15) | srk;
    gk[it] = Kp + (size_t)rowks * 64 + lcolk;
    lk[it] = &Klds[e];
    int rowv = e >> 7;
    int lcolv = ((((e >> 3) & 15) ^ (rowv & 15)) << 3);
    gv[it] = Vp + (size_t)rowv * TT + lcolv;
    lv[it] = &Vtlds[e];
  }

  const int kmaxwA = q0A + w * 16 + 15;
  const int kmaxwB = q0B + w * 16 + 15;
  const int base_lg = ((lg & 1) << 2) | (lg & 2);
  const int qmbA = qrowA - base_lg;
  const int qmbB = qrowB - base_lg;
  const int nblk = (q0B + 63) / 128 + 1;
  for (int blk = 0; blk < nblk; ++blk) {
    const int kv0 = blk * 128;
#pragma unroll
    for (int it = 0; it < 4; ++it) {
      gl_lds16(gk[it], lk[it]);
      gk[it] += 128 * 64;
    }
#pragma unroll
    for (int it = 0; it < 4; ++it) {
      gl_lds16(gv[it], lv[it]);
      gv[it] += 128;
    }
    __syncthreads();
#pragma unroll
    for (int kci = 0; kci < 4; ++kci) {
      const int kbase = kv0 + kci * 32;
      if (kbase > kmaxwB) break;
      const int kb = ka + kci * 2048;
      const short8 kf00 = *reinterpret_cast<const short8*>(&Klds[kb]);
      const short8 kf10 = *reinterpret_cast<const short8*>(&Klds[kb + 1024]);
      const short8 kf01 = *reinterpret_cast<const short8*>(&Klds[kb ^ 32]);
      const short8 kf11 = *reinterpret_cast<const short8*>(&Klds[(kb + 1024) ^ 32]);
      f32x4 sB0 = {}, sB1 = {};
      sB0 = mfma16(kf00, qfB0, sB0);
      sB1 = mfma16(kf10, qfB0, sB1);
      sB0 = mfma16(kf01, qfB1, sB0);
      sB1 = mfma16(kf11, qfB1, sB1);
      const bool aAct = (kbase <= kmaxwA);
      f32x4 sA0 = {}, sA1 = {};
      if (aAct) {
        sA0 = mfma16(kf00, qfA0, sA0);
        sA1 = mfma16(kf10, qfA0, sA1);
        sA0 = mfma16(kf01, qfA1, sA0);
        sA1 = mfma16(kf11, qfA1, sA1);
      }
      const int vb = va ^ (kci * 32);
      const short8 v0 = *reinterpret_cast<const short8*>(&Vtlds[vb]);
      const short8 v1 = *reinterpret_cast<const short8*>(&Vtlds[vb + 2048]);
      const short8 v2 = *reinterpret_cast<const short8*>(&Vtlds[vb + 4096]);
      const short8 v3 = *reinterpret_cast<const short8*>(&Vtlds[vb + 6144]);
      tile_step(sB0, sB1, kbase, kmaxwB, qmbB, ones, v0, v1, v2, v3, accB, accLB);
      if (aAct)
        tile_step(sA0, sA1, kbase, kmaxwA, qmbA, ones, v0, v1, v2, v3, accA, accLA);
    }
    __syncthreads();
  }
  __hip_bfloat16* Ylds = Klds + w * 1024;
  store_tile(Ylds, accA, accLA[0], q0A, w, l, lr, lg, bh, Y);
  store_tile(Ylds, accB, accLB[0], q0B, w, l, lr, lg, bh, Y);
}

// ---------------- launch ----------------
extern "C" void kernel_launch(void* const* d_in, const int* in_sizes, int n_in,
                              void* d_out, int out_size, void* d_ws, size_t ws_size,
                              hipStream_t stream) {
  const float* x     = (const float*)d_in[0];
  const float* Wqkv  = (const float*)d_in[1];
  const float* bqkv  = (const float*)d_in[2];
  const float* Wproj = (const float*)d_in[3];
  const float* bproj = (const float*)d_in[4];

  char* ws = (char*)d_ws;
  size_t off = 0;
  auto alloc = [&](size_t bytes) {
    char* p = ws + off;
    off += (bytes + 255) & ~(size_t)255;
    return p;
  };
  __hip_bfloat16* xb    = (__hip_bfloat16*)alloc((size_t)MTOT * 1024 * 2);
  __hip_bfloat16* wqkvT = (__hip_bfloat16*)alloc((size_t)3072 * 1024 * 2);
  __hip_bfloat16* wpT   = (__hip_bfloat16*)alloc((size_t)1024 * 1024 * 2);
  __hip_bfloat16* Qb    = (__hip_bfloat16*)alloc((size_t)64 * TT * 64 * 2);
  __hip_bfloat16* Kb    = (__hip_bfloat16*)alloc((size_t)64 * TT * 64 * 2);
  __hip_bfloat16* Vtb   = (__hip_bfloat16*)alloc((size_t)64 * TT * 64 * 2);
  __hip_bfloat16* Yb    = (__hip_bfloat16*)alloc((size_t)MTOT * 1024 * 2);

  k_cvt<<<(MTOT * 1024 / 8 + 255) / 256, 256, 0, stream>>>(x, xb, MTOT * 1024 / 8);
  k_transpose_cvt<<<dim3(3072 / 32, 1024 / 32), 256, 0, stream>>>(Wqkv, wqkvT, 1024, 3072);
  k_transpose_cvt<<<dim3(1024 / 32, 1024 / 32), 256, 0, stream>>>(Wproj, wpT, 1024, 1024);
  k_gemm3<<<dim3(64, 16), 512, 0, stream>>>(xb, wqkvT, bqkv, Qb, Kb, Vtb);
  k_flash<<<16 * 64, 256, 0, stream>>>(Qb, Kb, Vtb, Yb);
  k_gemm2<<<dim3(64, 8), 256, 0, stream>>>(Yb, wpT, bproj, (float*)d_out);
}